// Round 5
// baseline (5115.446 us; speedup 1.0000x reference)
//
#include <hip/hip_runtime.h>
#include <hip/hip_cooperative_groups.h>
#include <cstddef>

// ---------------------------------------------------------------------------
// DecoderWithAttention forward — Round 9.
// vs R8: coop loop restructured from 4 grid.syncs/step to 2:
//  Phase AB (256 blocks, task=(b,q)): att2[b] inline (redundant x4, L2-hot),
//    logits+softmax in-LDS, awe quarter, gate inline, h->xcat tail copy.
//  Phase C  (256 blocks, task=(nt,mh)): xlstm GEMM K=512..3072 (h folded into
//    xcat tail; hwhh eliminated), epilogue adds embw+bcat.
// Also: k_att1_v3 (BM=128, 2x MFMA density), tconv fusion (5 launches -> 2).
// ---------------------------------------------------------------------------

namespace cg = cooperative_groups;

namespace {

typedef _Float16 f16;
typedef f16 f16x8 __attribute__((ext_vector_type(8)));
typedef f16 f16x4 __attribute__((ext_vector_type(4)));
typedef f16 f16x2 __attribute__((ext_vector_type(2)));
typedef float f32x4 __attribute__((ext_vector_type(4)));

constexpr int NB = 64, NP = 196, NE = 2048, NA = 512, ND = 512, NV = 10000;
constexpr int NT_CAP = 21, NTD = 20;
constexpr int KC = 3072;   // xcat K: 512 emb + 2048 awe + 512 h
constexpr int LDT = 40;    // LDS row stride (f16) for legacy kernels
constexpr int LDK = 72;    // LDS row stride (f16) for BK=64 tiles (pad 8)

// ---- workspace byte offsets ----
constexpr size_t OFF_ATT1   = 0;           // f16 [12544][512]
constexpr size_t OFF_DAW    = 12845056;    // f16 [512][512]
constexpr size_t OFF_FBW    = 13369344;    // f16 [2048][512]
constexpr size_t OFF_EAW    = 15466496;    // f16 [512][2048]   (preamble only)
constexpr size_t OFF_IHW    = 17563648;    // f16 [512][2048]   (preamble only)
constexpr size_t OFF_ICW    = 19660800;    // f16 [512][2048]   (preamble only)
constexpr size_t OFF_FCW    = 15466496;    // f16 [10048][512]  ALIASES eaW/ihW/icW
constexpr size_t OFF_WCAT   = 25755648;    // f16 [2048][3072]  rows r = d*4+g
constexpr size_t OFF_MEAN16 = 38338560;    // f16 [64][2048]
constexpr size_t OFF_H16    = 38600704;    // f16 [64][512]
constexpr size_t OFF_HNEW16 = 38666240;    // f16 [64][512]
constexpr size_t OFF_C      = 38731776;    // f32 [64][512]
constexpr size_t OFF_ATT2   = 38862848;    // f32 [64][512]
constexpr size_t OFF_GATE   = 38993920;    // f32 [64][2048]
constexpr size_t OFF_ALPHA  = 39518208;    // f32 [64][200]
constexpr size_t OFF_XCAT   = 39569408;    // f16 [64][3072]
constexpr size_t OFF_INT    = 39962624;    // perm/declen/caps (8 KB)
constexpr size_t OFF_BCAT   = 39970816;    // f32 [2048] combined lstm bias, permuted
constexpr size_t OFF_ENC16  = 39979008;    // f16 [64][196][2048] (optional)
constexpr size_t FULL_BYTES = 91359232;
constexpr size_t OFF_HSEQ   = FULL_BYTES;  // f16 [20][64][512] (optional)
constexpr size_t FULL2_BYTES = FULL_BYTES + (size_t)NTD * NB * ND * 2;  // 92669952
constexpr size_t OFF_HWHH   = FULL2_BYTES;             // f32 [64][2048]   524288 B
constexpr size_t OFF_EMBW   = OFF_HWHH + 524288;       // f32 [1280][2048] 10485760 B
constexpr size_t OFF_EMBS   = OFF_EMBW + 10485760;     // f16 [1280][512]  1310720 B
constexpr size_t FULL3_BYTES = OFF_EMBS + 1310720;     // 104990720

__device__ __forceinline__ float sigmoidf_(float x) { return 1.0f / (1.0f + expf(-x)); }

// f16x8 dot accumulate into f32 (uses v_dot2 when available)
__device__ __forceinline__ float dot8_(const f16* __restrict__ a,
                                       const f16* __restrict__ b, float s) {
  const f16x8 av = *(const f16x8*)a;
  const f16x8 bv = *(const f16x8*)b;
#if __has_builtin(__builtin_amdgcn_fdot2)
#pragma unroll
  for (int j = 0; j < 4; ++j) {
    f16x2 a2, b2;
    a2[0] = av[j * 2]; a2[1] = av[j * 2 + 1];
    b2[0] = bv[j * 2]; b2[1] = bv[j * 2 + 1];
    s = __builtin_amdgcn_fdot2(a2, b2, s, false);
  }
#else
#pragma unroll
  for (int j = 0; j < 8; ++j) s += (float)av[j] * (float)bv[j];
#endif
  return s;
}

// stage 64 rows x 32 k of f16 into LDS (256 threads, 16 B each)
__device__ __forceinline__ void stage16(const f16* __restrict__ src, int lda, int k0,
                                        f16* __restrict__ lds, int tid) {
  const int row = tid >> 2, seg = tid & 3;
  *(f16x8*)&lds[row * LDT + seg * 8] =
      *(const f16x8*)&src[(size_t)row * lda + k0 + seg * 8];
}

// convert 8 consecutive fp32 -> 8 f16 at dst
__device__ __forceinline__ void cvt8(const float* __restrict__ p, f16* __restrict__ dst) {
  const float4 a = *(const float4*)p;
  const float4 b = *(const float4*)(p + 4);
  f16x8 v;
  v[0] = (f16)a.x; v[1] = (f16)a.y; v[2] = (f16)a.z; v[3] = (f16)a.w;
  v[4] = (f16)b.x; v[5] = (f16)b.y; v[6] = (f16)b.z; v[7] = (f16)b.w;
  *(f16x8*)dst = v;
}

// Barrier-free wave GEMM: 64m x 16n tile, equal A/B stride K.
__device__ __forceinline__ void wave_gemm64(const f16* __restrict__ A,
                                            const f16* __restrict__ Brow, int K,
                                            int kbeg, int kend,
                                            int col, int quad, f32x4* acc) {
  for (int k0 = kbeg; k0 < kend; k0 += 32) {
    const int kk = k0 + quad * 8;
    const f16x8 b = *(const f16x8*)&Brow[(size_t)col * K + kk];
#pragma unroll
    for (int mt = 0; mt < 4; ++mt) {
      const f16x8 a = *(const f16x8*)&A[(size_t)(mt * 16 + col) * K + kk];
      acc[mt] = __builtin_amdgcn_mfma_f32_16x16x32_f16(a, b, acc[mt], 0, 0, 0);
    }
  }
}

// Strided variant: separate A/B leading dims, MT m-tiles.
template <int MT>
__device__ __forceinline__ void wave_gemm_s(const f16* __restrict__ A, int lda,
                                            const f16* __restrict__ Brow, int ldb,
                                            int kbeg, int kend,
                                            int col, int quad, f32x4* acc) {
  for (int k0 = kbeg; k0 < kend; k0 += 32) {
    const int kk = k0 + quad * 8;
    const f16x8 b = *(const f16x8*)&Brow[(size_t)col * ldb + kk];
#pragma unroll
    for (int mt = 0; mt < MT; ++mt) {
      const f16x8 a = *(const f16x8*)&A[(size_t)(mt * 16 + col) * lda + kk];
      acc[mt] = __builtin_amdgcn_mfma_f32_16x16x32_f16(a, b, acc[mt], 0, 0, 0);
    }
  }
}

// ---------------------------------------------------------------------------
// K1: stable descending argsort + gathered caps/declen/sortind outputs.
// ---------------------------------------------------------------------------
__global__ void k_sort(const int* __restrict__ cap_len, const int* __restrict__ caps,
                       int* __restrict__ perm, int* __restrict__ declen,
                       int* __restrict__ caps_sorted,
                       float* __restrict__ out_caps, float* __restrict__ out_declen,
                       float* __restrict__ out_sortind) {
  __shared__ int cl[NB];
  __shared__ int pr[NB];
  const int i = threadIdx.x;
  int c = cap_len[i];
  if (c < 1) c = 1;
  cl[i] = c;
  __syncthreads();
  int rank = 0;
  for (int j = 0; j < NB; ++j) {
    const int cj = cl[j];
    if (cj > c || (cj == c && j < i)) rank++;
  }
  pr[rank] = i;
  __syncthreads();
  const int src = pr[i];
  perm[i] = src;
  const int dl = cl[src] - 1;
  declen[i] = dl;
  out_declen[i] = (float)dl;
  out_sortind[i] = (float)src;
  for (int j = 0; j < NT_CAP; ++j) {
    const int v = caps[src * NT_CAP + j];
    caps_sorted[i * NT_CAP + j] = v;
    out_caps[i * NT_CAP + j] = (float)v;
  }
}

// ---------------------------------------------------------------------------
// K2: transpose-convert fp32 [K][Nsrc] (K-major) -> f16 [N][K]; zero if n>=Nsrc.
// ---------------------------------------------------------------------------
__global__ __launch_bounds__(256) void k_tconv(const float* __restrict__ src,
                                               f16* __restrict__ dst, int K, int Nsrc) {
  __shared__ float tile[32][33];
  const int n0 = blockIdx.x * 32, k0 = blockIdx.y * 32;
  const int tid = threadIdx.x;
  const int a = tid & 31, q = tid >> 5;
#pragma unroll
  for (int r = 0; r < 4; ++r) {
    const int kl = q * 4 + r;
    tile[a][kl] = (n0 + a < Nsrc) ? src[(size_t)(k0 + kl) * Nsrc + n0 + a] : 0.0f;
  }
  __syncthreads();
#pragma unroll
  for (int r = 0; r < 4; ++r) {
    const int nl = q * 4 + r;
    dst[(size_t)(n0 + nl) * K + k0 + a] = (f16)tile[nl][a];
  }
}

// K2f3: three K=2048/Nsrc=512 tconvs in one launch. grid (16, 64, 3).
__global__ __launch_bounds__(256) void k_tconv3(const float* __restrict__ s0, f16* d0,
                                                const float* __restrict__ s1, f16* d1,
                                                const float* __restrict__ s2, f16* d2) {
  __shared__ float tile[32][33];
  const float* src = (blockIdx.z == 0) ? s0 : (blockIdx.z == 1) ? s1 : s2;
  f16* dst = (blockIdx.z == 0) ? d0 : (blockIdx.z == 1) ? d1 : d2;
  const int n0 = blockIdx.x * 32, k0 = blockIdx.y * 32;
  const int tid = threadIdx.x;
  const int a = tid & 31, q = tid >> 5;
#pragma unroll
  for (int r = 0; r < 4; ++r) {
    const int kl = q * 4 + r;
    tile[a][kl] = src[(size_t)(k0 + kl) * 512 + n0 + a];
  }
  __syncthreads();
#pragma unroll
  for (int r = 0; r < 4; ++r) {
    const int nl = q * 4 + r;
    dst[(size_t)(n0 + nl) * 2048 + k0 + a] = (f16)tile[nl][a];
  }
}

// K2f2: dec_att (16 x-tiles) + f_beta (64 x-tiles), K=512. grid (80, 16).
__global__ __launch_bounds__(256) void k_tconv2b(const float* __restrict__ sd, f16* dd,
                                                 const float* __restrict__ sf, f16* df) {
  __shared__ float tile[32][33];
  const bool is_d = blockIdx.x < 16;
  const float* src = is_d ? sd : sf;
  f16* dst = is_d ? dd : df;
  const int nsrc = is_d ? 512 : 2048;
  const int n0 = (is_d ? blockIdx.x : (blockIdx.x - 16)) * 32, k0 = blockIdx.y * 32;
  const int tid = threadIdx.x;
  const int a = tid & 31, q = tid >> 5;
#pragma unroll
  for (int r = 0; r < 4; ++r) {
    const int kl = q * 4 + r;
    tile[a][kl] = src[(size_t)(k0 + kl) * nsrc + n0 + a];
  }
  __syncthreads();
#pragma unroll
  for (int r = 0; r < 4; ++r) {
    const int nl = q * 4 + r;
    dst[(size_t)(n0 + nl) * 512 + k0 + a] = (f16)tile[nl][a];
  }
}

// ---------------------------------------------------------------------------
// K2b: permuted Wcat: row r = d*4+g <-> original n = g*512+d.
// ---------------------------------------------------------------------------
__global__ __launch_bounds__(256) void k_cvt_wcat2(const float* __restrict__ Wih,
                                                   const float* __restrict__ Whh,
                                                   const float* __restrict__ bih,
                                                   const float* __restrict__ bhh,
                                                   f16* __restrict__ Wcat2,
                                                   float* __restrict__ bcat) {
  const int r = blockIdx.x;
  const int d = r >> 2, g = r & 3;
  const int n = g * 512 + d;
  for (int k = threadIdx.x; k < KC; k += 256) {
    const float v = (k < 2560) ? Wih[(size_t)n * 2560 + k] : Whh[(size_t)n * 512 + (k - 2560)];
    Wcat2[(size_t)r * KC + k] = (f16)v;
  }
  if (threadIdx.x == 0) bcat[r] = bih[n] + bhh[n];
}

// ---------------------------------------------------------------------------
// K3 (!full): mean over P of sorted encoder rows -> mean16. grid (4, 64).
// ---------------------------------------------------------------------------
__global__ __launch_bounds__(256) void k_mean(const float* __restrict__ enc,
                                              const int* __restrict__ perm,
                                              f16* __restrict__ mean16) {
  const int b = blockIdx.y;
  const int c0 = blockIdx.x * 512 + threadIdx.x * 2;
  const float* base = enc + (size_t)perm[b] * NP * NE + c0;
  float a0 = 0.0f, a1 = 0.0f;
  for (int p = 0; p < NP; ++p) {
    const float2 v = *(const float2*)&base[(size_t)p * NE];
    a0 += v.x; a1 += v.y;
  }
  mean16[(size_t)b * NE + c0] = (f16)(a0 * (1.0f / (float)NP));
  mean16[(size_t)b * NE + c0 + 1] = (f16)(a1 * (1.0f / (float)NP));
}

// K3b (full): mean from enc16 (f16, already permuted).
__global__ __launch_bounds__(256) void k_mean16(const f16* __restrict__ enc16,
                                                f16* __restrict__ mean16) {
  const int b = blockIdx.y;
  const int c0 = blockIdx.x * 512 + threadIdx.x * 2;
  const f16* base = enc16 + (size_t)b * NP * NE + c0;
  float a0 = 0.0f, a1 = 0.0f;
  for (int p = 0; p < NP; ++p) {
    const f16x2 v = *(const f16x2*)&base[(size_t)p * NE];
    a0 += (float)v[0]; a1 += (float)v[1];
  }
  mean16[(size_t)b * NE + c0] = (f16)(a0 * (1.0f / (float)NP));
  mean16[(size_t)b * NE + c0 + 1] = (f16)(a1 * (1.0f / (float)NP));
}

// ---------------------------------------------------------------------------
// K4 (FULL only): enc16[b][p][c] = f16(enc[perm[b]][p][c]). grid (196, 64).
// ---------------------------------------------------------------------------
__global__ __launch_bounds__(256) void k_enc_cvt(const float* __restrict__ enc,
                                                 const int* __restrict__ perm,
                                                 f16* __restrict__ enc16) {
  const int p = blockIdx.x, b = blockIdx.y;
  const float* src = enc + ((size_t)perm[b] * NP + p) * NE;
  f16* dst = enc16 + ((size_t)b * NP + p) * NE;
  const int i0 = threadIdx.x * 8;
  cvt8(src + i0, dst + i0);
}

// ---------------------------------------------------------------------------
// K4b (full3): embs16[t][b][e] = f16(emb[caps_s[b][t]][e]). grid (20, 64).
// ---------------------------------------------------------------------------
__global__ __launch_bounds__(256) void k_embs(const float* __restrict__ emb,
                                              const int* __restrict__ caps_s,
                                              f16* __restrict__ embs16) {
  const int t = blockIdx.x, b = blockIdx.y;
  const int cap = caps_s[b * NT_CAP + t];
  const int i0 = threadIdx.x * 2;
  const float2 v = *(const float2*)(emb + (size_t)cap * 512 + i0);
  f16x2 ev; ev[0] = (f16)v.x; ev[1] = (f16)v.y;
  *(f16x2*)&embs16[((size_t)t * NB + b) * 512 + i0] = ev;
}

// ---------------------------------------------------------------------------
// K4c (full3): embw = embs16 @ Wcat2[:, 0:512]^T. M=1280, N=2048, K=512.
// ---------------------------------------------------------------------------
__global__ __launch_bounds__(256) void k_embw(const f16* __restrict__ embs16,
                                              const f16* __restrict__ Wcat2,
                                              float* __restrict__ embw) {
  __shared__ __align__(16) f16 lA[256 * LDK];
  __shared__ __align__(16) f16 lB[64 * LDK];
  const int n0 = blockIdx.x * 64, m0 = blockIdx.y * 256;
  const int tid = threadIdx.x, lane = tid & 63, wv = tid >> 6;
  const int col = lane & 15, quad = lane >> 4;
  const f16* gA = embs16 + (size_t)(m0 + tid) * 512;
  const f16* gB = Wcat2 + (size_t)(n0 + (tid >> 2)) * KC + (tid & 3) * 16;
  f16* wA = &lA[tid * LDK];
  f16* wB = &lB[(tid >> 2) * LDK + (tid & 3) * 16];
  f32x4 acc[4][4] = {};
  for (int k0 = 0; k0 < 512; k0 += 64) {
#pragma unroll
    for (int u = 0; u < 8; ++u)
      *(f16x8*)(wA + u * 8) = *(const f16x8*)(gA + k0 + u * 8);
    *(f16x8*)(wB)     = *(const f16x8*)(gB + k0);
    *(f16x8*)(wB + 8) = *(const f16x8*)(gB + k0 + 8);
    __syncthreads();
#pragma unroll
    for (int kh = 0; kh < 2; ++kh) {
      f16x8 a[4], b[4];
#pragma unroll
      for (int i = 0; i < 4; ++i)
        a[i] = *(const f16x8*)&lA[(wv * 64 + i * 16 + col) * LDK + kh * 32 + quad * 8];
#pragma unroll
      for (int j = 0; j < 4; ++j)
        b[j] = *(const f16x8*)&lB[(j * 16 + col) * LDK + kh * 32 + quad * 8];
#pragma unroll
      for (int i = 0; i < 4; ++i)
#pragma unroll
        for (int j = 0; j < 4; ++j)
          acc[i][j] = __builtin_amdgcn_mfma_f32_16x16x32_f16(a[i], b[j], acc[i][j], 0, 0, 0);
    }
    __syncthreads();
  }
#pragma unroll
  for (int j = 0; j < 4; ++j) {
    const int n = n0 + j * 16 + col;
#pragma unroll
    for (int i = 0; i < 4; ++i)
#pragma unroll
      for (int rr = 0; rr < 4; ++rr) {
        const int r = m0 + wv * 64 + i * 16 + quad * 4 + rr;
        embw[(size_t)r * NE + n] = acc[i][j][rr];
      }
  }
}

// ---------------------------------------------------------------------------
// K5: h0/c0 = tanh(mean @ W + b), barrier-free direct MFMA. grid (16, 2).
// ---------------------------------------------------------------------------
__global__ __launch_bounds__(256) void k_init_mfma(const f16* __restrict__ mean16,
                                                   const f16* __restrict__ ihWt,
                                                   const f16* __restrict__ icWt,
                                                   const float* __restrict__ ihb,
                                                   const float* __restrict__ icb,
                                                   f16* __restrict__ h16,
                                                   float* __restrict__ cst) {
  const int which = blockIdx.y;
  const f16* Wt = which ? icWt : ihWt;
  const float* bias = which ? icb : ihb;
  const int tid = threadIdx.x, lane = tid & 63, wv = tid >> 6;
  const int col = lane & 15, quad = lane >> 4;
  const int nt = blockIdx.x * 4 + wv;  // 0..31
  f32x4 acc[4] = {};
  wave_gemm64(mean16, Wt + (size_t)nt * 16 * NE, NE, 0, NE, col, quad, acc);
  const int n = nt * 16 + col;
#pragma unroll
  for (int mt = 0; mt < 4; ++mt) {
#pragma unroll
    for (int rr = 0; rr < 4; ++rr) {
      const int m = mt * 16 + quad * 4 + rr;
      const float v = tanhf(acc[mt][rr] + bias[n]);
      if (which == 0) h16[(size_t)m * ND + n] = (f16)v;
      else            cst[(size_t)m * ND + n] = v;
    }
  }
}

// ---------------------------------------------------------------------------
// K6 (!full fallback): att1 = enc @ enc_att_W + b. grid (4, 196), BK=32.
// ---------------------------------------------------------------------------
template <bool E16>
__global__ __launch_bounds__(256) void k_att1_mfma(const float* __restrict__ encf,
                                                   const f16* __restrict__ enc16,
                                                   const int* __restrict__ perm,
                                                   const f16* __restrict__ eaWt,
                                                   const float* __restrict__ eab,
                                                   f16* __restrict__ att1) {
  __shared__ __align__(16) f16 lA[64 * LDT];
  __shared__ __align__(16) f16 lB[128 * LDT];
  __shared__ int rowoff[64];
  const int r0 = blockIdx.y * 64;
  const int n0 = blockIdx.x * 128;
  const int tid = threadIdx.x, lane = tid & 63, wv = tid >> 6;
  const int col = lane & 15, quad = lane >> 4;
  if (!E16) {
    if (tid < 64) {
      const int r = r0 + tid;
      const int b = r / NP, p = r - b * NP;
      rowoff[tid] = (perm[b] * NP + p) * NE;
    }
    __syncthreads();
  }
  f32x4 acc[8] = {};
  for (int k0 = 0; k0 < NE; k0 += 32) {
    if (E16) {
      stage16(enc16 + (size_t)r0 * NE, NE, k0, lA, tid);
    } else {
      const int row = tid >> 2, seg = tid & 3;
      cvt8(encf + (size_t)rowoff[row] + k0 + seg * 8, &lA[row * LDT + seg * 8]);
    }
    {
      const int row0 = tid >> 2, seg = tid & 3;
#pragma unroll
      for (int u = 0; u < 2; ++u) {
        const int row = row0 + 64 * u;
        *(f16x8*)&lB[row * LDT + seg * 8] =
            *(const f16x8*)&eaWt[(size_t)(n0 + row) * NE + k0 + seg * 8];
      }
    }
    __syncthreads();
    const f16x8 a = *(const f16x8*)&lA[(wv * 16 + col) * LDT + quad * 8];
#pragma unroll
    for (int ns = 0; ns < 8; ++ns) {
      const f16x8 b = *(const f16x8*)&lB[(ns * 16 + col) * LDT + quad * 8];
      acc[ns] = __builtin_amdgcn_mfma_f32_16x16x32_f16(a, b, acc[ns], 0, 0, 0);
    }
    __syncthreads();
  }
#pragma unroll
  for (int ns = 0; ns < 8; ++ns) {
    const int n = n0 + ns * 16 + col;
#pragma unroll
    for (int rr = 0; rr < 4; ++rr) {
      const int r = r0 + wv * 16 + quad * 4 + rr;
      att1[(size_t)r * NA + n] = (f16)(acc[ns][rr] + eab[n]);
    }
  }
}

// ---------------------------------------------------------------------------
// K6v3 (full): att1 GEMM, BM=128, BN=128, BK=64, wave=64x64 (32 MFMA/K-iter).
// grid (98, 4). LDS 36.9 KB.
// ---------------------------------------------------------------------------
__global__ __launch_bounds__(256) void k_att1_v3(const f16* __restrict__ enc16,
                                                 const f16* __restrict__ eaWt,
                                                 const float* __restrict__ eab,
                                                 f16* __restrict__ att1) {
  __shared__ __align__(16) f16 lA[128 * LDK];
  __shared__ __align__(16) f16 lB[128 * LDK];
  const int r0 = blockIdx.x * 128, n0 = blockIdx.y * 128;
  const int tid = threadIdx.x, lane = tid & 63, wv = tid >> 6;
  const int col = lane & 15, quad = lane >> 4;
  const int wr = wv >> 1, wc = wv & 1;  // wave quadrant: 64m x 64n
  const int srow = tid >> 1, sseg = (tid & 1) * 32;
  const f16* gA = enc16 + (size_t)(r0 + srow) * NE + sseg;
  const f16* gB = eaWt + (size_t)(n0 + srow) * NE + sseg;
  f16* wA = &lA[srow * LDK + sseg];
  f16* wB = &lB[srow * LDK + sseg];
  f32x4 acc[4][4] = {};
  for (int k0 = 0; k0 < NE; k0 += 64) {
#pragma unroll
    for (int u = 0; u < 4; ++u) {
      *(f16x8*)(wA + u * 8) = *(const f16x8*)(gA + k0 + u * 8);
      *(f16x8*)(wB + u * 8) = *(const f16x8*)(gB + k0 + u * 8);
    }
    __syncthreads();
#pragma unroll
    for (int kh = 0; kh < 2; ++kh) {
      f16x8 a[4], b[4];
#pragma unroll
      for (int i = 0; i < 4; ++i)
        a[i] = *(const f16x8*)&lA[(wr * 64 + i * 16 + col) * LDK + kh * 32 + quad * 8];
#pragma unroll
      for (int j = 0; j < 4; ++j)
        b[j] = *(const f16x8*)&lB[(wc * 64 + j * 16 + col) * LDK + kh * 32 + quad * 8];
#pragma unroll
      for (int i = 0; i < 4; ++i)
#pragma unroll
        for (int j = 0; j < 4; ++j)
          acc[i][j] = __builtin_amdgcn_mfma_f32_16x16x32_f16(a[i], b[j], acc[i][j], 0, 0, 0);
    }
    __syncthreads();
  }
#pragma unroll
  for (int j = 0; j < 4; ++j) {
    const int n = n0 + wc * 64 + j * 16 + col;
    const float bv = eab[n];
#pragma unroll
    for (int i = 0; i < 4; ++i)
#pragma unroll
      for (int rr = 0; rr < 4; ++rr) {
        const int r = r0 + wr * 64 + i * 16 + quad * 4 + rr;
        att1[(size_t)r * NA + n] = (f16)(acc[i][j][rr] + bv);
      }
  }
}

// ---------------------------------------------------------------------------
// K-STEPS2 (full3 + cooperative): 20-step loop, 2 grid.syncs per step.
// ---------------------------------------------------------------------------
struct Step2Params {
  f16* h16;
  const f16* daWt; const float* dab;
  const f16* fbWt; const float* fbb;
  const f16* Wcat2; const float* bcat;
  const f16* att1; const float* fullW;
  const f16* enc16;
  const float* embw;
  const int* declen;
  float* out_alphas;
  f16* xcat;
  float* cst;
  f16* hseq;
};

__global__ __launch_bounds__(512, 2) void k_steps2(Step2Params P) {
  cg::grid_group grid = cg::this_grid();
  __shared__ float S[4096];  // 16 KB, reused across phases
  // Phase AB layout:
  float* att2L = S;                  // [512]
  float* eL    = S + 512;            // [200]
  float* alL   = S + 712;            // [200]
  float* redL  = S + 912;            // [2]
  f16*   hL    = (f16*)(S + 1024);   // [512] f16 (256 floats)
  float* partL = S + 1280;           // [1024]
  const int tid = threadIdx.x, lane = tid & 63, wv = tid >> 6;
  const int col = lane & 15, quad = lane >> 4;
  const int bid = blockIdx.x, nblk = gridDim.x;

  for (int t = 0; t < NTD; ++t) {
    // ===== Phase AB: per (b, q): att2 + logits + softmax + awe + gate ======
    for (int task = bid; task < 256; task += nblk) {
      const int b = task >> 2, q = task & 3;
      // 1. h[b] -> LDS
      if (tid < 64)
        ((f16x8*)hL)[tid] = ((const f16x8*)(P.h16 + (size_t)b * ND))[tid];
      __syncthreads();
      // 2. att2[n] = dot(h, daWt[n]) + dab[n]  (one col per thread)
      {
        const f16* wrow = P.daWt + (size_t)tid * ND;
        float s = 0.0f;
        for (int k = 0; k < ND; k += 8) s = dot8_(&hL[k], &wrow[k], s);
        att2L[tid] = s + P.dab[tid];
      }
      __syncthreads();
      // 3. logits: wave per p
      {
        float a2r[8], fwr[8];
#pragma unroll
        for (int j = 0; j < 8; ++j) a2r[j] = att2L[lane * 8 + j];
        const float4* FW = (const float4*)(P.fullW + lane * 8);
        const float4 w0 = FW[0], w1 = FW[1];
        fwr[0] = w0.x; fwr[1] = w0.y; fwr[2] = w0.z; fwr[3] = w0.w;
        fwr[4] = w1.x; fwr[5] = w1.y; fwr[6] = w1.z; fwr[7] = w1.w;
        for (int p = wv; p < NP; p += 8) {
          const f16x8 row = *(const f16x8*)(P.att1 + ((size_t)b * NP + p) * NA + lane * 8);
          float acc = 0.0f;
#pragma unroll
          for (int j = 0; j < 8; ++j)
            acc += fmaxf((float)row[j] + a2r[j], 0.0f) * fwr[j];
#pragma unroll
          for (int off = 32; off > 0; off >>= 1) acc += __shfl_down(acc, off, 64);
          if (lane == 0) eL[p] = acc;
        }
      }
      __syncthreads();
      // 4. softmax (wave 0 butterfly)
      if (wv == 0) {
        const float v0 = eL[lane];
        const float v1 = eL[lane + 64];
        const float v2 = eL[lane + 128];
        const float v3 = (lane < 4) ? eL[192 + lane] : -INFINITY;
        float mx = fmaxf(fmaxf(v0, v1), fmaxf(v2, v3));
#pragma unroll
        for (int off = 32; off > 0; off >>= 1) mx = fmaxf(mx, __shfl_xor(mx, off, 64));
        float s = expf(v0 - mx) + expf(v1 - mx) + expf(v2 - mx) +
                  ((lane < 4) ? expf(v3 - mx) : 0.0f);
#pragma unroll
        for (int off = 32; off > 0; off >>= 1) s += __shfl_xor(s, off, 64);
        if (lane == 0) { redL[0] = mx; redL[1] = 1.0f / s; }
      }
      __syncthreads();
      if (tid < NP) {
        const float a = expf(eL[tid] - redL[0]) * redL[1];
        alL[tid] = a;
        if (q == 0) {
          const bool act = t < P.declen[b];
          P.out_alphas[((size_t)b * NTD + t) * NP + tid] = act ? a : 0.0f;
        }
      }
      __syncthreads();
      // 5. awe partials: 2 cols/thread over half the p-range
      {
        const int cl = (tid & 255) * 2, ph = tid >> 8;
        const int c = q * 512 + cl;
        const f16* base = P.enc16 + (size_t)b * NP * NE + c;
        float a0 = 0.0f, a1 = 0.0f;
        const int p0 = ph ? 98 : 0, p1 = ph ? 196 : 98;
        for (int p = p0; p < p1; ++p) {
          const f16x2 v = *(const f16x2*)&base[(size_t)p * NE];
          const float ap = alL[p];
          a0 += ap * (float)v[0]; a1 += ap * (float)v[1];
        }
        partL[ph * 512 + cl] = a0;
        partL[ph * 512 + cl + 1] = a1;
      }
      __syncthreads();
      // 6. combine + inline gate -> xcat mid; q==0 extra threads copy h tail
      if (tid < 256) {
        const int c2 = tid * 2;
        const float r0 = partL[c2] + partL[512 + c2];
        const float r1 = partL[c2 + 1] + partL[512 + c2 + 1];
        const int n = q * 512 + c2;
        const f16* w0 = P.fbWt + (size_t)n * ND;
        const f16* w1 = w0 + ND;
        float g0 = 0.0f, g1 = 0.0f;
        for (int k = 0; k < ND; k += 8) {
          g0 = dot8_(&hL[k], &w0[k], g0);
          g1 = dot8_(&hL[k], &w1[k], g1);
        }
        g0 = sigmoidf_(g0 + P.fbb[n]);
        g1 = sigmoidf_(g1 + P.fbb[n + 1]);
        f16x2 o; o[0] = (f16)(r0 * g0); o[1] = (f16)(r1 * g1);
        *(f16x2*)&P.xcat[(size_t)b * KC + 512 + n] = o;
      } else if (q == 0) {
        const int i0 = (tid - 256) * 2;
        *(f16x2*)&P.xcat[(size_t)b * KC + 2560 + i0] = *(const f16x2*)&hL[i0];
      }
      __syncthreads();
    }
    __threadfence();
    grid.sync();

    // ===== Phase C: xlstm GEMM K=512..3072 + cell epilogue ================
    for (int task = bid; task < 256; task += nblk) {
      const int nt = task >> 1, mh = task & 1;
      f32x4 acc[2] = {};
      wave_gemm_s<2>(P.xcat + (size_t)mh * 32 * KC, KC,
                     P.Wcat2 + (size_t)nt * 16 * KC, KC,
                     512 + wv * 320, 512 + wv * 320 + 320, col, quad, acc);
#pragma unroll
      for (int mt = 0; mt < 2; ++mt)
#pragma unroll
        for (int rr = 0; rr < 4; ++rr)
          S[wv * 512 + (mt * 4 + rr) * 64 + lane] = acc[mt][rr];
      __syncthreads();
      {
        float s = S[tid];
#pragma unroll
        for (int w = 1; w < 8; ++w) s += S[w * 512 + tid];
        S[tid] = s;
      }
      __syncthreads();
      if (tid < 128) {
        const int ml = tid >> 2, dl = tid & 3;
        const int m = mh * 32 + ml;
        const int d = nt * 4 + dl;
        const int mt = ml >> 4, qd = (ml >> 2) & 3, rr = ml & 3;
        float g4[4];
#pragma unroll
        for (int g = 0; g < 4; ++g) {
          const int cv = dl * 4 + g;
          const int r = nt * 16 + cv;
          g4[g] = S[(mt * 4 + rr) * 64 + qd * 16 + cv] + P.bcat[r] +
                  P.embw[((size_t)t * NB + m) * NE + r];
        }
        const float iv = sigmoidf_(g4[0]);
        const float fv = sigmoidf_(g4[1]);
        const float gv = tanhf(g4[2]);
        const float ov = sigmoidf_(g4[3]);
        const float cold = P.cst[(size_t)m * ND + d];
        const float cn = fv * cold + iv * gv;
        const float hn = ov * tanhf(cn);
        P.hseq[((size_t)t * NB + m) * ND + d] = (f16)hn;
        if (t < P.declen[m]) {
          P.cst[(size_t)m * ND + d] = cn;
          P.h16[(size_t)m * ND + d] = (f16)hn;
        }
      }
      __syncthreads();
    }
    __threadfence();
    grid.sync();
  }
}

// ---------------------------------------------------------------------------
// Fallback per-step kernels — unchanged from R7/R8.
// ---------------------------------------------------------------------------
__global__ __launch_bounds__(256) void k_hgemm_v2(const f16* __restrict__ h16,
                                                  const f16* __restrict__ daWt,
                                                  const float* __restrict__ dab,
                                                  const f16* __restrict__ fbWt,
                                                  const float* __restrict__ fbb,
                                                  float* __restrict__ att2,
                                                  float* __restrict__ gate) {
  __shared__ float R[2 * 64 * 16];
  const int tid = threadIdx.x, lane = tid & 63, wv = tid >> 6;
  const int col = lane & 15, quad = lane >> 4;
  const int sub = wv >> 1, kh = wv & 1;
  const int nt = blockIdx.x * 2 + sub;  // 0..159
  const bool is_att = nt < 32;
  const f16* Brow = is_att ? (daWt + (size_t)nt * 16 * ND)
                           : (fbWt + (size_t)(nt - 32) * 16 * ND);
  f32x4 acc[4] = {};
  wave_gemm64(h16, Brow, ND, kh * 256, kh * 256 + 256, col, quad, acc);
  if (kh) {
#pragma unroll
    for (int mt = 0; mt < 4; ++mt)
#pragma unroll
      for (int rr = 0; rr < 4; ++rr)
        R[(sub * 64 + lane) * 16 + mt * 4 + rr] = acc[mt][rr];
  }
  __syncthreads();
  if (kh) return;
#pragma unroll
  for (int mt = 0; mt < 4; ++mt)
#pragma unroll
    for (int rr = 0; rr < 4; ++rr)
      acc[mt][rr] += R[(sub * 64 + lane) * 16 + mt * 4 + rr];
  if (is_att) {
    const int n = nt * 16 + col;
#pragma unroll
    for (int mt = 0; mt < 4; ++mt)
#pragma unroll
      for (int rr = 0; rr < 4; ++rr) {
        const int m = mt * 16 + quad * 4 + rr;
        att2[(size_t)m * NA + n] = acc[mt][rr] + dab[n];
      }
  } else {
    const int n = (nt - 32) * 16 + col;
#pragma unroll
    for (int mt = 0; mt < 4; ++mt)
#pragma unroll
      for (int rr = 0; rr < 4; ++rr) {
        const int m = mt * 16 + quad * 4 + rr;
        gate[(size_t)m * NE + n] = sigmoidf_(acc[mt][rr] + fbb[n]);
      }
  }
}

template <bool E16>
__global__ __launch_bounds__(512) void k_attn_awe(const f16* __restrict__ att1,
                                                  const float* __restrict__ att2,
                                                  const float* __restrict__ fullW,
                                                  const int* __restrict__ declen, int t,
                                                  const float* __restrict__ encf,
                                                  const f16* __restrict__ enc16,
                                                  const int* __restrict__ perm,
                                                  const float* __restrict__ gate,
                                                  const float* __restrict__ emb,
                                                  const int* __restrict__ caps_s,
                                                  const f16* __restrict__ h16,
                                                  f16* __restrict__ xcat,
                                                  float* __restrict__ out_alphas) {
  const int b = blockIdx.x;
  const int tid = threadIdx.x, wv = tid >> 6, lane = tid & 63;
  __shared__ float e[200];
  __shared__ float al[200];
  __shared__ float red2[2];
  {
    float a2r[8], fwr[8];
    const float4* A2 = (const float4*)(att2 + (size_t)b * NA + lane * 8);
    const float4* FW = (const float4*)(fullW + lane * 8);
    const float4 q0 = A2[0], q1 = A2[1], w0 = FW[0], w1 = FW[1];
    a2r[0] = q0.x; a2r[1] = q0.y; a2r[2] = q0.z; a2r[3] = q0.w;
    a2r[4] = q1.x; a2r[5] = q1.y; a2r[6] = q1.z; a2r[7] = q1.w;
    fwr[0] = w0.x; fwr[1] = w0.y; fwr[2] = w0.z; fwr[3] = w0.w;
    fwr[4] = w1.x; fwr[5] = w1.y; fwr[6] = w1.z; fwr[7] = w1.w;
    for (int p = wv; p < NP; p += 8) {
      const f16x8 row = *(const f16x8*)(att1 + ((size_t)b * NP + p) * NA + lane * 8);
      float acc = 0.0f;
#pragma unroll
      for (int j = 0; j < 8; ++j) acc += fmaxf((float)row[j] + a2r[j], 0.0f) * fwr[j];
#pragma unroll
      for (int off = 32; off > 0; off >>= 1) acc += __shfl_down(acc, off, 64);
      if (lane == 0) e[p] = acc;
    }
  }
  __syncthreads();
  if (wv == 0) {
    const float v0 = e[lane];
    const float v1 = e[lane + 64];
    const float v2 = e[lane + 128];
    const float v3 = (lane < 4) ? e[192 + lane] : -INFINITY;
    float mx = fmaxf(fmaxf(v0, v1), fmaxf(v2, v3));
#pragma unroll
    for (int off = 32; off > 0; off >>= 1) mx = fmaxf(mx, __shfl_xor(mx, off, 64));
    float s = expf(v0 - mx) + expf(v1 - mx) + expf(v2 - mx) +
              ((lane < 4) ? expf(v3 - mx) : 0.0f);
#pragma unroll
    for (int off = 32; off > 0; off >>= 1) s += __shfl_xor(s, off, 64);
    if (lane == 0) { red2[0] = mx; red2[1] = 1.0f / s; }
  }
  __syncthreads();
  {
    const float mx = red2[0], inv = red2[1];
    if (tid < NP) {
      const float a = expf(e[tid] - mx) * inv;
      al[tid] = a;
      const bool act = t < declen[b];
      out_alphas[((size_t)b * NTD + t) * NP + tid] = act ? a : 0.0f;
    }
  }
  __syncthreads();
  {
    const int c = tid * 4;
    float a0 = 0.0f, a1 = 0.0f, a2 = 0.0f, a3 = 0.0f;
    if (E16) {
      const f16* base = enc16 + (size_t)b * NP * NE + c;
      for (int p = 0; p < NP; ++p) {
        const f16x4 v = *(const f16x4*)&base[(size_t)p * NE];
        const float ap = al[p];
        a0 += ap * (float)v[0]; a1 += ap * (float)v[1];
        a2 += ap * (float)v[2]; a3 += ap * (float)v[3];
      }
    } else {
      const float* base = encf + (size_t)perm[b] * NP * NE + c;
      for (int p = 0; p < NP; ++p) {
        const float4 v = *(const float4*)&base[(size_t)p * NE];
        const float ap = al[p];
        a0 += ap * v.x; a1 += ap * v.y; a2 += ap * v.z; a3 += ap * v.w;
      }
    }
    const float4 g = *(const float4*)&gate[(size_t)b * NE + c];
    f16x4 o;
    o[0] = (f16)(a0 * g.x); o[1] = (f16)(a1 * g.y);
    o[2] = (f16)(a2 * g.z); o[3] = (f16)(a3 * g.w);
    *(f16x4*)&xcat[(size_t)b * KC + 512 + c] = o;
  }
  if (tid < 256) {
    const int cap = caps_s[b * NT_CAP + t];
    const int i0 = tid * 2;
    const float2 v = *(const float2*)(emb + (size_t)cap * 512 + i0);
    f16x2 ev; ev[0] = (f16)v.x; ev[1] = (f16)v.y;
    *(f16x2*)&xcat[(size_t)b * KC + i0] = ev;
    *(f16x2*)&xcat[(size_t)b * KC + 2560 + i0] = *(const f16x2*)&h16[(size_t)b * ND + i0];
  }
}

__global__ __launch_bounds__(512) void k_xlstm_v2(const f16* __restrict__ xcat,
                                                  const f16* __restrict__ Wcat2,
                                                  const float* __restrict__ bcat,
                                                  const int* __restrict__ declen, int t,
                                                  float* __restrict__ cst,
                                                  f16* __restrict__ h16,
                                                  f16* __restrict__ hnew16,
                                                  f16* __restrict__ hseq) {
  __shared__ float R[8 * 64 * 16];
  const int nt = blockIdx.x;
  const int tid = threadIdx.x, lane = tid & 63, wv = tid >> 6;
  const int col = lane & 15, quad = lane >> 4;
  f32x4 acc[4] = {};
  wave_gemm64(xcat, Wcat2 + (size_t)nt * 16 * KC, KC, wv * 384, wv * 384 + 384,
              col, quad, acc);
#pragma unroll
  for (int mt = 0; mt < 4; ++mt)
#pragma unroll
    for (int rr = 0; rr < 4; ++rr)
      R[(wv * 64 + lane) * 16 + mt * 4 + rr] = acc[mt][rr];
  __syncthreads();
  {
    const int j0 = tid * 2;
#pragma unroll
    for (int j = 0; j < 2; ++j) {
      const int e2 = j0 + j;
      float s = R[e2];
#pragma unroll
      for (int w = 1; w < 8; ++w) s += R[w * 1024 + e2];
      R[e2] = s;
    }
  }
  __syncthreads();
  if (tid < 256) {
    const int m = tid >> 2, dl = tid & 3;
    const int mt = m >> 4, qd = (m >> 2) & 3, rr = m & 3;
    float g4[4];
#pragma unroll
    for (int g = 0; g < 4; ++g) {
      const int cv = dl * 4 + g;
      g4[g] = R[(qd * 16 + cv) * 16 + mt * 4 + rr] + bcat[nt * 16 + cv];
    }
    const int d = nt * 4 + dl;
    const float iv = sigmoidf_(g4[0]);
    const float fv = sigmoidf_(g4[1]);
    const float gv = tanhf(g4[2]);
    const float ov = sigmoidf_(g4[3]);
    const float cold = cst[(size_t)m * ND + d];
    const float cn = fv * cold + iv * gv;
    const float hn = ov * tanhf(cn);
    hnew16[(size_t)m * ND + d] = (f16)hn;
    if (hseq) hseq[((size_t)t * NB + m) * ND + d] = (f16)hn;
    if (t < declen[m]) {
      cst[(size_t)m * ND + d] = cn;
      h16[(size_t)m * ND + d] = (f16)hn;
    }
  }
}

__global__ __launch_bounds__(256) void k_fc_mfma(const f16* __restrict__ hnew16,
                                                 const f16* __restrict__ fcWt,
                                                 const float* __restrict__ fcb,
                                                 const int* __restrict__ declen, int t,
                                                 float* __restrict__ out_pred) {
  const int tid = threadIdx.x, lane = tid & 63, wv = tid >> 6;
  const int col = lane & 15, quad = lane >> 4;
  const int nt = blockIdx.x * 4 + wv;  // 0..627
  f32x4 acc[4] = {};
  wave_gemm64(hnew16, fcWt + (size_t)nt * 16 * ND, ND, 0, ND, col, quad, acc);
  const int n = nt * 16 + col;
  if (n < NV) {
    const float bv = fcb[n];
#pragma unroll
    for (int mt = 0; mt < 4; ++mt)
#pragma unroll
      for (int rr = 0; rr < 4; ++rr) {
        const int m = mt * 16 + quad * 4 + rr;
        const bool act = t < declen[m];
        out_pred[((size_t)m * NTD + t) * NV + n] = act ? (acc[mt][rr] + bv) : 0.0f;
      }
  }
}

// ---------------------------------------------------------------------------
// K11v2 (batch): preds for ALL steps from hseq. LDS-tiled GEMM grid (157, 5).
// ---------------------------------------------------------------------------
__global__ __launch_bounds__(256) void k_fc_v2(const f16* __restrict__ hseq,
                                               const f16* __restrict__ fcWt,
                                               const float* __restrict__ fcb,
                                               const int* __restrict__ declen,
                                               float* __restrict__ out_pred) {
  __shared__ __align__(16) f16 lA[256 * LDK];
  __shared__ __align__(16) f16 lB[64 * LDK];
  const int n0 = blockIdx.x * 64, m0 = blockIdx.y * 256;
  const int tid = threadIdx.x, lane = tid & 63, wv = tid >> 6;
  const int col = lane & 15, quad = lane >> 4;
  const f16* gA = hseq + (size_t)(m0 + tid) * ND;
  const f16* gB = fcWt + (size_t)(n0 + (tid >> 2)) * ND + (tid & 3) * 16;
  f16* wA = &lA[tid * LDK];
  f16* wB = &lB[(tid >> 2) * LDK + (tid & 3) * 16];
  f32x4 acc[4][4] = {};
  for (int k0 = 0; k0 < ND; k0 += 64) {
#pragma unroll
    for (int u = 0; u < 8; ++u)
      *(f16x8*)(wA + u * 8) = *(const f16x8*)(gA + k0 + u * 8);
    *(f16x8*)(wB)     = *(const f16x8*)(gB + k0);
    *(f16x8*)(wB + 8) = *(const f16x8*)(gB + k0 + 8);
    __syncthreads();
#pragma unroll
    for (int kh = 0; kh < 2; ++kh) {
      f16x8 a[4], b[4];
#pragma unroll
      for (int i = 0; i < 4; ++i)
        a[i] = *(const f16x8*)&lA[(wv * 64 + i * 16 + col) * LDK + kh * 32 + quad * 8];
#pragma unroll
      for (int j = 0; j < 4; ++j)
        b[j] = *(const f16x8*)&lB[(j * 16 + col) * LDK + kh * 32 + quad * 8];
#pragma unroll
      for (int i = 0; i < 4; ++i)
#pragma unroll
        for (int j = 0; j < 4; ++j)
          acc[i][j] = __builtin_amdgcn_mfma_f32_16x16x32_f16(a[i], b[j], acc[i][j], 0, 0, 0);
    }
    __syncthreads();
  }
#pragma unroll
  for (int j = 0; j < 4; ++j) {
    const int n = n0 + j * 16 + col;
    if (n >= NV) continue;
    const float bv = fcb[n];
#pragma unroll
    for (int i = 0; i < 4; ++i)
#pragma unroll
      for (int rr = 0; rr < 4; ++rr) {
        const int r = m0 + wv * 64 + i * 16 + quad * 4 + rr;
        const int tt = r >> 6, m = r & 63;
        const bool act = tt < declen[m];
        out_pred[((size_t)m * NTD + tt) * NV + n] = act ? (acc[i][j][rr] + bv) : 0.0f;
      }
  }
}

// full3 fallback per-step kernels (non-coop): hall/logits/awe/xlstm_v3
__global__ __launch_bounds__(256) void k_hall(const f16* __restrict__ h16,
                                              const f16* __restrict__ daWt,
                                              const float* __restrict__ dab,
                                              const f16* __restrict__ fbWt,
                                              const float* __restrict__ fbb,
                                              const f16* __restrict__ Wcat2,
                                              float* __restrict__ att2,
                                              float* __restrict__ gate,
                                              float* __restrict__ hwhh) {
  __shared__ float R[4 * 1024];
  const int nt = blockIdx.x;
  const int tid = threadIdx.x, lane = tid & 63, wv = tid >> 6;
  const int col = lane & 15, quad = lane >> 4;
  const f16* Brow; int ldb;
  if (nt < 32)       { Brow = daWt + (size_t)nt * 16 * ND; ldb = ND; }
  else if (nt < 160) { Brow = fbWt + (size_t)(nt - 32) * 16 * ND; ldb = ND; }
  else               { Brow = Wcat2 + (size_t)(nt - 160) * 16 * KC + 2560; ldb = KC; }
  f32x4 acc[4] = {};
  wave_gemm_s<4>(h16, ND, Brow, ldb, wv * 128, wv * 128 + 128, col, quad, acc);
#pragma unroll
  for (int mt = 0; mt < 4; ++mt)
#pragma unroll
    for (int rr = 0; rr < 4; ++rr)
      R[wv * 1024 + (mt * 4 + rr) * 64 + lane] = acc[mt][rr];
  __syncthreads();
#pragma unroll
  for (int j = 0; j < 4; ++j) {
    const int slot = tid * 4 + j;
    const float s = R[slot] + R[1024 + slot] + R[2048 + slot] + R[3072 + slot];
    const int c2 = slot >> 6;
    const int lane_s = slot & 63;
    const int mt = c2 >> 2, rr = c2 & 3;
    const int m = mt * 16 + (lane_s >> 4) * 4 + rr;
    const int nl = lane_s & 15;
    if (nt < 32) {
      const int n = nt * 16 + nl;
      att2[(size_t)m * NA + n] = s + dab[n];
    } else if (nt < 160) {
      const int n = (nt - 32) * 16 + nl;
      gate[(size_t)m * NE + n] = sigmoidf_(s + fbb[n]);
    } else {
      const int r = (nt - 160) * 16 + nl;
      hwhh[(size_t)m * NE + r] = s;
    }
  }
}

__global__ __launch_bounds__(512) void k_logits(const f16* __restrict__ att1,
                                                const float* __restrict__ att2,
                                                const float* __restrict__ fullW,
                                                const int* __restrict__ declen, int t,
                                                float* __restrict__ alpha_ws,
                                                float* __restrict__ out_alphas) {
  const int b = blockIdx.x;
  const int tid = threadIdx.x, wv = tid >> 6, lane = tid & 63;
  __shared__ float e[200];
  __shared__ float red2[2];
  {
    float a2r[8], fwr[8];
    const float4* A2 = (const float4*)(att2 + (size_t)b * NA + lane * 8);
    const float4* FW = (const float4*)(fullW + lane * 8);
    const float4 q0 = A2[0], q1 = A2[1], w0 = FW[0], w1 = FW[1];
    a2r[0] = q0.x; a2r[1] = q0.y; a2r[2] = q0.z; a2r[3] = q0.w;
    a2r[4] = q1.x; a2r[5] = q1.y; a2r[6] = q1.z; a2r[7] = q1.w;
    fwr[0] = w0.x; fwr[1] = w0.y; fwr[2] = w0.z; fwr[3] = w0.w;
    fwr[4] = w1.x; fwr[5] = w1.y; fwr[6] = w1.z; fwr[7] = w1.w;
    for (int p = wv; p < NP; p += 8) {
      const f16x8 row = *(const f16x8*)(att1 + ((size_t)b * NP + p) * NA + lane * 8);
      float acc = 0.0f;
#pragma unroll
      for (int j = 0; j < 8; ++j) acc += fmaxf((float)row[j] + a2r[j], 0.0f) * fwr[j];
#pragma unroll
      for (int off = 32; off > 0; off >>= 1) acc += __shfl_down(acc, off, 64);
      if (lane == 0) e[p] = acc;
    }
  }
  __syncthreads();
  if (wv == 0) {
    const float v0 = e[lane];
    const float v1 = e[lane + 64];
    const float v2 = e[lane + 128];
    const float v3 = (lane < 4) ? e[192 + lane] : -INFINITY;
    float mx = fmaxf(fmaxf(v0, v1), fmaxf(v2, v3));
#pragma unroll
    for (int off = 32; off > 0; off >>= 1) mx = fmaxf(mx, __shfl_xor(mx, off, 64));
    float s = expf(v0 - mx) + expf(v1 - mx) + expf(v2 - mx) +
              ((lane < 4) ? expf(v3 - mx) : 0.0f);
#pragma unroll
    for (int off = 32; off > 0; off >>= 1) s += __shfl_xor(s, off, 64);
    if (lane == 0) { red2[0] = mx; red2[1] = 1.0f / s; }
  }
  __syncthreads();
  if (tid < NP) {
    const float a = expf(e[tid] - red2[0]) * red2[1];
    alpha_ws[(size_t)b * NP + tid] = a;
    const bool act = t < declen[b];
    out_alphas[((size_t)b * NTD + t) * NP + tid] = act ? a : 0.0f;
  }
}

__global__ __launch_bounds__(256) void k_awe(const f16* __restrict__ enc16,
                                             const float* __restrict__ alpha_ws,
                                             const float* __restrict__ gate,
                                             f16* __restrict__ xcat) {
  const int b = blockIdx.x >> 2, q = blockIdx.x & 3;
  const int tid = threadIdx.x;
  __shared__ float al[NP];
  if (tid < NP) al[tid] = alpha_ws[(size_t)b * NP + tid];
  __syncthreads();
  const int c = q * 512 + tid * 2;
  const f16* base = enc16 + (size_t)b * NP * NE + c;
  float a0 = 0.0f, a1 = 0.0f, b0 = 0.0f, b1 = 0.0f;
  for (int p = 0; p < NP; p += 2) {
    const f16x2 v0 = *(const f16x2*)&base[(size_t)p * NE];
    const f16x2 v1 = *(const f16x2*)&base[(size_t)(p + 1) * NE];
    const float ap0 = al[p], ap1 = al[p + 1];
    a0 += ap0 * (float)v0[0]; a1 += ap0 * (float)v0[1];
    b0 += ap1 * (float)v1[0]; b1 += ap1 * (float)v1[1];
  }
  a0 += b0; a1 += b1;
  const float2 g = *(const float2*)&gate[(size_t)b * NE + c];
  f16x2 o; o[0] = (f16)(a0 * g.x); o[1] = (f16)(a1 * g.y);
  *(f16x2*)&xcat[(size_t)b * KC + 512 + c] = o;
}

__global__ __launch_bounds__(512) void k_xlstm_v3(const f16* __restrict__ xcat,
                                                  const f16* __restrict__ Wcat2,
                                                  const float* __restrict__ bcat,
                                                  const float* __restrict__ hwhh,
                                                  const float* __restrict__ embw,
                                                  const int* __restrict__ declen, int t,
                                                  float* __restrict__ cst,
                                                  f16* __restrict__ h16,
                                                  f16* __restrict__ hnew16,
                                                  f16* __restrict__ hseq) {
  __shared__ float R[8 * 512];
  const int nt = blockIdx.x >> 1, mh = blockIdx.x & 1;
  const int tid = threadIdx.x, lane = tid & 63, wv = tid >> 6;
  const int col = lane & 15, quad = lane >> 4;
  f32x4 acc[2] = {};
  wave_gemm_s<2>(xcat + (size_t)mh * 32 * KC, KC,
                 Wcat2 + (size_t)nt * 16 * KC, KC,
                 512 + wv * 256, 512 + wv * 256 + 256, col, quad, acc);
#pragma unroll
  for (int mt = 0; mt < 2; ++mt)
#pragma unroll
    for (int rr = 0; rr < 4; ++rr)
      R[wv * 512 + (mt * 4 + rr) * 64 + lane] = acc[mt][rr];
  __syncthreads();
  {
    float s = R[tid];
#pragma unroll
    for (int w = 1; w < 8; ++w) s += R[w * 512 + tid];
    R[tid] = s;
  }
  __syncthreads();
  if (tid < 128) {
    const int ml = tid >> 2, dl = tid & 3;
    const int m = mh * 32 + ml;
    const int d = nt * 4 + dl;
    const int mt = ml >> 4, qd = (ml >> 2) & 3, rr = ml & 3;
    float g4[4];
#pragma unroll
    for (int g = 0; g < 4; ++g) {
      const int cv = dl * 4 + g;
      const int r = nt * 16 + cv;
      const float s = R[(mt * 4 + rr) * 64 + qd * 16 + cv];
      g4[g] = s + bcat[r] + hwhh[(size_t)m * NE + r] +
              embw[((size_t)t * NB + m) * NE + r];
    }
    const float iv = sigmoidf_(g4[0]);
    const float fv = sigmoidf_(g4[1]);
    const float gv = tanhf(g4[2]);
    const float ov = sigmoidf_(g4[3]);
    const float cold = cst[(size_t)m * ND + d];
    const float cn = fv * cold + iv * gv;
    const float hn = ov * tanhf(cn);
    hnew16[(size_t)m * ND + d] = (f16)hn;
    hseq[((size_t)t * NB + m) * ND + d] = (f16)hn;
    if (t < declen[m]) {
      cst[(size_t)m * ND + d] = cn;
      h16[(size_t)m * ND + d] = (f16)hn;
    }
  }
}

}  // namespace

extern "C" void kernel_launch(void* const* d_in, const int* in_sizes, int n_in,
                              void* d_out, int out_size, void* d_ws, size_t ws_size,
                              hipStream_t stream) {
  const float* enc        = (const float*)d_in[0];
  const int*   caps       = (const int*)d_in[1];
  const int*   caplen     = (const int*)d_in[2];
  const float* emb        = (const float*)d_in[3];
  const float* enc_att_W  = (const float*)d_in[4];
  const float* enc_att_b  = (const float*)d_in[5];
  const float* dec_att_W  = (const float*)d_in[6];
  const float* dec_att_b  = (const float*)d_in[7];
  const float* full_att_W = (const float*)d_in[8];
  // d_in[9] full_att_b: shift-invariant under softmax, unused.
  const float* init_h_W   = (const float*)d_in[10];
  const float* init_h_b   = (const float*)d_in[11];
  const float* init_c_W   = (const float*)d_in[12];
  const float* init_c_b   = (const float*)d_in[13];
  const float* f_beta_W   = (const float*)d_in[14];
  const float* f_beta_b   = (const float*)d_in[15];
  const float* W_ih       = (const float*)d_in[16];
  const float* b_ih       = (const float*)d_in[17];
  const float* W_hh       = (const float*)d_in[18];
  const float* b_hh       = (const float*)d_in[19];
  const float* fc_W       = (const float*)d_in[20];
  const float* fc_b       = (const float*)d_in[21];

  char* ws = (char*)d_ws;
  f16*   att1   = (f16*)(ws + OFF_ATT1);
  f16*   daWt   = (f16*)(ws + OFF_DAW);
  f16*   fbWt   = (f16*)(ws + OFF_FBW);
  f16*   eaWt   = (f16*)(ws + OFF_EAW);
  f16*   ihWt   = (f16*)(ws + OFF_IHW);
  f16*   icWt   = (f16*)(ws + OFF_ICW);
  f16*   fcWt   = (f16*)(ws + OFF_FCW);   // aliases eaWt/ihWt/icWt (written after)
  f16*   Wcat2  = (f16*)(ws + OFF_WCAT);
  f16*   mean16 = (f16*)(ws + OFF_MEAN16);
  f16*   h16    = (f16*)(ws + OFF_H16);
  f16*   hnew16 = (f16*)(ws + OFF_HNEW16);
  float* cst    = (float*)(ws + OFF_C);
  float* att2   = (float*)(ws + OFF_ATT2);
  float* gate   = (float*)(ws + OFF_GATE);
  float* alpha  = (float*)(ws + OFF_ALPHA);
  f16*   xcat   = (f16*)(ws + OFF_XCAT);
  int*   wsi    = (int*)(ws + OFF_INT);
  int*   perm   = wsi;
  int*   declen = wsi + 64;
  int*   caps_s = wsi + 128;
  float* bcat   = (float*)(ws + OFF_BCAT);
  f16*   enc16  = (f16*)(ws + OFF_ENC16);
  float* hwhh   = (float*)(ws + OFF_HWHH);
  float* embw   = (float*)(ws + OFF_EMBW);
  f16*   embs16 = (f16*)(ws + OFF_EMBS);

  const bool full  = ws_size >= FULL_BYTES;
  const bool batch = ws_size >= FULL2_BYTES;
  const bool full3 = ws_size >= FULL3_BYTES;
  f16* hseq = batch ? (f16*)(ws + OFF_HSEQ) : (f16*)nullptr;

  // cooperative-launch capability check (host-side queries only; graph-safe)
  bool coop_ok = false;
  int coop_grid = 0;
  if (full3) {
    int dev = 0;
    if (hipGetDevice(&dev) == hipSuccess) {
      int coop = 0;
      hipDeviceGetAttribute(&coop, hipDeviceAttributeCooperativeLaunch, dev);
      if (coop) {
        int ncu = 0;
        hipDeviceGetAttribute(&ncu, hipDeviceAttributeMultiprocessorCount, dev);
        int maxb = 0;
        if (hipOccupancyMaxActiveBlocksPerMultiprocessor(
                &maxb, reinterpret_cast<const void*>(&k_steps2), 512, 0) == hipSuccess &&
            maxb >= 1 && ncu > 0) {
          coop_grid = maxb * ncu;
          if (coop_grid > 256) coop_grid = 256;
          coop_ok = coop_grid >= 64;
        }
      }
    }
  }

  float* out         = (float*)d_out;
  float* out_pred    = out;
  float* out_caps    = out_pred + (size_t)NB * NTD * NV;
  float* out_declen  = out_caps + (size_t)NB * NT_CAP;
  float* out_alphas  = out_declen + NB;
  float* out_sortind = out_alphas + (size_t)NB * NTD * NP;

  k_sort<<<1, 64, 0, stream>>>(caplen, caps, perm, declen, caps_s,
                               out_caps, out_declen, out_sortind);
  k_tconv3<<<dim3(16, 64, 3), 256, 0, stream>>>(enc_att_W, eaWt, init_h_W, ihWt,
                                                init_c_W, icWt);
  k_tconv2b<<<dim3(80, 16), 256, 0, stream>>>(dec_att_W, daWt, f_beta_W, fbWt);
  if (full) {
    k_enc_cvt<<<dim3(196, 64), 256, 0, stream>>>(enc, perm, enc16);
    k_mean16<<<dim3(4, 64), 256, 0, stream>>>(enc16, mean16);
  } else {
    k_mean<<<dim3(4, 64), 256, 0, stream>>>(enc, perm, mean16);
  }
  k_init_mfma<<<dim3(16, 2), 256, 0, stream>>>(mean16, ihWt, icWt, init_h_b, init_c_b,
                                               h16, cst);
  if (full)
    k_att1_v3<<<dim3(98, 4), 256, 0, stream>>>(enc16, eaWt, enc_att_b, att1);
  else
    k_att1_mfma<false><<<dim3(4, 196), 256, 0, stream>>>(enc, enc16, perm, eaWt,
                                                         enc_att_b, att1);
  // fcWt write ALIASES eaWt/ihWt/icWt — must come after k_init/k_att1 (stream order).
  k_tconv<<<dim3(314, 16), 256, 0, stream>>>(fc_W, fcWt, 512, NV);
  k_cvt_wcat2<<<2048, 256, 0, stream>>>(W_ih, W_hh, b_ih, b_hh, Wcat2, bcat);
  if (full3) {
    k_embs<<<dim3(NTD, NB), 256, 0, stream>>>(emb, caps_s, embs16);
    k_embw<<<dim3(32, 5), 256, 0, stream>>>(embs16, Wcat2, embw);
  }

  if (full3 && coop_ok) {
    Step2Params P;
    P.h16 = h16; P.daWt = daWt; P.dab = dec_att_b; P.fbWt = fbWt; P.fbb = f_beta_b;
    P.Wcat2 = Wcat2; P.bcat = bcat; P.att1 = att1; P.fullW = full_att_W;
    P.enc16 = enc16; P.embw = embw; P.declen = declen;
    P.out_alphas = out_alphas; P.xcat = xcat; P.cst = cst; P.hseq = hseq;
    void* args[] = { &P };
    hipLaunchCooperativeKernel(reinterpret_cast<const void*>(&k_steps2),
                               dim3(coop_grid), dim3(512), args, 0, stream);
    k_fc_v2<<<dim3(157, 5), 256, 0, stream>>>(hseq, fcWt, fc_b, declen, out_pred);
  } else if (full3) {
    for (int t = 0; t < NTD; ++t) {
      k_hall<<<288, 256, 0, stream>>>(h16, daWt, dec_att_b, fbWt, f_beta_b, Wcat2,
                                      att2, gate, hwhh);
      k_logits<<<NB, 512, 0, stream>>>(att1, att2, full_att_W, declen, t,
                                       alpha, out_alphas);
      k_awe<<<256, 256, 0, stream>>>(enc16, alpha, gate, xcat);
      k_xlstm_v3<<<256, 512, 0, stream>>>(xcat, Wcat2, bcat, hwhh, embw, declen, t,
                                          cst, h16, hnew16, hseq);
    }
    k_fc_v2<<<dim3(157, 5), 256, 0, stream>>>(hseq, fcWt, fc_b, declen, out_pred);
  } else {
    for (int t = 0; t < NTD; ++t) {
      k_hgemm_v2<<<80, 256, 0, stream>>>(h16, daWt, dec_att_b, fbWt, f_beta_b,
                                         att2, gate);
      if (full)
        k_attn_awe<true><<<NB, 512, 0, stream>>>(att1, att2, full_att_W, declen, t,
                                                 enc, enc16, perm, gate, emb, caps_s,
                                                 h16, xcat, out_alphas);
      else
        k_attn_awe<false><<<NB, 512, 0, stream>>>(att1, att2, full_att_W, declen, t,
                                                  enc, enc16, perm, gate, emb, caps_s,
                                                  h16, xcat, out_alphas);
      k_xlstm_v2<<<128, 512, 0, stream>>>(xcat, Wcat2, bcat, declen, t,
                                          cst, h16, hnew16, hseq);
      if (!batch)
        k_fc_mfma<<<157, 256, 0, stream>>>(hnew16, fcWt, fc_b, declen, t, out_pred);
    }
    if (batch)
      k_fc_v2<<<dim3(157, 5), 256, 0, stream>>>(hseq, fcWt, fc_b, declen, out_pred);
  }
}

// Round 6
// 1292.790 us; speedup vs baseline: 3.9569x; 3.9569x over previous
//
#include <hip/hip_runtime.h>
#include <hip/hip_cooperative_groups.h>
#include <cstddef>

// ---------------------------------------------------------------------------
// DecoderWithAttention forward — Round 10.
// vs R9 (5115 µs, REGRESSION): R9's inline att2/gate used per-thread row dots
// (uncoalesced: adjacent lanes 1KB apart -> 64 cache lines/instr, FETCH +430MB).
// R10 = 3-phase coop, all accesses coalesced:
//  P1 hall-lite (160 tasks): att2+gate via MFMA (R8's validated hall, minus
//     the Whh slice -- xlstm K covers it via xcat tail, validated in R9).
//  P2 (b,q)x256: logits (att2 from GLOBAL, coalesced) + softmax + awe +
//     gate from GLOBAL + h->xcat tail. Only redundancy: 4x att1[b] re-read
//     (coalesced, LLC-resident).
//  P3 xlstm K=512..3072 + cell epilogue (R9-validated).
// 3 grid.syncs/step (was 4). Fallback paths unchanged.
// ---------------------------------------------------------------------------

namespace cg = cooperative_groups;

namespace {

typedef _Float16 f16;
typedef f16 f16x8 __attribute__((ext_vector_type(8)));
typedef f16 f16x4 __attribute__((ext_vector_type(4)));
typedef f16 f16x2 __attribute__((ext_vector_type(2)));
typedef float f32x4 __attribute__((ext_vector_type(4)));

constexpr int NB = 64, NP = 196, NE = 2048, NA = 512, ND = 512, NV = 10000;
constexpr int NT_CAP = 21, NTD = 20;
constexpr int KC = 3072;   // xcat K: 512 emb + 2048 awe + 512 h
constexpr int LDT = 40;    // LDS row stride (f16) for legacy kernels
constexpr int LDK = 72;    // LDS row stride (f16) for BK=64 tiles (pad 8)

// ---- workspace byte offsets ----
constexpr size_t OFF_ATT1   = 0;           // f16 [12544][512]
constexpr size_t OFF_DAW    = 12845056;    // f16 [512][512]
constexpr size_t OFF_FBW    = 13369344;    // f16 [2048][512]
constexpr size_t OFF_EAW    = 15466496;    // f16 [512][2048]   (preamble only)
constexpr size_t OFF_IHW    = 17563648;    // f16 [512][2048]   (preamble only)
constexpr size_t OFF_ICW    = 19660800;    // f16 [512][2048]   (preamble only)
constexpr size_t OFF_FCW    = 15466496;    // f16 [10048][512]  ALIASES eaW/ihW/icW
constexpr size_t OFF_WCAT   = 25755648;    // f16 [2048][3072]  rows r = d*4+g
constexpr size_t OFF_MEAN16 = 38338560;    // f16 [64][2048]
constexpr size_t OFF_H16    = 38600704;    // f16 [64][512]
constexpr size_t OFF_HNEW16 = 38666240;    // f16 [64][512]
constexpr size_t OFF_C      = 38731776;    // f32 [64][512]
constexpr size_t OFF_ATT2   = 38862848;    // f32 [64][512]
constexpr size_t OFF_GATE   = 38993920;    // f32 [64][2048]
constexpr size_t OFF_ALPHA  = 39518208;    // f32 [64][200]
constexpr size_t OFF_XCAT   = 39569408;    // f16 [64][3072]
constexpr size_t OFF_INT    = 39962624;    // perm/declen/caps (8 KB)
constexpr size_t OFF_BCAT   = 39970816;    // f32 [2048] combined lstm bias, permuted
constexpr size_t OFF_ENC16  = 39979008;    // f16 [64][196][2048] (optional)
constexpr size_t FULL_BYTES = 91359232;
constexpr size_t OFF_HSEQ   = FULL_BYTES;  // f16 [20][64][512] (optional)
constexpr size_t FULL2_BYTES = FULL_BYTES + (size_t)NTD * NB * ND * 2;  // 92669952
constexpr size_t OFF_HWHH   = FULL2_BYTES;             // f32 [64][2048]   524288 B
constexpr size_t OFF_EMBW   = OFF_HWHH + 524288;       // f32 [1280][2048] 10485760 B
constexpr size_t OFF_EMBS   = OFF_EMBW + 10485760;     // f16 [1280][512]  1310720 B
constexpr size_t FULL3_BYTES = OFF_EMBS + 1310720;     // 104990720

__device__ __forceinline__ float sigmoidf_(float x) { return 1.0f / (1.0f + expf(-x)); }

// stage 64 rows x 32 k of f16 into LDS (256 threads, 16 B each)
__device__ __forceinline__ void stage16(const f16* __restrict__ src, int lda, int k0,
                                        f16* __restrict__ lds, int tid) {
  const int row = tid >> 2, seg = tid & 3;
  *(f16x8*)&lds[row * LDT + seg * 8] =
      *(const f16x8*)&src[(size_t)row * lda + k0 + seg * 8];
}

// convert 8 consecutive fp32 -> 8 f16 at dst
__device__ __forceinline__ void cvt8(const float* __restrict__ p, f16* __restrict__ dst) {
  const float4 a = *(const float4*)p;
  const float4 b = *(const float4*)(p + 4);
  f16x8 v;
  v[0] = (f16)a.x; v[1] = (f16)a.y; v[2] = (f16)a.z; v[3] = (f16)a.w;
  v[4] = (f16)b.x; v[5] = (f16)b.y; v[6] = (f16)b.z; v[7] = (f16)b.w;
  *(f16x8*)dst = v;
}

// Barrier-free wave GEMM: 64m x 16n tile, equal A/B stride K.
__device__ __forceinline__ void wave_gemm64(const f16* __restrict__ A,
                                            const f16* __restrict__ Brow, int K,
                                            int kbeg, int kend,
                                            int col, int quad, f32x4* acc) {
  for (int k0 = kbeg; k0 < kend; k0 += 32) {
    const int kk = k0 + quad * 8;
    const f16x8 b = *(const f16x8*)&Brow[(size_t)col * K + kk];
#pragma unroll
    for (int mt = 0; mt < 4; ++mt) {
      const f16x8 a = *(const f16x8*)&A[(size_t)(mt * 16 + col) * K + kk];
      acc[mt] = __builtin_amdgcn_mfma_f32_16x16x32_f16(a, b, acc[mt], 0, 0, 0);
    }
  }
}

// Strided variant: separate A/B leading dims, MT m-tiles.
template <int MT>
__device__ __forceinline__ void wave_gemm_s(const f16* __restrict__ A, int lda,
                                            const f16* __restrict__ Brow, int ldb,
                                            int kbeg, int kend,
                                            int col, int quad, f32x4* acc) {
  for (int k0 = kbeg; k0 < kend; k0 += 32) {
    const int kk = k0 + quad * 8;
    const f16x8 b = *(const f16x8*)&Brow[(size_t)col * ldb + kk];
#pragma unroll
    for (int mt = 0; mt < MT; ++mt) {
      const f16x8 a = *(const f16x8*)&A[(size_t)(mt * 16 + col) * lda + kk];
      acc[mt] = __builtin_amdgcn_mfma_f32_16x16x32_f16(a, b, acc[mt], 0, 0, 0);
    }
  }
}

// ---------------------------------------------------------------------------
// K1: stable descending argsort + gathered caps/declen/sortind outputs.
// ---------------------------------------------------------------------------
__global__ void k_sort(const int* __restrict__ cap_len, const int* __restrict__ caps,
                       int* __restrict__ perm, int* __restrict__ declen,
                       int* __restrict__ caps_sorted,
                       float* __restrict__ out_caps, float* __restrict__ out_declen,
                       float* __restrict__ out_sortind) {
  __shared__ int cl[NB];
  __shared__ int pr[NB];
  const int i = threadIdx.x;
  int c = cap_len[i];
  if (c < 1) c = 1;
  cl[i] = c;
  __syncthreads();
  int rank = 0;
  for (int j = 0; j < NB; ++j) {
    const int cj = cl[j];
    if (cj > c || (cj == c && j < i)) rank++;
  }
  pr[rank] = i;
  __syncthreads();
  const int src = pr[i];
  perm[i] = src;
  const int dl = cl[src] - 1;
  declen[i] = dl;
  out_declen[i] = (float)dl;
  out_sortind[i] = (float)src;
  for (int j = 0; j < NT_CAP; ++j) {
    const int v = caps[src * NT_CAP + j];
    caps_sorted[i * NT_CAP + j] = v;
    out_caps[i * NT_CAP + j] = (float)v;
  }
}

// ---------------------------------------------------------------------------
// K2: transpose-convert fp32 [K][Nsrc] (K-major) -> f16 [N][K]; zero if n>=Nsrc.
// ---------------------------------------------------------------------------
__global__ __launch_bounds__(256) void k_tconv(const float* __restrict__ src,
                                               f16* __restrict__ dst, int K, int Nsrc) {
  __shared__ float tile[32][33];
  const int n0 = blockIdx.x * 32, k0 = blockIdx.y * 32;
  const int tid = threadIdx.x;
  const int a = tid & 31, q = tid >> 5;
#pragma unroll
  for (int r = 0; r < 4; ++r) {
    const int kl = q * 4 + r;
    tile[a][kl] = (n0 + a < Nsrc) ? src[(size_t)(k0 + kl) * Nsrc + n0 + a] : 0.0f;
  }
  __syncthreads();
#pragma unroll
  for (int r = 0; r < 4; ++r) {
    const int nl = q * 4 + r;
    dst[(size_t)(n0 + nl) * K + k0 + a] = (f16)tile[nl][a];
  }
}

// K2f3: three K=2048/Nsrc=512 tconvs in one launch. grid (16, 64, 3).
__global__ __launch_bounds__(256) void k_tconv3(const float* __restrict__ s0, f16* d0,
                                                const float* __restrict__ s1, f16* d1,
                                                const float* __restrict__ s2, f16* d2) {
  __shared__ float tile[32][33];
  const float* src = (blockIdx.z == 0) ? s0 : (blockIdx.z == 1) ? s1 : s2;
  f16* dst = (blockIdx.z == 0) ? d0 : (blockIdx.z == 1) ? d1 : d2;
  const int n0 = blockIdx.x * 32, k0 = blockIdx.y * 32;
  const int tid = threadIdx.x;
  const int a = tid & 31, q = tid >> 5;
#pragma unroll
  for (int r = 0; r < 4; ++r) {
    const int kl = q * 4 + r;
    tile[a][kl] = src[(size_t)(k0 + kl) * 512 + n0 + a];
  }
  __syncthreads();
#pragma unroll
  for (int r = 0; r < 4; ++r) {
    const int nl = q * 4 + r;
    dst[(size_t)(n0 + nl) * 2048 + k0 + a] = (f16)tile[nl][a];
  }
}

// K2f2: dec_att (16 x-tiles) + f_beta (64 x-tiles), K=512. grid (80, 16).
__global__ __launch_bounds__(256) void k_tconv2b(const float* __restrict__ sd, f16* dd,
                                                 const float* __restrict__ sf, f16* df) {
  __shared__ float tile[32][33];
  const bool is_d = blockIdx.x < 16;
  const float* src = is_d ? sd : sf;
  f16* dst = is_d ? dd : df;
  const int nsrc = is_d ? 512 : 2048;
  const int n0 = (is_d ? blockIdx.x : (blockIdx.x - 16)) * 32, k0 = blockIdx.y * 32;
  const int tid = threadIdx.x;
  const int a = tid & 31, q = tid >> 5;
#pragma unroll
  for (int r = 0; r < 4; ++r) {
    const int kl = q * 4 + r;
    tile[a][kl] = src[(size_t)(k0 + kl) * nsrc + n0 + a];
  }
  __syncthreads();
#pragma unroll
  for (int r = 0; r < 4; ++r) {
    const int nl = q * 4 + r;
    dst[(size_t)(n0 + nl) * 512 + k0 + a] = (f16)tile[nl][a];
  }
}

// ---------------------------------------------------------------------------
// K2b: permuted Wcat: row r = d*4+g <-> original n = g*512+d.
// ---------------------------------------------------------------------------
__global__ __launch_bounds__(256) void k_cvt_wcat2(const float* __restrict__ Wih,
                                                   const float* __restrict__ Whh,
                                                   const float* __restrict__ bih,
                                                   const float* __restrict__ bhh,
                                                   f16* __restrict__ Wcat2,
                                                   float* __restrict__ bcat) {
  const int r = blockIdx.x;
  const int d = r >> 2, g = r & 3;
  const int n = g * 512 + d;
  for (int k = threadIdx.x; k < KC; k += 256) {
    const float v = (k < 2560) ? Wih[(size_t)n * 2560 + k] : Whh[(size_t)n * 512 + (k - 2560)];
    Wcat2[(size_t)r * KC + k] = (f16)v;
  }
  if (threadIdx.x == 0) bcat[r] = bih[n] + bhh[n];
}

// ---------------------------------------------------------------------------
// K3 (!full): mean over P of sorted encoder rows -> mean16. grid (4, 64).
// ---------------------------------------------------------------------------
__global__ __launch_bounds__(256) void k_mean(const float* __restrict__ enc,
                                              const int* __restrict__ perm,
                                              f16* __restrict__ mean16) {
  const int b = blockIdx.y;
  const int c0 = blockIdx.x * 512 + threadIdx.x * 2;
  const float* base = enc + (size_t)perm[b] * NP * NE + c0;
  float a0 = 0.0f, a1 = 0.0f;
  for (int p = 0; p < NP; ++p) {
    const float2 v = *(const float2*)&base[(size_t)p * NE];
    a0 += v.x; a1 += v.y;
  }
  mean16[(size_t)b * NE + c0] = (f16)(a0 * (1.0f / (float)NP));
  mean16[(size_t)b * NE + c0 + 1] = (f16)(a1 * (1.0f / (float)NP));
}

// K3b (full): mean from enc16 (f16, already permuted).
__global__ __launch_bounds__(256) void k_mean16(const f16* __restrict__ enc16,
                                                f16* __restrict__ mean16) {
  const int b = blockIdx.y;
  const int c0 = blockIdx.x * 512 + threadIdx.x * 2;
  const f16* base = enc16 + (size_t)b * NP * NE + c0;
  float a0 = 0.0f, a1 = 0.0f;
  for (int p = 0; p < NP; ++p) {
    const f16x2 v = *(const f16x2*)&base[(size_t)p * NE];
    a0 += (float)v[0]; a1 += (float)v[1];
  }
  mean16[(size_t)b * NE + c0] = (f16)(a0 * (1.0f / (float)NP));
  mean16[(size_t)b * NE + c0 + 1] = (f16)(a1 * (1.0f / (float)NP));
}

// ---------------------------------------------------------------------------
// K4 (FULL only): enc16[b][p][c] = f16(enc[perm[b]][p][c]). grid (196, 64).
// ---------------------------------------------------------------------------
__global__ __launch_bounds__(256) void k_enc_cvt(const float* __restrict__ enc,
                                                 const int* __restrict__ perm,
                                                 f16* __restrict__ enc16) {
  const int p = blockIdx.x, b = blockIdx.y;
  const float* src = enc + ((size_t)perm[b] * NP + p) * NE;
  f16* dst = enc16 + ((size_t)b * NP + p) * NE;
  const int i0 = threadIdx.x * 8;
  cvt8(src + i0, dst + i0);
}

// ---------------------------------------------------------------------------
// K4b (full3): embs16[t][b][e] = f16(emb[caps_s[b][t]][e]). grid (20, 64).
// ---------------------------------------------------------------------------
__global__ __launch_bounds__(256) void k_embs(const float* __restrict__ emb,
                                              const int* __restrict__ caps_s,
                                              f16* __restrict__ embs16) {
  const int t = blockIdx.x, b = blockIdx.y;
  const int cap = caps_s[b * NT_CAP + t];
  const int i0 = threadIdx.x * 2;
  const float2 v = *(const float2*)(emb + (size_t)cap * 512 + i0);
  f16x2 ev; ev[0] = (f16)v.x; ev[1] = (f16)v.y;
  *(f16x2*)&embs16[((size_t)t * NB + b) * 512 + i0] = ev;
}

// ---------------------------------------------------------------------------
// K4c (full3): embw = embs16 @ Wcat2[:, 0:512]^T. M=1280, N=2048, K=512.
// ---------------------------------------------------------------------------
__global__ __launch_bounds__(256) void k_embw(const f16* __restrict__ embs16,
                                              const f16* __restrict__ Wcat2,
                                              float* __restrict__ embw) {
  __shared__ __align__(16) f16 lA[256 * LDK];
  __shared__ __align__(16) f16 lB[64 * LDK];
  const int n0 = blockIdx.x * 64, m0 = blockIdx.y * 256;
  const int tid = threadIdx.x, lane = tid & 63, wv = tid >> 6;
  const int col = lane & 15, quad = lane >> 4;
  const f16* gA = embs16 + (size_t)(m0 + tid) * 512;
  const f16* gB = Wcat2 + (size_t)(n0 + (tid >> 2)) * KC + (tid & 3) * 16;
  f16* wA = &lA[tid * LDK];
  f16* wB = &lB[(tid >> 2) * LDK + (tid & 3) * 16];
  f32x4 acc[4][4] = {};
  for (int k0 = 0; k0 < 512; k0 += 64) {
#pragma unroll
    for (int u = 0; u < 8; ++u)
      *(f16x8*)(wA + u * 8) = *(const f16x8*)(gA + k0 + u * 8);
    *(f16x8*)(wB)     = *(const f16x8*)(gB + k0);
    *(f16x8*)(wB + 8) = *(const f16x8*)(gB + k0 + 8);
    __syncthreads();
#pragma unroll
    for (int kh = 0; kh < 2; ++kh) {
      f16x8 a[4], b[4];
#pragma unroll
      for (int i = 0; i < 4; ++i)
        a[i] = *(const f16x8*)&lA[(wv * 64 + i * 16 + col) * LDK + kh * 32 + quad * 8];
#pragma unroll
      for (int j = 0; j < 4; ++j)
        b[j] = *(const f16x8*)&lB[(j * 16 + col) * LDK + kh * 32 + quad * 8];
#pragma unroll
      for (int i = 0; i < 4; ++i)
#pragma unroll
        for (int j = 0; j < 4; ++j)
          acc[i][j] = __builtin_amdgcn_mfma_f32_16x16x32_f16(a[i], b[j], acc[i][j], 0, 0, 0);
    }
    __syncthreads();
  }
#pragma unroll
  for (int j = 0; j < 4; ++j) {
    const int n = n0 + j * 16 + col;
#pragma unroll
    for (int i = 0; i < 4; ++i)
#pragma unroll
      for (int rr = 0; rr < 4; ++rr) {
        const int r = m0 + wv * 64 + i * 16 + quad * 4 + rr;
        embw[(size_t)r * NE + n] = acc[i][j][rr];
      }
  }
}

// ---------------------------------------------------------------------------
// K5: h0/c0 = tanh(mean @ W + b), barrier-free direct MFMA. grid (16, 2).
// ---------------------------------------------------------------------------
__global__ __launch_bounds__(256) void k_init_mfma(const f16* __restrict__ mean16,
                                                   const f16* __restrict__ ihWt,
                                                   const f16* __restrict__ icWt,
                                                   const float* __restrict__ ihb,
                                                   const float* __restrict__ icb,
                                                   f16* __restrict__ h16,
                                                   float* __restrict__ cst) {
  const int which = blockIdx.y;
  const f16* Wt = which ? icWt : ihWt;
  const float* bias = which ? icb : ihb;
  const int tid = threadIdx.x, lane = tid & 63, wv = tid >> 6;
  const int col = lane & 15, quad = lane >> 4;
  const int nt = blockIdx.x * 4 + wv;  // 0..31
  f32x4 acc[4] = {};
  wave_gemm64(mean16, Wt + (size_t)nt * 16 * NE, NE, 0, NE, col, quad, acc);
  const int n = nt * 16 + col;
#pragma unroll
  for (int mt = 0; mt < 4; ++mt) {
#pragma unroll
    for (int rr = 0; rr < 4; ++rr) {
      const int m = mt * 16 + quad * 4 + rr;
      const float v = tanhf(acc[mt][rr] + bias[n]);
      if (which == 0) h16[(size_t)m * ND + n] = (f16)v;
      else            cst[(size_t)m * ND + n] = v;
    }
  }
}

// ---------------------------------------------------------------------------
// K6 (!full fallback): att1 = enc @ enc_att_W + b. grid (4, 196), BK=32.
// ---------------------------------------------------------------------------
template <bool E16>
__global__ __launch_bounds__(256) void k_att1_mfma(const float* __restrict__ encf,
                                                   const f16* __restrict__ enc16,
                                                   const int* __restrict__ perm,
                                                   const f16* __restrict__ eaWt,
                                                   const float* __restrict__ eab,
                                                   f16* __restrict__ att1) {
  __shared__ __align__(16) f16 lA[64 * LDT];
  __shared__ __align__(16) f16 lB[128 * LDT];
  __shared__ int rowoff[64];
  const int r0 = blockIdx.y * 64;
  const int n0 = blockIdx.x * 128;
  const int tid = threadIdx.x, lane = tid & 63, wv = tid >> 6;
  const int col = lane & 15, quad = lane >> 4;
  if (!E16) {
    if (tid < 64) {
      const int r = r0 + tid;
      const int b = r / NP, p = r - b * NP;
      rowoff[tid] = (perm[b] * NP + p) * NE;
    }
    __syncthreads();
  }
  f32x4 acc[8] = {};
  for (int k0 = 0; k0 < NE; k0 += 32) {
    if (E16) {
      stage16(enc16 + (size_t)r0 * NE, NE, k0, lA, tid);
    } else {
      const int row = tid >> 2, seg = tid & 3;
      cvt8(encf + (size_t)rowoff[row] + k0 + seg * 8, &lA[row * LDT + seg * 8]);
    }
    {
      const int row0 = tid >> 2, seg = tid & 3;
#pragma unroll
      for (int u = 0; u < 2; ++u) {
        const int row = row0 + 64 * u;
        *(f16x8*)&lB[row * LDT + seg * 8] =
            *(const f16x8*)&eaWt[(size_t)(n0 + row) * NE + k0 + seg * 8];
      }
    }
    __syncthreads();
    const f16x8 a = *(const f16x8*)&lA[(wv * 16 + col) * LDT + quad * 8];
#pragma unroll
    for (int ns = 0; ns < 8; ++ns) {
      const f16x8 b = *(const f16x8*)&lB[(ns * 16 + col) * LDT + quad * 8];
      acc[ns] = __builtin_amdgcn_mfma_f32_16x16x32_f16(a, b, acc[ns], 0, 0, 0);
    }
    __syncthreads();
  }
#pragma unroll
  for (int ns = 0; ns < 8; ++ns) {
    const int n = n0 + ns * 16 + col;
#pragma unroll
    for (int rr = 0; rr < 4; ++rr) {
      const int r = r0 + wv * 16 + quad * 4 + rr;
      att1[(size_t)r * NA + n] = (f16)(acc[ns][rr] + eab[n]);
    }
  }
}

// ---------------------------------------------------------------------------
// K6v3 (full): att1 GEMM, BM=128, BN=128, BK=64, wave=64x64 (32 MFMA/K-iter).
// grid (98, 4). LDS 36.9 KB. (validated R9)
// ---------------------------------------------------------------------------
__global__ __launch_bounds__(256) void k_att1_v3(const f16* __restrict__ enc16,
                                                 const f16* __restrict__ eaWt,
                                                 const float* __restrict__ eab,
                                                 f16* __restrict__ att1) {
  __shared__ __align__(16) f16 lA[128 * LDK];
  __shared__ __align__(16) f16 lB[128 * LDK];
  const int r0 = blockIdx.x * 128, n0 = blockIdx.y * 128;
  const int tid = threadIdx.x, lane = tid & 63, wv = tid >> 6;
  const int col = lane & 15, quad = lane >> 4;
  const int wr = wv >> 1, wc = wv & 1;  // wave quadrant: 64m x 64n
  const int srow = tid >> 1, sseg = (tid & 1) * 32;
  const f16* gA = enc16 + (size_t)(r0 + srow) * NE + sseg;
  const f16* gB = eaWt + (size_t)(n0 + srow) * NE + sseg;
  f16* wA = &lA[srow * LDK + sseg];
  f16* wB = &lB[srow * LDK + sseg];
  f32x4 acc[4][4] = {};
  for (int k0 = 0; k0 < NE; k0 += 64) {
#pragma unroll
    for (int u = 0; u < 4; ++u) {
      *(f16x8*)(wA + u * 8) = *(const f16x8*)(gA + k0 + u * 8);
      *(f16x8*)(wB + u * 8) = *(const f16x8*)(gB + k0 + u * 8);
    }
    __syncthreads();
#pragma unroll
    for (int kh = 0; kh < 2; ++kh) {
      f16x8 a[4], b[4];
#pragma unroll
      for (int i = 0; i < 4; ++i)
        a[i] = *(const f16x8*)&lA[(wr * 64 + i * 16 + col) * LDK + kh * 32 + quad * 8];
#pragma unroll
      for (int j = 0; j < 4; ++j)
        b[j] = *(const f16x8*)&lB[(wc * 64 + j * 16 + col) * LDK + kh * 32 + quad * 8];
#pragma unroll
      for (int i = 0; i < 4; ++i)
#pragma unroll
        for (int j = 0; j < 4; ++j)
          acc[i][j] = __builtin_amdgcn_mfma_f32_16x16x32_f16(a[i], b[j], acc[i][j], 0, 0, 0);
    }
    __syncthreads();
  }
#pragma unroll
  for (int j = 0; j < 4; ++j) {
    const int n = n0 + wc * 64 + j * 16 + col;
    const float bv = eab[n];
#pragma unroll
    for (int i = 0; i < 4; ++i)
#pragma unroll
      for (int rr = 0; rr < 4; ++rr) {
        const int r = r0 + wr * 64 + i * 16 + quad * 4 + rr;
        att1[(size_t)r * NA + n] = (f16)(acc[i][j][rr] + bv);
      }
  }
}

// ---------------------------------------------------------------------------
// K-STEPS3 (full3 + cooperative): 20-step loop, 3 grid.syncs per step.
// All global accesses coalesced (the R9 lesson).
// ---------------------------------------------------------------------------
struct Step3Params {
  f16* h16;
  const f16* daWt; const float* dab;
  const f16* fbWt; const float* fbb;
  const f16* Wcat2; const float* bcat;
  const f16* att1; const float* fullW;
  const f16* enc16;
  const float* embw;
  const int* declen;
  float* att2; float* gate;
  float* out_alphas;
  f16* xcat;
  float* cst;
  f16* hseq;
};

__global__ __launch_bounds__(512, 2) void k_steps3(Step3Params P) {
  cg::grid_group grid = cg::this_grid();
  __shared__ float S[8192];  // 32 KB, reused across phases
  const int tid = threadIdx.x, lane = tid & 63, wv = tid >> 6;
  const int col = lane & 15, quad = lane >> 4;
  const int bid = blockIdx.x, nblk = gridDim.x;

  for (int t = 0; t < NTD; ++t) {
    // ===== Phase 1: hall-lite — att2 (32 tiles) + gate (128 tiles) =========
    for (int nt = bid; nt < 160; nt += nblk) {
      const f16* Brow = (nt < 32) ? (P.daWt + (size_t)nt * 16 * ND)
                                  : (P.fbWt + (size_t)(nt - 32) * 16 * ND);
      f32x4 acc[4] = {};
      wave_gemm_s<4>(P.h16, ND, Brow, ND, wv * 64, wv * 64 + 64, col, quad, acc);
#pragma unroll
      for (int mt = 0; mt < 4; ++mt)
#pragma unroll
        for (int rr = 0; rr < 4; ++rr)
          S[wv * 1024 + (mt * 4 + rr) * 64 + lane] = acc[mt][rr];
      __syncthreads();
#pragma unroll
      for (int j = 0; j < 2; ++j) {
        const int slot = tid * 2 + j;
        float s = S[slot];
#pragma unroll
        for (int w = 1; w < 8; ++w) s += S[w * 1024 + slot];
        const int c2 = slot >> 6, lane_s = slot & 63;
        const int mt = c2 >> 2, rr = c2 & 3;
        const int m = mt * 16 + (lane_s >> 4) * 4 + rr;
        const int nl = lane_s & 15;
        if (nt < 32) {
          const int n = nt * 16 + nl;
          P.att2[(size_t)m * NA + n] = s + P.dab[n];
        } else {
          const int n = (nt - 32) * 16 + nl;
          P.gate[(size_t)m * NE + n] = sigmoidf_(s + P.fbb[n]);
        }
      }
      __syncthreads();
    }
    __threadfence();
    grid.sync();

    // ===== Phase 2: (b,q) — logits + softmax + awe + xcat =================
    // (att2/gate read from GLOBAL, coalesced; att1[b] re-read 4x, LLC-hot)
    for (int task = bid; task < 256; task += nblk) {
      const int b = task >> 2, q = task & 3;
      // logits: wave per p
      {
        float a2r[8], fwr[8];
        const float4* A2 = (const float4*)(P.att2 + (size_t)b * NA + lane * 8);
        const float4* FW = (const float4*)(P.fullW + lane * 8);
        const float4 q0 = A2[0], q1 = A2[1], w0 = FW[0], w1 = FW[1];
        a2r[0] = q0.x; a2r[1] = q0.y; a2r[2] = q0.z; a2r[3] = q0.w;
        a2r[4] = q1.x; a2r[5] = q1.y; a2r[6] = q1.z; a2r[7] = q1.w;
        fwr[0] = w0.x; fwr[1] = w0.y; fwr[2] = w0.z; fwr[3] = w0.w;
        fwr[4] = w1.x; fwr[5] = w1.y; fwr[6] = w1.z; fwr[7] = w1.w;
        for (int p = wv; p < NP; p += 8) {
          const f16x8 row = *(const f16x8*)(P.att1 + ((size_t)b * NP + p) * NA + lane * 8);
          float acc = 0.0f;
#pragma unroll
          for (int j = 0; j < 8; ++j)
            acc += fmaxf((float)row[j] + a2r[j], 0.0f) * fwr[j];
#pragma unroll
          for (int off = 32; off > 0; off >>= 1) acc += __shfl_down(acc, off, 64);
          if (lane == 0) S[p] = acc;
        }
      }
      __syncthreads();
      // softmax (wave 0 butterfly)
      if (wv == 0) {
        const float v0 = S[lane];
        const float v1 = S[lane + 64];
        const float v2 = S[lane + 128];
        const float v3 = (lane < 4) ? S[192 + lane] : -INFINITY;
        float mx = fmaxf(fmaxf(v0, v1), fmaxf(v2, v3));
#pragma unroll
        for (int off = 32; off > 0; off >>= 1) mx = fmaxf(mx, __shfl_xor(mx, off, 64));
        float s = expf(v0 - mx) + expf(v1 - mx) + expf(v2 - mx) +
                  ((lane < 4) ? expf(v3 - mx) : 0.0f);
#pragma unroll
        for (int off = 32; off > 0; off >>= 1) s += __shfl_xor(s, off, 64);
        if (lane == 0) { S[200] = mx; S[201] = 1.0f / s; }
      }
      __syncthreads();
      if (tid < NP) {
        const float a = expf(S[tid] - S[200]) * S[201];
        S[256 + tid] = a;  // alpha
        if (q == 0) {
          const bool act = t < P.declen[b];
          P.out_alphas[((size_t)b * NTD + t) * NP + tid] = act ? a : 0.0f;
        }
      }
      __syncthreads();
      // awe partials: 2 ch/thread over half the p-range
      {
        const int cl = (tid & 255) * 2, ph = tid >> 8;
        const int c = q * 512 + cl;
        const f16* base = P.enc16 + (size_t)b * NP * NE + c;
        float a0 = 0.0f, a1 = 0.0f;
        const int p0 = ph ? 98 : 0, p1 = ph ? 196 : 98;
        for (int p = p0; p < p1; ++p) {
          const f16x2 v = *(const f16x2*)&base[(size_t)p * NE];
          const float ap = S[256 + p];
          a0 += ap * (float)v[0]; a1 += ap * (float)v[1];
        }
        S[512 + ph * 512 + cl] = a0;
        S[512 + ph * 512 + cl + 1] = a1;
      }
      __syncthreads();
      // combine + gate (global, coalesced) -> xcat mid; q==0: h tail copy
      if (tid < 256) {
        const int c2 = tid * 2;
        const float r0 = S[512 + c2] + S[1024 + c2];
        const float r1 = S[512 + c2 + 1] + S[1024 + c2 + 1];
        const int n = q * 512 + c2;
        const float2 g = *(const float2*)&P.gate[(size_t)b * NE + n];
        f16x2 o; o[0] = (f16)(r0 * g.x); o[1] = (f16)(r1 * g.y);
        *(f16x2*)&P.xcat[(size_t)b * KC + 512 + n] = o;
      } else if (q == 0) {
        const int i0 = (tid - 256) * 2;
        *(f16x2*)&P.xcat[(size_t)b * KC + 2560 + i0] =
            *(const f16x2*)&P.h16[(size_t)b * ND + i0];
      }
      __syncthreads();
    }
    __threadfence();
    grid.sync();

    // ===== Phase 3: xlstm GEMM K=512..3072 + cell epilogue =================
    for (int task = bid; task < 256; task += nblk) {
      const int nt = task >> 1, mh = task & 1;
      f32x4 acc[2] = {};
      wave_gemm_s<2>(P.xcat + (size_t)mh * 32 * KC, KC,
                     P.Wcat2 + (size_t)nt * 16 * KC, KC,
                     512 + wv * 320, 512 + wv * 320 + 320, col, quad, acc);
#pragma unroll
      for (int mt = 0; mt < 2; ++mt)
#pragma unroll
        for (int rr = 0; rr < 4; ++rr)
          S[wv * 512 + (mt * 4 + rr) * 64 + lane] = acc[mt][rr];
      __syncthreads();
      {
        float s = S[tid];
#pragma unroll
        for (int w = 1; w < 8; ++w) s += S[w * 512 + tid];
        S[tid] = s;
      }
      __syncthreads();
      if (tid < 128) {
        const int ml = tid >> 2, dl = tid & 3;
        const int m = mh * 32 + ml;
        const int d = nt * 4 + dl;
        const int mt = ml >> 4, qd = (ml >> 2) & 3, rr = ml & 3;
        float g4[4];
#pragma unroll
        for (int g = 0; g < 4; ++g) {
          const int cv = dl * 4 + g;
          const int r = nt * 16 + cv;
          g4[g] = S[(mt * 4 + rr) * 64 + qd * 16 + cv] + P.bcat[r] +
                  P.embw[((size_t)t * NB + m) * NE + r];
        }
        const float iv = sigmoidf_(g4[0]);
        const float fv = sigmoidf_(g4[1]);
        const float gv = tanhf(g4[2]);
        const float ov = sigmoidf_(g4[3]);
        const float cold = P.cst[(size_t)m * ND + d];
        const float cn = fv * cold + iv * gv;
        const float hn = ov * tanhf(cn);
        P.hseq[((size_t)t * NB + m) * ND + d] = (f16)hn;
        if (t < P.declen[m]) {
          P.cst[(size_t)m * ND + d] = cn;
          P.h16[(size_t)m * ND + d] = (f16)hn;
        }
      }
      __syncthreads();
    }
    __threadfence();
    grid.sync();
  }
}

// ---------------------------------------------------------------------------
// Fallback per-step kernels — unchanged (validated R6-R8).
// ---------------------------------------------------------------------------
__global__ __launch_bounds__(256) void k_hgemm_v2(const f16* __restrict__ h16,
                                                  const f16* __restrict__ daWt,
                                                  const float* __restrict__ dab,
                                                  const f16* __restrict__ fbWt,
                                                  const float* __restrict__ fbb,
                                                  float* __restrict__ att2,
                                                  float* __restrict__ gate) {
  __shared__ float R[2 * 64 * 16];
  const int tid = threadIdx.x, lane = tid & 63, wv = tid >> 6;
  const int col = lane & 15, quad = lane >> 4;
  const int sub = wv >> 1, kh = wv & 1;
  const int nt = blockIdx.x * 2 + sub;  // 0..159
  const bool is_att = nt < 32;
  const f16* Brow = is_att ? (daWt + (size_t)nt * 16 * ND)
                           : (fbWt + (size_t)(nt - 32) * 16 * ND);
  f32x4 acc[4] = {};
  wave_gemm64(h16, Brow, ND, kh * 256, kh * 256 + 256, col, quad, acc);
  if (kh) {
#pragma unroll
    for (int mt = 0; mt < 4; ++mt)
#pragma unroll
      for (int rr = 0; rr < 4; ++rr)
        R[(sub * 64 + lane) * 16 + mt * 4 + rr] = acc[mt][rr];
  }
  __syncthreads();
  if (kh) return;
#pragma unroll
  for (int mt = 0; mt < 4; ++mt)
#pragma unroll
    for (int rr = 0; rr < 4; ++rr)
      acc[mt][rr] += R[(sub * 64 + lane) * 16 + mt * 4 + rr];
  if (is_att) {
    const int n = nt * 16 + col;
#pragma unroll
    for (int mt = 0; mt < 4; ++mt)
#pragma unroll
      for (int rr = 0; rr < 4; ++rr) {
        const int m = mt * 16 + quad * 4 + rr;
        att2[(size_t)m * NA + n] = acc[mt][rr] + dab[n];
      }
  } else {
    const int n = (nt - 32) * 16 + col;
#pragma unroll
    for (int mt = 0; mt < 4; ++mt)
#pragma unroll
      for (int rr = 0; rr < 4; ++rr) {
        const int m = mt * 16 + quad * 4 + rr;
        gate[(size_t)m * NE + n] = sigmoidf_(acc[mt][rr] + fbb[n]);
      }
  }
}

template <bool E16>
__global__ __launch_bounds__(512) void k_attn_awe(const f16* __restrict__ att1,
                                                  const float* __restrict__ att2,
                                                  const float* __restrict__ fullW,
                                                  const int* __restrict__ declen, int t,
                                                  const float* __restrict__ encf,
                                                  const f16* __restrict__ enc16,
                                                  const int* __restrict__ perm,
                                                  const float* __restrict__ gate,
                                                  const float* __restrict__ emb,
                                                  const int* __restrict__ caps_s,
                                                  const f16* __restrict__ h16,
                                                  f16* __restrict__ xcat,
                                                  float* __restrict__ out_alphas) {
  const int b = blockIdx.x;
  const int tid = threadIdx.x, wv = tid >> 6, lane = tid & 63;
  __shared__ float e[200];
  __shared__ float al[200];
  __shared__ float red2[2];
  {
    float a2r[8], fwr[8];
    const float4* A2 = (const float4*)(att2 + (size_t)b * NA + lane * 8);
    const float4* FW = (const float4*)(fullW + lane * 8);
    const float4 q0 = A2[0], q1 = A2[1], w0 = FW[0], w1 = FW[1];
    a2r[0] = q0.x; a2r[1] = q0.y; a2r[2] = q0.z; a2r[3] = q0.w;
    a2r[4] = q1.x; a2r[5] = q1.y; a2r[6] = q1.z; a2r[7] = q1.w;
    fwr[0] = w0.x; fwr[1] = w0.y; fwr[2] = w0.z; fwr[3] = w0.w;
    fwr[4] = w1.x; fwr[5] = w1.y; fwr[6] = w1.z; fwr[7] = w1.w;
    for (int p = wv; p < NP; p += 8) {
      const f16x8 row = *(const f16x8*)(att1 + ((size_t)b * NP + p) * NA + lane * 8);
      float acc = 0.0f;
#pragma unroll
      for (int j = 0; j < 8; ++j) acc += fmaxf((float)row[j] + a2r[j], 0.0f) * fwr[j];
#pragma unroll
      for (int off = 32; off > 0; off >>= 1) acc += __shfl_down(acc, off, 64);
      if (lane == 0) e[p] = acc;
    }
  }
  __syncthreads();
  if (wv == 0) {
    const float v0 = e[lane];
    const float v1 = e[lane + 64];
    const float v2 = e[lane + 128];
    const float v3 = (lane < 4) ? e[192 + lane] : -INFINITY;
    float mx = fmaxf(fmaxf(v0, v1), fmaxf(v2, v3));
#pragma unroll
    for (int off = 32; off > 0; off >>= 1) mx = fmaxf(mx, __shfl_xor(mx, off, 64));
    float s = expf(v0 - mx) + expf(v1 - mx) + expf(v2 - mx) +
              ((lane < 4) ? expf(v3 - mx) : 0.0f);
#pragma unroll
    for (int off = 32; off > 0; off >>= 1) s += __shfl_xor(s, off, 64);
    if (lane == 0) { red2[0] = mx; red2[1] = 1.0f / s; }
  }
  __syncthreads();
  {
    const float mx = red2[0], inv = red2[1];
    if (tid < NP) {
      const float a = expf(e[tid] - mx) * inv;
      al[tid] = a;
      const bool act = t < declen[b];
      out_alphas[((size_t)b * NTD + t) * NP + tid] = act ? a : 0.0f;
    }
  }
  __syncthreads();
  {
    const int c = tid * 4;
    float a0 = 0.0f, a1 = 0.0f, a2 = 0.0f, a3 = 0.0f;
    if (E16) {
      const f16* base = enc16 + (size_t)b * NP * NE + c;
      for (int p = 0; p < NP; ++p) {
        const f16x4 v = *(const f16x4*)&base[(size_t)p * NE];
        const float ap = al[p];
        a0 += ap * (float)v[0]; a1 += ap * (float)v[1];
        a2 += ap * (float)v[2]; a3 += ap * (float)v[3];
      }
    } else {
      const float* base = encf + (size_t)perm[b] * NP * NE + c;
      for (int p = 0; p < NP; ++p) {
        const float4 v = *(const float4*)&base[(size_t)p * NE];
        const float ap = al[p];
        a0 += ap * v.x; a1 += ap * v.y; a2 += ap * v.z; a3 += ap * v.w;
      }
    }
    const float4 g = *(const float4*)&gate[(size_t)b * NE + c];
    f16x4 o;
    o[0] = (f16)(a0 * g.x); o[1] = (f16)(a1 * g.y);
    o[2] = (f16)(a2 * g.z); o[3] = (f16)(a3 * g.w);
    *(f16x4*)&xcat[(size_t)b * KC + 512 + c] = o;
  }
  if (tid < 256) {
    const int cap = caps_s[b * NT_CAP + t];
    const int i0 = tid * 2;
    const float2 v = *(const float2*)(emb + (size_t)cap * 512 + i0);
    f16x2 ev; ev[0] = (f16)v.x; ev[1] = (f16)v.y;
    *(f16x2*)&xcat[(size_t)b * KC + i0] = ev;
    *(f16x2*)&xcat[(size_t)b * KC + 2560 + i0] = *(const f16x2*)&h16[(size_t)b * ND + i0];
  }
}

__global__ __launch_bounds__(512) void k_xlstm_v2(const f16* __restrict__ xcat,
                                                  const f16* __restrict__ Wcat2,
                                                  const float* __restrict__ bcat,
                                                  const int* __restrict__ declen, int t,
                                                  float* __restrict__ cst,
                                                  f16* __restrict__ h16,
                                                  f16* __restrict__ hnew16,
                                                  f16* __restrict__ hseq) {
  __shared__ float R[8 * 64 * 16];
  const int nt = blockIdx.x;
  const int tid = threadIdx.x, lane = tid & 63, wv = tid >> 6;
  const int col = lane & 15, quad = lane >> 4;
  f32x4 acc[4] = {};
  wave_gemm64(xcat, Wcat2 + (size_t)nt * 16 * KC, KC, wv * 384, wv * 384 + 384,
              col, quad, acc);
#pragma unroll
  for (int mt = 0; mt < 4; ++mt)
#pragma unroll
    for (int rr = 0; rr < 4; ++rr)
      R[(wv * 64 + lane) * 16 + mt * 4 + rr] = acc[mt][rr];
  __syncthreads();
  {
    const int j0 = tid * 2;
#pragma unroll
    for (int j = 0; j < 2; ++j) {
      const int e2 = j0 + j;
      float s = R[e2];
#pragma unroll
      for (int w = 1; w < 8; ++w) s += R[w * 1024 + e2];
      R[e2] = s;
    }
  }
  __syncthreads();
  if (tid < 256) {
    const int m = tid >> 2, dl = tid & 3;
    const int mt = m >> 4, qd = (m >> 2) & 3, rr = m & 3;
    float g4[4];
#pragma unroll
    for (int g = 0; g < 4; ++g) {
      const int cv = dl * 4 + g;
      g4[g] = R[(qd * 16 + cv) * 16 + mt * 4 + rr] + bcat[nt * 16 + cv];
    }
    const int d = nt * 4 + dl;
    const float iv = sigmoidf_(g4[0]);
    const float fv = sigmoidf_(g4[1]);
    const float gv = tanhf(g4[2]);
    const float ov = sigmoidf_(g4[3]);
    const float cold = cst[(size_t)m * ND + d];
    const float cn = fv * cold + iv * gv;
    const float hn = ov * tanhf(cn);
    hnew16[(size_t)m * ND + d] = (f16)hn;
    if (hseq) hseq[((size_t)t * NB + m) * ND + d] = (f16)hn;
    if (t < declen[m]) {
      cst[(size_t)m * ND + d] = cn;
      h16[(size_t)m * ND + d] = (f16)hn;
    }
  }
}

__global__ __launch_bounds__(256) void k_fc_mfma(const f16* __restrict__ hnew16,
                                                 const f16* __restrict__ fcWt,
                                                 const float* __restrict__ fcb,
                                                 const int* __restrict__ declen, int t,
                                                 float* __restrict__ out_pred) {
  const int tid = threadIdx.x, lane = tid & 63, wv = tid >> 6;
  const int col = lane & 15, quad = lane >> 4;
  const int nt = blockIdx.x * 4 + wv;  // 0..627
  f32x4 acc[4] = {};
  wave_gemm64(hnew16, fcWt + (size_t)nt * 16 * ND, ND, 0, ND, col, quad, acc);
  const int n = nt * 16 + col;
  if (n < NV) {
    const float bv = fcb[n];
#pragma unroll
    for (int mt = 0; mt < 4; ++mt)
#pragma unroll
      for (int rr = 0; rr < 4; ++rr) {
        const int m = mt * 16 + quad * 4 + rr;
        const bool act = t < declen[m];
        out_pred[((size_t)m * NTD + t) * NV + n] = act ? (acc[mt][rr] + bv) : 0.0f;
      }
  }
}

// ---------------------------------------------------------------------------
// K11v2 (batch): preds for ALL steps from hseq. LDS-tiled GEMM grid (157, 5).
// ---------------------------------------------------------------------------
__global__ __launch_bounds__(256) void k_fc_v2(const f16* __restrict__ hseq,
                                               const f16* __restrict__ fcWt,
                                               const float* __restrict__ fcb,
                                               const int* __restrict__ declen,
                                               float* __restrict__ out_pred) {
  __shared__ __align__(16) f16 lA[256 * LDK];
  __shared__ __align__(16) f16 lB[64 * LDK];
  const int n0 = blockIdx.x * 64, m0 = blockIdx.y * 256;
  const int tid = threadIdx.x, lane = tid & 63, wv = tid >> 6;
  const int col = lane & 15, quad = lane >> 4;
  const f16* gA = hseq + (size_t)(m0 + tid) * ND;
  const f16* gB = fcWt + (size_t)(n0 + (tid >> 2)) * ND + (tid & 3) * 16;
  f16* wA = &lA[tid * LDK];
  f16* wB = &lB[(tid >> 2) * LDK + (tid & 3) * 16];
  f32x4 acc[4][4] = {};
  for (int k0 = 0; k0 < ND; k0 += 64) {
#pragma unroll
    for (int u = 0; u < 8; ++u)
      *(f16x8*)(wA + u * 8) = *(const f16x8*)(gA + k0 + u * 8);
    *(f16x8*)(wB)     = *(const f16x8*)(gB + k0);
    *(f16x8*)(wB + 8) = *(const f16x8*)(gB + k0 + 8);
    __syncthreads();
#pragma unroll
    for (int kh = 0; kh < 2; ++kh) {
      f16x8 a[4], b[4];
#pragma unroll
      for (int i = 0; i < 4; ++i)
        a[i] = *(const f16x8*)&lA[(wv * 64 + i * 16 + col) * LDK + kh * 32 + quad * 8];
#pragma unroll
      for (int j = 0; j < 4; ++j)
        b[j] = *(const f16x8*)&lB[(j * 16 + col) * LDK + kh * 32 + quad * 8];
#pragma unroll
      for (int i = 0; i < 4; ++i)
#pragma unroll
        for (int j = 0; j < 4; ++j)
          acc[i][j] = __builtin_amdgcn_mfma_f32_16x16x32_f16(a[i], b[j], acc[i][j], 0, 0, 0);
    }
    __syncthreads();
  }
#pragma unroll
  for (int j = 0; j < 4; ++j) {
    const int n = n0 + j * 16 + col;
    if (n >= NV) continue;
    const float bv = fcb[n];
#pragma unroll
    for (int i = 0; i < 4; ++i)
#pragma unroll
      for (int rr = 0; rr < 4; ++rr) {
        const int r = m0 + wv * 64 + i * 16 + quad * 4 + rr;
        const int tt = r >> 6, m = r & 63;
        const bool act = tt < declen[m];
        out_pred[((size_t)m * NTD + tt) * NV + n] = act ? (acc[i][j][rr] + bv) : 0.0f;
      }
  }
}

// full3 fallback per-step kernels (non-coop): hall/logits/awe/xlstm_v3
__global__ __launch_bounds__(256) void k_hall(const f16* __restrict__ h16,
                                              const f16* __restrict__ daWt,
                                              const float* __restrict__ dab,
                                              const f16* __restrict__ fbWt,
                                              const float* __restrict__ fbb,
                                              const f16* __restrict__ Wcat2,
                                              float* __restrict__ att2,
                                              float* __restrict__ gate,
                                              float* __restrict__ hwhh) {
  __shared__ float R[4 * 1024];
  const int nt = blockIdx.x;
  const int tid = threadIdx.x, lane = tid & 63, wv = tid >> 6;
  const int col = lane & 15, quad = lane >> 4;
  const f16* Brow; int ldb;
  if (nt < 32)       { Brow = daWt + (size_t)nt * 16 * ND; ldb = ND; }
  else if (nt < 160) { Brow = fbWt + (size_t)(nt - 32) * 16 * ND; ldb = ND; }
  else               { Brow = Wcat2 + (size_t)(nt - 160) * 16 * KC + 2560; ldb = KC; }
  f32x4 acc[4] = {};
  wave_gemm_s<4>(h16, ND, Brow, ldb, wv * 128, wv * 128 + 128, col, quad, acc);
#pragma unroll
  for (int mt = 0; mt < 4; ++mt)
#pragma unroll
    for (int rr = 0; rr < 4; ++rr)
      R[wv * 1024 + (mt * 4 + rr) * 64 + lane] = acc[mt][rr];
  __syncthreads();
#pragma unroll
  for (int j = 0; j < 4; ++j) {
    const int slot = tid * 4 + j;
    const float s = R[slot] + R[1024 + slot] + R[2048 + slot] + R[3072 + slot];
    const int c2 = slot >> 6;
    const int lane_s = slot & 63;
    const int mt = c2 >> 2, rr = c2 & 3;
    const int m = mt * 16 + (lane_s >> 4) * 4 + rr;
    const int nl = lane_s & 15;
    if (nt < 32) {
      const int n = nt * 16 + nl;
      att2[(size_t)m * NA + n] = s + dab[n];
    } else if (nt < 160) {
      const int n = (nt - 32) * 16 + nl;
      gate[(size_t)m * NE + n] = sigmoidf_(s + fbb[n]);
    } else {
      const int r = (nt - 160) * 16 + nl;
      hwhh[(size_t)m * NE + r] = s;
    }
  }
}

__global__ __launch_bounds__(512) void k_logits(const f16* __restrict__ att1,
                                                const float* __restrict__ att2,
                                                const float* __restrict__ fullW,
                                                const int* __restrict__ declen, int t,
                                                float* __restrict__ alpha_ws,
                                                float* __restrict__ out_alphas) {
  const int b = blockIdx.x;
  const int tid = threadIdx.x, wv = tid >> 6, lane = tid & 63;
  __shared__ float e[200];
  __shared__ float red2[2];
  {
    float a2r[8], fwr[8];
    const float4* A2 = (const float4*)(att2 + (size_t)b * NA + lane * 8);
    const float4* FW = (const float4*)(fullW + lane * 8);
    const float4 q0 = A2[0], q1 = A2[1], w0 = FW[0], w1 = FW[1];
    a2r[0] = q0.x; a2r[1] = q0.y; a2r[2] = q0.z; a2r[3] = q0.w;
    a2r[4] = q1.x; a2r[5] = q1.y; a2r[6] = q1.z; a2r[7] = q1.w;
    fwr[0] = w0.x; fwr[1] = w0.y; fwr[2] = w0.z; fwr[3] = w0.w;
    fwr[4] = w1.x; fwr[5] = w1.y; fwr[6] = w1.z; fwr[7] = w1.w;
    for (int p = wv; p < NP; p += 8) {
      const f16x8 row = *(const f16x8*)(att1 + ((size_t)b * NP + p) * NA + lane * 8);
      float acc = 0.0f;
#pragma unroll
      for (int j = 0; j < 8; ++j) acc += fmaxf((float)row[j] + a2r[j], 0.0f) * fwr[j];
#pragma unroll
      for (int off = 32; off > 0; off >>= 1) acc += __shfl_down(acc, off, 64);
      if (lane == 0) e[p] = acc;
    }
  }
  __syncthreads();
  if (wv == 0) {
    const float v0 = e[lane];
    const float v1 = e[lane + 64];
    const float v2 = e[lane + 128];
    const float v3 = (lane < 4) ? e[192 + lane] : -INFINITY;
    float mx = fmaxf(fmaxf(v0, v1), fmaxf(v2, v3));
#pragma unroll
    for (int off = 32; off > 0; off >>= 1) mx = fmaxf(mx, __shfl_xor(mx, off, 64));
    float s = expf(v0 - mx) + expf(v1 - mx) + expf(v2 - mx) +
              ((lane < 4) ? expf(v3 - mx) : 0.0f);
#pragma unroll
    for (int off = 32; off > 0; off >>= 1) s += __shfl_xor(s, off, 64);
    if (lane == 0) { red2[0] = mx; red2[1] = 1.0f / s; }
  }
  __syncthreads();
  if (tid < NP) {
    const float a = expf(e[tid] - red2[0]) * red2[1];
    alpha_ws[(size_t)b * NP + tid] = a;
    const bool act = t < declen[b];
    out_alphas[((size_t)b * NTD + t) * NP + tid] = act ? a : 0.0f;
  }
}

__global__ __launch_bounds__(256) void k_awe(const f16* __restrict__ enc16,
                                             const float* __restrict__ alpha_ws,
                                             const float* __restrict__ gate,
                                             f16* __restrict__ xcat) {
  const int b = blockIdx.x >> 2, q = blockIdx.x & 3;
  const int tid = threadIdx.x;
  __shared__ float al[NP];
  if (tid < NP) al[tid] = alpha_ws[(size_t)b * NP + tid];
  __syncthreads();
  const int c = q * 512 + tid * 2;
  const f16* base = enc16 + (size_t)b * NP * NE + c;
  float a0 = 0.0f, a1 = 0.0f, b0 = 0.0f, b1 = 0.0f;
  for (int p = 0; p < NP; p += 2) {
    const f16x2 v0 = *(const f16x2*)&base[(size_t)p * NE];
    const f16x2 v1 = *(const f16x2*)&base[(size_t)(p + 1) * NE];
    const float ap0 = al[p], ap1 = al[p + 1];
    a0 += ap0 * (float)v0[0]; a1 += ap0 * (float)v0[1];
    b0 += ap1 * (float)v1[0]; b1 += ap1 * (float)v1[1];
  }
  a0 += b0; a1 += b1;
  const float2 g = *(const float2*)&gate[(size_t)b * NE + c];
  f16x2 o; o[0] = (f16)(a0 * g.x); o[1] = (f16)(a1 * g.y);
  *(f16x2*)&xcat[(size_t)b * KC + 512 + c] = o;
}

__global__ __launch_bounds__(512) void k_xlstm_v3(const f16* __restrict__ xcat,
                                                  const f16* __restrict__ Wcat2,
                                                  const float* __restrict__ bcat,
                                                  const float* __restrict__ hwhh,
                                                  const float* __restrict__ embw,
                                                  const int* __restrict__ declen, int t,
                                                  float* __restrict__ cst,
                                                  f16* __restrict__ h16,
                                                  f16* __restrict__ hnew16,
                                                  f16* __restrict__ hseq) {
  __shared__ float R[8 * 512];
  const int nt = blockIdx.x >> 1, mh = blockIdx.x & 1;
  const int tid = threadIdx.x, lane = tid & 63, wv = tid >> 6;
  const int col = lane & 15, quad = lane >> 4;
  f32x4 acc[2] = {};
  wave_gemm_s<2>(xcat + (size_t)mh * 32 * KC, KC,
                 Wcat2 + (size_t)nt * 16 * KC, KC,
                 512 + wv * 256, 512 + wv * 256 + 256, col, quad, acc);
#pragma unroll
  for (int mt = 0; mt < 2; ++mt)
#pragma unroll
    for (int rr = 0; rr < 4; ++rr)
      R[wv * 512 + (mt * 4 + rr) * 64 + lane] = acc[mt][rr];
  __syncthreads();
  {
    float s = R[tid];
#pragma unroll
    for (int w = 1; w < 8; ++w) s += R[w * 512 + tid];
    R[tid] = s;
  }
  __syncthreads();
  if (tid < 128) {
    const int ml = tid >> 2, dl = tid & 3;
    const int m = mh * 32 + ml;
    const int d = nt * 4 + dl;
    const int mt = ml >> 4, qd = (ml >> 2) & 3, rr = ml & 3;
    float g4[4];
#pragma unroll
    for (int g = 0; g < 4; ++g) {
      const int cv = dl * 4 + g;
      const int r = nt * 16 + cv;
      const float s = R[(mt * 4 + rr) * 64 + qd * 16 + cv];
      g4[g] = s + bcat[r] + hwhh[(size_t)m * NE + r] +
              embw[((size_t)t * NB + m) * NE + r];
    }
    const float iv = sigmoidf_(g4[0]);
    const float fv = sigmoidf_(g4[1]);
    const float gv = tanhf(g4[2]);
    const float ov = sigmoidf_(g4[3]);
    const float cold = cst[(size_t)m * ND + d];
    const float cn = fv * cold + iv * gv;
    const float hn = ov * tanhf(cn);
    hnew16[(size_t)m * ND + d] = (f16)hn;
    hseq[((size_t)t * NB + m) * ND + d] = (f16)hn;
    if (t < declen[m]) {
      cst[(size_t)m * ND + d] = cn;
      h16[(size_t)m * ND + d] = (f16)hn;
    }
  }
}

}  // namespace

extern "C" void kernel_launch(void* const* d_in, const int* in_sizes, int n_in,
                              void* d_out, int out_size, void* d_ws, size_t ws_size,
                              hipStream_t stream) {
  const float* enc        = (const float*)d_in[0];
  const int*   caps       = (const int*)d_in[1];
  const int*   caplen     = (const int*)d_in[2];
  const float* emb        = (const float*)d_in[3];
  const float* enc_att_W  = (const float*)d_in[4];
  const float* enc_att_b  = (const float*)d_in[5];
  const float* dec_att_W  = (const float*)d_in[6];
  const float* dec_att_b  = (const float*)d_in[7];
  const float* full_att_W = (const float*)d_in[8];
  // d_in[9] full_att_b: shift-invariant under softmax, unused.
  const float* init_h_W   = (const float*)d_in[10];
  const float* init_h_b   = (const float*)d_in[11];
  const float* init_c_W   = (const float*)d_in[12];
  const float* init_c_b   = (const float*)d_in[13];
  const float* f_beta_W   = (const float*)d_in[14];
  const float* f_beta_b   = (const float*)d_in[15];
  const float* W_ih       = (const float*)d_in[16];
  const float* b_ih       = (const float*)d_in[17];
  const float* W_hh       = (const float*)d_in[18];
  const float* b_hh       = (const float*)d_in[19];
  const float* fc_W       = (const float*)d_in[20];
  const float* fc_b       = (const float*)d_in[21];

  char* ws = (char*)d_ws;
  f16*   att1   = (f16*)(ws + OFF_ATT1);
  f16*   daWt   = (f16*)(ws + OFF_DAW);
  f16*   fbWt   = (f16*)(ws + OFF_FBW);
  f16*   eaWt   = (f16*)(ws + OFF_EAW);
  f16*   ihWt   = (f16*)(ws + OFF_IHW);
  f16*   icWt   = (f16*)(ws + OFF_ICW);
  f16*   fcWt   = (f16*)(ws + OFF_FCW);   // aliases eaWt/ihWt/icWt (written after)
  f16*   Wcat2  = (f16*)(ws + OFF_WCAT);
  f16*   mean16 = (f16*)(ws + OFF_MEAN16);
  f16*   h16    = (f16*)(ws + OFF_H16);
  f16*   hnew16 = (f16*)(ws + OFF_HNEW16);
  float* cst    = (float*)(ws + OFF_C);
  float* att2   = (float*)(ws + OFF_ATT2);
  float* gate   = (float*)(ws + OFF_GATE);
  float* alpha  = (float*)(ws + OFF_ALPHA);
  f16*   xcat   = (f16*)(ws + OFF_XCAT);
  int*   wsi    = (int*)(ws + OFF_INT);
  int*   perm   = wsi;
  int*   declen = wsi + 64;
  int*   caps_s = wsi + 128;
  float* bcat   = (float*)(ws + OFF_BCAT);
  f16*   enc16  = (f16*)(ws + OFF_ENC16);
  float* hwhh   = (float*)(ws + OFF_HWHH);
  float* embw   = (float*)(ws + OFF_EMBW);
  f16*   embs16 = (f16*)(ws + OFF_EMBS);

  const bool full  = ws_size >= FULL_BYTES;
  const bool batch = ws_size >= FULL2_BYTES;
  const bool full3 = ws_size >= FULL3_BYTES;
  f16* hseq = batch ? (f16*)(ws + OFF_HSEQ) : (f16*)nullptr;

  // cooperative-launch capability check (host-side queries only; graph-safe)
  bool coop_ok = false;
  int coop_grid = 0;
  if (full3) {
    int dev = 0;
    if (hipGetDevice(&dev) == hipSuccess) {
      int coop = 0;
      hipDeviceGetAttribute(&coop, hipDeviceAttributeCooperativeLaunch, dev);
      if (coop) {
        int ncu = 0;
        hipDeviceGetAttribute(&ncu, hipDeviceAttributeMultiprocessorCount, dev);
        int maxb = 0;
        if (hipOccupancyMaxActiveBlocksPerMultiprocessor(
                &maxb, reinterpret_cast<const void*>(&k_steps3), 512, 0) == hipSuccess &&
            maxb >= 1 && ncu > 0) {
          coop_grid = maxb * ncu;
          if (coop_grid > 256) coop_grid = 256;
          coop_ok = coop_grid >= 64;
        }
      }
    }
  }

  float* out         = (float*)d_out;
  float* out_pred    = out;
  float* out_caps    = out_pred + (size_t)NB * NTD * NV;
  float* out_declen  = out_caps + (size_t)NB * NT_CAP;
  float* out_alphas  = out_declen + NB;
  float* out_sortind = out_alphas + (size_t)NB * NTD * NP;

  k_sort<<<1, 64, 0, stream>>>(caplen, caps, perm, declen, caps_s,
                               out_caps, out_declen, out_sortind);
  k_tconv3<<<dim3(16, 64, 3), 256, 0, stream>>>(enc_att_W, eaWt, init_h_W, ihWt,
                                                init_c_W, icWt);
  k_tconv2b<<<dim3(80, 16), 256, 0, stream>>>(dec_att_W, daWt, f_beta_W, fbWt);
  if (full) {
    k_enc_cvt<<<dim3(196, 64), 256, 0, stream>>>(enc, perm, enc16);
    k_mean16<<<dim3(4, 64), 256, 0, stream>>>(enc16, mean16);
  } else {
    k_mean<<<dim3(4, 64), 256, 0, stream>>>(enc, perm, mean16);
  }
  k_init_mfma<<<dim3(16, 2), 256, 0, stream>>>(mean16, ihWt, icWt, init_h_b, init_c_b,
                                               h16, cst);
  if (full)
    k_att1_v3<<<dim3(98, 4), 256, 0, stream>>>(enc16, eaWt, enc_att_b, att1);
  else
    k_att1_mfma<false><<<dim3(4, 196), 256, 0, stream>>>(enc, enc16, perm, eaWt,
                                                         enc_att_b, att1);
  // fcWt write ALIASES eaWt/ihWt/icWt — must come after k_init/k_att1 (stream order).
  k_tconv<<<dim3(314, 16), 256, 0, stream>>>(fc_W, fcWt, 512, NV);
  k_cvt_wcat2<<<2048, 256, 0, stream>>>(W_ih, W_hh, b_ih, b_hh, Wcat2, bcat);
  if (full3) {
    k_embs<<<dim3(NTD, NB), 256, 0, stream>>>(emb, caps_s, embs16);
    k_embw<<<dim3(32, 5), 256, 0, stream>>>(embs16, Wcat2, embw);
  }

  if (full3 && coop_ok) {
    Step3Params P;
    P.h16 = h16; P.daWt = daWt; P.dab = dec_att_b; P.fbWt = fbWt; P.fbb = f_beta_b;
    P.Wcat2 = Wcat2; P.bcat = bcat; P.att1 = att1; P.fullW = full_att_W;
    P.enc16 = enc16; P.embw = embw; P.declen = declen;
    P.att2 = att2; P.gate = gate;
    P.out_alphas = out_alphas; P.xcat = xcat; P.cst = cst; P.hseq = hseq;
    void* args[] = { &P };
    hipLaunchCooperativeKernel(reinterpret_cast<const void*>(&k_steps3),
                               dim3(coop_grid), dim3(512), args, 0, stream);
    k_fc_v2<<<dim3(157, 5), 256, 0, stream>>>(hseq, fcWt, fc_b, declen, out_pred);
  } else if (full3) {
    for (int t = 0; t < NTD; ++t) {
      k_hall<<<288, 256, 0, stream>>>(h16, daWt, dec_att_b, fbWt, f_beta_b, Wcat2,
                                      att2, gate, hwhh);
      k_logits<<<NB, 512, 0, stream>>>(att1, att2, full_att_W, declen, t,
                                       alpha, out_alphas);
      k_awe<<<256, 256, 0, stream>>>(enc16, alpha, gate, xcat);
      k_xlstm_v3<<<256, 512, 0, stream>>>(xcat, Wcat2, bcat, hwhh, embw, declen, t,
                                          cst, h16, hnew16, hseq);
    }
    k_fc_v2<<<dim3(157, 5), 256, 0, stream>>>(hseq, fcWt, fc_b, declen, out_pred);
  } else {
    for (int t = 0; t < NTD; ++t) {
      k_hgemm_v2<<<80, 256, 0, stream>>>(h16, daWt, dec_att_b, fbWt, f_beta_b,
                                         att2, gate);
      if (full)
        k_attn_awe<true><<<NB, 512, 0, stream>>>(att1, att2, full_att_W, declen, t,
                                                 enc, enc16, perm, gate, emb, caps_s,
                                                 h16, xcat, out_alphas);
      else
        k_attn_awe<false><<<NB, 512, 0, stream>>>(att1, att2, full_att_W, declen, t,
                                                  enc, enc16, perm, gate, emb, caps_s,
                                                  h16, xcat, out_alphas);
      k_xlstm_v2<<<128, 512, 0, stream>>>(xcat, Wcat2, bcat, declen, t,
                                          cst, h16, hnew16, hseq);
      if (!batch)
        k_fc_mfma<<<157, 256, 0, stream>>>(hnew16, fcWt, fc_b, declen, t, out_pred);
    }
    if (batch)
      k_fc_v2<<<dim3(157, 5), 256, 0, stream>>>(hseq, fcWt, fc_b, declen, out_pred);
  }
}

// Round 7
// 1288.058 us; speedup vs baseline: 3.9714x; 1.0037x over previous
//
#include <hip/hip_runtime.h>
#include <hip/hip_cooperative_groups.h>
#include <cstddef>

// ---------------------------------------------------------------------------
// DecoderWithAttention forward — Round 11.
// vs R10 (1293): cross-round evidence (80-launch loop, 4-phase coop, 3-phase
// coop all ≈50 µs/step) says phase INTERIORS dominate, not sync/launch.
// Arithmetic: P2 awe = 98 sequential f16x2 loads -> ~5 B/cyc/CU ≈ 16 µs/step.
// R11 = R10 skeleton with ILP'd P2 loops:
//  - awe: f16x4 loads, 4-way p-split (128thr x 4ch), 4 accumulator streams.
//  - logits: 2-stream manual unroll (p, p+8 pairs).
// Everything else identical to R10 (validated, absmax 0.5089722).
// ---------------------------------------------------------------------------

namespace cg = cooperative_groups;

namespace {

typedef _Float16 f16;
typedef f16 f16x8 __attribute__((ext_vector_type(8)));
typedef f16 f16x4 __attribute__((ext_vector_type(4)));
typedef f16 f16x2 __attribute__((ext_vector_type(2)));
typedef float f32x4 __attribute__((ext_vector_type(4)));

constexpr int NB = 64, NP = 196, NE = 2048, NA = 512, ND = 512, NV = 10000;
constexpr int NT_CAP = 21, NTD = 20;
constexpr int KC = 3072;   // xcat K: 512 emb + 2048 awe + 512 h
constexpr int LDT = 40;    // LDS row stride (f16) for legacy kernels
constexpr int LDK = 72;    // LDS row stride (f16) for BK=64 tiles (pad 8)

// ---- workspace byte offsets ----
constexpr size_t OFF_ATT1   = 0;           // f16 [12544][512]
constexpr size_t OFF_DAW    = 12845056;    // f16 [512][512]
constexpr size_t OFF_FBW    = 13369344;    // f16 [2048][512]
constexpr size_t OFF_EAW    = 15466496;    // f16 [512][2048]   (preamble only)
constexpr size_t OFF_IHW    = 17563648;    // f16 [512][2048]   (preamble only)
constexpr size_t OFF_ICW    = 19660800;    // f16 [512][2048]   (preamble only)
constexpr size_t OFF_FCW    = 15466496;    // f16 [10048][512]  ALIASES eaW/ihW/icW
constexpr size_t OFF_WCAT   = 25755648;    // f16 [2048][3072]  rows r = d*4+g
constexpr size_t OFF_MEAN16 = 38338560;    // f16 [64][2048]
constexpr size_t OFF_H16    = 38600704;    // f16 [64][512]
constexpr size_t OFF_HNEW16 = 38666240;    // f16 [64][512]
constexpr size_t OFF_C      = 38731776;    // f32 [64][512]
constexpr size_t OFF_ATT2   = 38862848;    // f32 [64][512]
constexpr size_t OFF_GATE   = 38993920;    // f32 [64][2048]
constexpr size_t OFF_ALPHA  = 39518208;    // f32 [64][200]
constexpr size_t OFF_XCAT   = 39569408;    // f16 [64][3072]
constexpr size_t OFF_INT    = 39962624;    // perm/declen/caps (8 KB)
constexpr size_t OFF_BCAT   = 39970816;    // f32 [2048] combined lstm bias, permuted
constexpr size_t OFF_ENC16  = 39979008;    // f16 [64][196][2048] (optional)
constexpr size_t FULL_BYTES = 91359232;
constexpr size_t OFF_HSEQ   = FULL_BYTES;  // f16 [20][64][512] (optional)
constexpr size_t FULL2_BYTES = FULL_BYTES + (size_t)NTD * NB * ND * 2;  // 92669952
constexpr size_t OFF_HWHH   = FULL2_BYTES;             // f32 [64][2048]   524288 B
constexpr size_t OFF_EMBW   = OFF_HWHH + 524288;       // f32 [1280][2048] 10485760 B
constexpr size_t OFF_EMBS   = OFF_EMBW + 10485760;     // f16 [1280][512]  1310720 B
constexpr size_t FULL3_BYTES = OFF_EMBS + 1310720;     // 104990720

__device__ __forceinline__ float sigmoidf_(float x) { return 1.0f / (1.0f + expf(-x)); }

// stage 64 rows x 32 k of f16 into LDS (256 threads, 16 B each)
__device__ __forceinline__ void stage16(const f16* __restrict__ src, int lda, int k0,
                                        f16* __restrict__ lds, int tid) {
  const int row = tid >> 2, seg = tid & 3;
  *(f16x8*)&lds[row * LDT + seg * 8] =
      *(const f16x8*)&src[(size_t)row * lda + k0 + seg * 8];
}

// convert 8 consecutive fp32 -> 8 f16 at dst
__device__ __forceinline__ void cvt8(const float* __restrict__ p, f16* __restrict__ dst) {
  const float4 a = *(const float4*)p;
  const float4 b = *(const float4*)(p + 4);
  f16x8 v;
  v[0] = (f16)a.x; v[1] = (f16)a.y; v[2] = (f16)a.z; v[3] = (f16)a.w;
  v[4] = (f16)b.x; v[5] = (f16)b.y; v[6] = (f16)b.z; v[7] = (f16)b.w;
  *(f16x8*)dst = v;
}

// Barrier-free wave GEMM: 64m x 16n tile, equal A/B stride K.
__device__ __forceinline__ void wave_gemm64(const f16* __restrict__ A,
                                            const f16* __restrict__ Brow, int K,
                                            int kbeg, int kend,
                                            int col, int quad, f32x4* acc) {
  for (int k0 = kbeg; k0 < kend; k0 += 32) {
    const int kk = k0 + quad * 8;
    const f16x8 b = *(const f16x8*)&Brow[(size_t)col * K + kk];
#pragma unroll
    for (int mt = 0; mt < 4; ++mt) {
      const f16x8 a = *(const f16x8*)&A[(size_t)(mt * 16 + col) * K + kk];
      acc[mt] = __builtin_amdgcn_mfma_f32_16x16x32_f16(a, b, acc[mt], 0, 0, 0);
    }
  }
}

// Strided variant: separate A/B leading dims, MT m-tiles.
template <int MT>
__device__ __forceinline__ void wave_gemm_s(const f16* __restrict__ A, int lda,
                                            const f16* __restrict__ Brow, int ldb,
                                            int kbeg, int kend,
                                            int col, int quad, f32x4* acc) {
  for (int k0 = kbeg; k0 < kend; k0 += 32) {
    const int kk = k0 + quad * 8;
    const f16x8 b = *(const f16x8*)&Brow[(size_t)col * ldb + kk];
#pragma unroll
    for (int mt = 0; mt < MT; ++mt) {
      const f16x8 a = *(const f16x8*)&A[(size_t)(mt * 16 + col) * lda + kk];
      acc[mt] = __builtin_amdgcn_mfma_f32_16x16x32_f16(a, b, acc[mt], 0, 0, 0);
    }
  }
}

// ---------------------------------------------------------------------------
// K1: stable descending argsort + gathered caps/declen/sortind outputs.
// ---------------------------------------------------------------------------
__global__ void k_sort(const int* __restrict__ cap_len, const int* __restrict__ caps,
                       int* __restrict__ perm, int* __restrict__ declen,
                       int* __restrict__ caps_sorted,
                       float* __restrict__ out_caps, float* __restrict__ out_declen,
                       float* __restrict__ out_sortind) {
  __shared__ int cl[NB];
  __shared__ int pr[NB];
  const int i = threadIdx.x;
  int c = cap_len[i];
  if (c < 1) c = 1;
  cl[i] = c;
  __syncthreads();
  int rank = 0;
  for (int j = 0; j < NB; ++j) {
    const int cj = cl[j];
    if (cj > c || (cj == c && j < i)) rank++;
  }
  pr[rank] = i;
  __syncthreads();
  const int src = pr[i];
  perm[i] = src;
  const int dl = cl[src] - 1;
  declen[i] = dl;
  out_declen[i] = (float)dl;
  out_sortind[i] = (float)src;
  for (int j = 0; j < NT_CAP; ++j) {
    const int v = caps[src * NT_CAP + j];
    caps_sorted[i * NT_CAP + j] = v;
    out_caps[i * NT_CAP + j] = (float)v;
  }
}

// ---------------------------------------------------------------------------
// K2: transpose-convert fp32 [K][Nsrc] (K-major) -> f16 [N][K]; zero if n>=Nsrc.
// ---------------------------------------------------------------------------
__global__ __launch_bounds__(256) void k_tconv(const float* __restrict__ src,
                                               f16* __restrict__ dst, int K, int Nsrc) {
  __shared__ float tile[32][33];
  const int n0 = blockIdx.x * 32, k0 = blockIdx.y * 32;
  const int tid = threadIdx.x;
  const int a = tid & 31, q = tid >> 5;
#pragma unroll
  for (int r = 0; r < 4; ++r) {
    const int kl = q * 4 + r;
    tile[a][kl] = (n0 + a < Nsrc) ? src[(size_t)(k0 + kl) * Nsrc + n0 + a] : 0.0f;
  }
  __syncthreads();
#pragma unroll
  for (int r = 0; r < 4; ++r) {
    const int nl = q * 4 + r;
    dst[(size_t)(n0 + nl) * K + k0 + a] = (f16)tile[nl][a];
  }
}

// K2f3: three K=2048/Nsrc=512 tconvs in one launch. grid (16, 64, 3).
__global__ __launch_bounds__(256) void k_tconv3(const float* __restrict__ s0, f16* d0,
                                                const float* __restrict__ s1, f16* d1,
                                                const float* __restrict__ s2, f16* d2) {
  __shared__ float tile[32][33];
  const float* src = (blockIdx.z == 0) ? s0 : (blockIdx.z == 1) ? s1 : s2;
  f16* dst = (blockIdx.z == 0) ? d0 : (blockIdx.z == 1) ? d1 : d2;
  const int n0 = blockIdx.x * 32, k0 = blockIdx.y * 32;
  const int tid = threadIdx.x;
  const int a = tid & 31, q = tid >> 5;
#pragma unroll
  for (int r = 0; r < 4; ++r) {
    const int kl = q * 4 + r;
    tile[a][kl] = src[(size_t)(k0 + kl) * 512 + n0 + a];
  }
  __syncthreads();
#pragma unroll
  for (int r = 0; r < 4; ++r) {
    const int nl = q * 4 + r;
    dst[(size_t)(n0 + nl) * 2048 + k0 + a] = (f16)tile[nl][a];
  }
}

// K2f2: dec_att (16 x-tiles) + f_beta (64 x-tiles), K=512. grid (80, 16).
__global__ __launch_bounds__(256) void k_tconv2b(const float* __restrict__ sd, f16* dd,
                                                 const float* __restrict__ sf, f16* df) {
  __shared__ float tile[32][33];
  const bool is_d = blockIdx.x < 16;
  const float* src = is_d ? sd : sf;
  f16* dst = is_d ? dd : df;
  const int nsrc = is_d ? 512 : 2048;
  const int n0 = (is_d ? blockIdx.x : (blockIdx.x - 16)) * 32, k0 = blockIdx.y * 32;
  const int tid = threadIdx.x;
  const int a = tid & 31, q = tid >> 5;
#pragma unroll
  for (int r = 0; r < 4; ++r) {
    const int kl = q * 4 + r;
    tile[a][kl] = src[(size_t)(k0 + kl) * nsrc + n0 + a];
  }
  __syncthreads();
#pragma unroll
  for (int r = 0; r < 4; ++r) {
    const int nl = q * 4 + r;
    dst[(size_t)(n0 + nl) * 512 + k0 + a] = (f16)tile[nl][a];
  }
}

// ---------------------------------------------------------------------------
// K2b: permuted Wcat: row r = d*4+g <-> original n = g*512+d.
// ---------------------------------------------------------------------------
__global__ __launch_bounds__(256) void k_cvt_wcat2(const float* __restrict__ Wih,
                                                   const float* __restrict__ Whh,
                                                   const float* __restrict__ bih,
                                                   const float* __restrict__ bhh,
                                                   f16* __restrict__ Wcat2,
                                                   float* __restrict__ bcat) {
  const int r = blockIdx.x;
  const int d = r >> 2, g = r & 3;
  const int n = g * 512 + d;
  for (int k = threadIdx.x; k < KC; k += 256) {
    const float v = (k < 2560) ? Wih[(size_t)n * 2560 + k] : Whh[(size_t)n * 512 + (k - 2560)];
    Wcat2[(size_t)r * KC + k] = (f16)v;
  }
  if (threadIdx.x == 0) bcat[r] = bih[n] + bhh[n];
}

// ---------------------------------------------------------------------------
// K3 (!full): mean over P of sorted encoder rows -> mean16. grid (4, 64).
// ---------------------------------------------------------------------------
__global__ __launch_bounds__(256) void k_mean(const float* __restrict__ enc,
                                              const int* __restrict__ perm,
                                              f16* __restrict__ mean16) {
  const int b = blockIdx.y;
  const int c0 = blockIdx.x * 512 + threadIdx.x * 2;
  const float* base = enc + (size_t)perm[b] * NP * NE + c0;
  float a0 = 0.0f, a1 = 0.0f;
  for (int p = 0; p < NP; ++p) {
    const float2 v = *(const float2*)&base[(size_t)p * NE];
    a0 += v.x; a1 += v.y;
  }
  mean16[(size_t)b * NE + c0] = (f16)(a0 * (1.0f / (float)NP));
  mean16[(size_t)b * NE + c0 + 1] = (f16)(a1 * (1.0f / (float)NP));
}

// K3b (full): mean from enc16 (f16, already permuted).
__global__ __launch_bounds__(256) void k_mean16(const f16* __restrict__ enc16,
                                                f16* __restrict__ mean16) {
  const int b = blockIdx.y;
  const int c0 = blockIdx.x * 512 + threadIdx.x * 2;
  const f16* base = enc16 + (size_t)b * NP * NE + c0;
  float a0 = 0.0f, a1 = 0.0f;
  for (int p = 0; p < NP; ++p) {
    const f16x2 v = *(const f16x2*)&base[(size_t)p * NE];
    a0 += (float)v[0]; a1 += (float)v[1];
  }
  mean16[(size_t)b * NE + c0] = (f16)(a0 * (1.0f / (float)NP));
  mean16[(size_t)b * NE + c0 + 1] = (f16)(a1 * (1.0f / (float)NP));
}

// ---------------------------------------------------------------------------
// K4 (FULL only): enc16[b][p][c] = f16(enc[perm[b]][p][c]). grid (196, 64).
// ---------------------------------------------------------------------------
__global__ __launch_bounds__(256) void k_enc_cvt(const float* __restrict__ enc,
                                                 const int* __restrict__ perm,
                                                 f16* __restrict__ enc16) {
  const int p = blockIdx.x, b = blockIdx.y;
  const float* src = enc + ((size_t)perm[b] * NP + p) * NE;
  f16* dst = enc16 + ((size_t)b * NP + p) * NE;
  const int i0 = threadIdx.x * 8;
  cvt8(src + i0, dst + i0);
}

// ---------------------------------------------------------------------------
// K4b (full3): embs16[t][b][e] = f16(emb[caps_s[b][t]][e]). grid (20, 64).
// ---------------------------------------------------------------------------
__global__ __launch_bounds__(256) void k_embs(const float* __restrict__ emb,
                                              const int* __restrict__ caps_s,
                                              f16* __restrict__ embs16) {
  const int t = blockIdx.x, b = blockIdx.y;
  const int cap = caps_s[b * NT_CAP + t];
  const int i0 = threadIdx.x * 2;
  const float2 v = *(const float2*)(emb + (size_t)cap * 512 + i0);
  f16x2 ev; ev[0] = (f16)v.x; ev[1] = (f16)v.y;
  *(f16x2*)&embs16[((size_t)t * NB + b) * 512 + i0] = ev;
}

// ---------------------------------------------------------------------------
// K4c (full3): embw = embs16 @ Wcat2[:, 0:512]^T. M=1280, N=2048, K=512.
// ---------------------------------------------------------------------------
__global__ __launch_bounds__(256) void k_embw(const f16* __restrict__ embs16,
                                              const f16* __restrict__ Wcat2,
                                              float* __restrict__ embw) {
  __shared__ __align__(16) f16 lA[256 * LDK];
  __shared__ __align__(16) f16 lB[64 * LDK];
  const int n0 = blockIdx.x * 64, m0 = blockIdx.y * 256;
  const int tid = threadIdx.x, lane = tid & 63, wv = tid >> 6;
  const int col = lane & 15, quad = lane >> 4;
  const f16* gA = embs16 + (size_t)(m0 + tid) * 512;
  const f16* gB = Wcat2 + (size_t)(n0 + (tid >> 2)) * KC + (tid & 3) * 16;
  f16* wA = &lA[tid * LDK];
  f16* wB = &lB[(tid >> 2) * LDK + (tid & 3) * 16];
  f32x4 acc[4][4] = {};
  for (int k0 = 0; k0 < 512; k0 += 64) {
#pragma unroll
    for (int u = 0; u < 8; ++u)
      *(f16x8*)(wA + u * 8) = *(const f16x8*)(gA + k0 + u * 8);
    *(f16x8*)(wB)     = *(const f16x8*)(gB + k0);
    *(f16x8*)(wB + 8) = *(const f16x8*)(gB + k0 + 8);
    __syncthreads();
#pragma unroll
    for (int kh = 0; kh < 2; ++kh) {
      f16x8 a[4], b[4];
#pragma unroll
      for (int i = 0; i < 4; ++i)
        a[i] = *(const f16x8*)&lA[(wv * 64 + i * 16 + col) * LDK + kh * 32 + quad * 8];
#pragma unroll
      for (int j = 0; j < 4; ++j)
        b[j] = *(const f16x8*)&lB[(j * 16 + col) * LDK + kh * 32 + quad * 8];
#pragma unroll
      for (int i = 0; i < 4; ++i)
#pragma unroll
        for (int j = 0; j < 4; ++j)
          acc[i][j] = __builtin_amdgcn_mfma_f32_16x16x32_f16(a[i], b[j], acc[i][j], 0, 0, 0);
    }
    __syncthreads();
  }
#pragma unroll
  for (int j = 0; j < 4; ++j) {
    const int n = n0 + j * 16 + col;
#pragma unroll
    for (int i = 0; i < 4; ++i)
#pragma unroll
      for (int rr = 0; rr < 4; ++rr) {
        const int r = m0 + wv * 64 + i * 16 + quad * 4 + rr;
        embw[(size_t)r * NE + n] = acc[i][j][rr];
      }
  }
}

// ---------------------------------------------------------------------------
// K5: h0/c0 = tanh(mean @ W + b), barrier-free direct MFMA. grid (16, 2).
// ---------------------------------------------------------------------------
__global__ __launch_bounds__(256) void k_init_mfma(const f16* __restrict__ mean16,
                                                   const f16* __restrict__ ihWt,
                                                   const f16* __restrict__ icWt,
                                                   const float* __restrict__ ihb,
                                                   const float* __restrict__ icb,
                                                   f16* __restrict__ h16,
                                                   float* __restrict__ cst) {
  const int which = blockIdx.y;
  const f16* Wt = which ? icWt : ihWt;
  const float* bias = which ? icb : ihb;
  const int tid = threadIdx.x, lane = tid & 63, wv = tid >> 6;
  const int col = lane & 15, quad = lane >> 4;
  const int nt = blockIdx.x * 4 + wv;  // 0..31
  f32x4 acc[4] = {};
  wave_gemm64(mean16, Wt + (size_t)nt * 16 * NE, NE, 0, NE, col, quad, acc);
  const int n = nt * 16 + col;
#pragma unroll
  for (int mt = 0; mt < 4; ++mt) {
#pragma unroll
    for (int rr = 0; rr < 4; ++rr) {
      const int m = mt * 16 + quad * 4 + rr;
      const float v = tanhf(acc[mt][rr] + bias[n]);
      if (which == 0) h16[(size_t)m * ND + n] = (f16)v;
      else            cst[(size_t)m * ND + n] = v;
    }
  }
}

// ---------------------------------------------------------------------------
// K6 (!full fallback): att1 = enc @ enc_att_W + b. grid (4, 196), BK=32.
// ---------------------------------------------------------------------------
template <bool E16>
__global__ __launch_bounds__(256) void k_att1_mfma(const float* __restrict__ encf,
                                                   const f16* __restrict__ enc16,
                                                   const int* __restrict__ perm,
                                                   const f16* __restrict__ eaWt,
                                                   const float* __restrict__ eab,
                                                   f16* __restrict__ att1) {
  __shared__ __align__(16) f16 lA[64 * LDT];
  __shared__ __align__(16) f16 lB[128 * LDT];
  __shared__ int rowoff[64];
  const int r0 = blockIdx.y * 64;
  const int n0 = blockIdx.x * 128;
  const int tid = threadIdx.x, lane = tid & 63, wv = tid >> 6;
  const int col = lane & 15, quad = lane >> 4;
  if (!E16) {
    if (tid < 64) {
      const int r = r0 + tid;
      const int b = r / NP, p = r - b * NP;
      rowoff[tid] = (perm[b] * NP + p) * NE;
    }
    __syncthreads();
  }
  f32x4 acc[8] = {};
  for (int k0 = 0; k0 < NE; k0 += 32) {
    if (E16) {
      stage16(enc16 + (size_t)r0 * NE, NE, k0, lA, tid);
    } else {
      const int row = tid >> 2, seg = tid & 3;
      cvt8(encf + (size_t)rowoff[row] + k0 + seg * 8, &lA[row * LDT + seg * 8]);
    }
    {
      const int row0 = tid >> 2, seg = tid & 3;
#pragma unroll
      for (int u = 0; u < 2; ++u) {
        const int row = row0 + 64 * u;
        *(f16x8*)&lB[row * LDT + seg * 8] =
            *(const f16x8*)&eaWt[(size_t)(n0 + row) * NE + k0 + seg * 8];
      }
    }
    __syncthreads();
    const f16x8 a = *(const f16x8*)&lA[(wv * 16 + col) * LDT + quad * 8];
#pragma unroll
    for (int ns = 0; ns < 8; ++ns) {
      const f16x8 b = *(const f16x8*)&lB[(ns * 16 + col) * LDT + quad * 8];
      acc[ns] = __builtin_amdgcn_mfma_f32_16x16x32_f16(a, b, acc[ns], 0, 0, 0);
    }
    __syncthreads();
  }
#pragma unroll
  for (int ns = 0; ns < 8; ++ns) {
    const int n = n0 + ns * 16 + col;
#pragma unroll
    for (int rr = 0; rr < 4; ++rr) {
      const int r = r0 + wv * 16 + quad * 4 + rr;
      att1[(size_t)r * NA + n] = (f16)(acc[ns][rr] + eab[n]);
    }
  }
}

// ---------------------------------------------------------------------------
// K6v3 (full): att1 GEMM, BM=128, BN=128, BK=64, wave=64x64 (32 MFMA/K-iter).
// grid (98, 4). LDS 36.9 KB. (validated R9/R10)
// ---------------------------------------------------------------------------
__global__ __launch_bounds__(256) void k_att1_v3(const f16* __restrict__ enc16,
                                                 const f16* __restrict__ eaWt,
                                                 const float* __restrict__ eab,
                                                 f16* __restrict__ att1) {
  __shared__ __align__(16) f16 lA[128 * LDK];
  __shared__ __align__(16) f16 lB[128 * LDK];
  const int r0 = blockIdx.x * 128, n0 = blockIdx.y * 128;
  const int tid = threadIdx.x, lane = tid & 63, wv = tid >> 6;
  const int col = lane & 15, quad = lane >> 4;
  const int wr = wv >> 1, wc = wv & 1;  // wave quadrant: 64m x 64n
  const int srow = tid >> 1, sseg = (tid & 1) * 32;
  const f16* gA = enc16 + (size_t)(r0 + srow) * NE + sseg;
  const f16* gB = eaWt + (size_t)(n0 + srow) * NE + sseg;
  f16* wA = &lA[srow * LDK + sseg];
  f16* wB = &lB[srow * LDK + sseg];
  f32x4 acc[4][4] = {};
  for (int k0 = 0; k0 < NE; k0 += 64) {
#pragma unroll
    for (int u = 0; u < 4; ++u) {
      *(f16x8*)(wA + u * 8) = *(const f16x8*)(gA + k0 + u * 8);
      *(f16x8*)(wB + u * 8) = *(const f16x8*)(gB + k0 + u * 8);
    }
    __syncthreads();
#pragma unroll
    for (int kh = 0; kh < 2; ++kh) {
      f16x8 a[4], b[4];
#pragma unroll
      for (int i = 0; i < 4; ++i)
        a[i] = *(const f16x8*)&lA[(wr * 64 + i * 16 + col) * LDK + kh * 32 + quad * 8];
#pragma unroll
      for (int j = 0; j < 4; ++j)
        b[j] = *(const f16x8*)&lB[(wc * 64 + j * 16 + col) * LDK + kh * 32 + quad * 8];
#pragma unroll
      for (int i = 0; i < 4; ++i)
#pragma unroll
        for (int j = 0; j < 4; ++j)
          acc[i][j] = __builtin_amdgcn_mfma_f32_16x16x32_f16(a[i], b[j], acc[i][j], 0, 0, 0);
    }
    __syncthreads();
  }
#pragma unroll
  for (int j = 0; j < 4; ++j) {
    const int n = n0 + wc * 64 + j * 16 + col;
    const float bv = eab[n];
#pragma unroll
    for (int i = 0; i < 4; ++i)
#pragma unroll
      for (int rr = 0; rr < 4; ++rr) {
        const int r = r0 + wr * 64 + i * 16 + quad * 4 + rr;
        att1[(size_t)r * NA + n] = (f16)(acc[i][j][rr] + bv);
      }
  }
}

// ---------------------------------------------------------------------------
// K-STEPS3 (full3 + cooperative): 20-step loop, 3 grid.syncs per step.
// R11: P2 loops rebuilt for ILP (multi-stream, f16x4).
// ---------------------------------------------------------------------------
struct Step3Params {
  f16* h16;
  const f16* daWt; const float* dab;
  const f16* fbWt; const float* fbb;
  const f16* Wcat2; const float* bcat;
  const f16* att1; const float* fullW;
  const f16* enc16;
  const float* embw;
  const int* declen;
  float* att2; float* gate;
  float* out_alphas;
  f16* xcat;
  float* cst;
  f16* hseq;
};

__global__ __launch_bounds__(512, 2) void k_steps3(Step3Params P) {
  cg::grid_group grid = cg::this_grid();
  __shared__ float S[8192];  // 32 KB, reused across phases
  const int tid = threadIdx.x, lane = tid & 63, wv = tid >> 6;
  const int col = lane & 15, quad = lane >> 4;
  const int bid = blockIdx.x, nblk = gridDim.x;

  for (int t = 0; t < NTD; ++t) {
    // ===== Phase 1: hall-lite — att2 (32 tiles) + gate (128 tiles) =========
    for (int nt = bid; nt < 160; nt += nblk) {
      const f16* Brow = (nt < 32) ? (P.daWt + (size_t)nt * 16 * ND)
                                  : (P.fbWt + (size_t)(nt - 32) * 16 * ND);
      f32x4 acc[4] = {};
      wave_gemm_s<4>(P.h16, ND, Brow, ND, wv * 64, wv * 64 + 64, col, quad, acc);
#pragma unroll
      for (int mt = 0; mt < 4; ++mt)
#pragma unroll
        for (int rr = 0; rr < 4; ++rr)
          S[wv * 1024 + (mt * 4 + rr) * 64 + lane] = acc[mt][rr];
      __syncthreads();
#pragma unroll
      for (int j = 0; j < 2; ++j) {
        const int slot = tid * 2 + j;
        float s = S[slot];
#pragma unroll
        for (int w = 1; w < 8; ++w) s += S[w * 1024 + slot];
        const int c2 = slot >> 6, lane_s = slot & 63;
        const int mt = c2 >> 2, rr = c2 & 3;
        const int m = mt * 16 + (lane_s >> 4) * 4 + rr;
        const int nl = lane_s & 15;
        if (nt < 32) {
          const int n = nt * 16 + nl;
          P.att2[(size_t)m * NA + n] = s + P.dab[n];
        } else {
          const int n = (nt - 32) * 16 + nl;
          P.gate[(size_t)m * NE + n] = sigmoidf_(s + P.fbb[n]);
        }
      }
      __syncthreads();
    }
    __threadfence();
    grid.sync();

    // ===== Phase 2: (b,q) — logits + softmax + awe + xcat =================
    for (int task = bid; task < 256; task += nblk) {
      const int b = task >> 2, q = task & 3;
      // logits: wave per p, 2 independent streams (p, p+8)
      {
        float a2r[8], fwr[8];
        const float4* A2 = (const float4*)(P.att2 + (size_t)b * NA + lane * 8);
        const float4* FW = (const float4*)(P.fullW + lane * 8);
        const float4 q0 = A2[0], q1 = A2[1], w0 = FW[0], w1 = FW[1];
        a2r[0] = q0.x; a2r[1] = q0.y; a2r[2] = q0.z; a2r[3] = q0.w;
        a2r[4] = q1.x; a2r[5] = q1.y; a2r[6] = q1.z; a2r[7] = q1.w;
        fwr[0] = w0.x; fwr[1] = w0.y; fwr[2] = w0.z; fwr[3] = w0.w;
        fwr[4] = w1.x; fwr[5] = w1.y; fwr[6] = w1.z; fwr[7] = w1.w;
        const f16* abase = P.att1 + (size_t)b * NP * NA + lane * 8;
        int p = wv;
        for (; p + 8 < NP; p += 16) {
          const f16x8 r0 = *(const f16x8*)(abase + (size_t)p * NA);
          const f16x8 r1 = *(const f16x8*)(abase + (size_t)(p + 8) * NA);
          float s0 = 0.0f, s1 = 0.0f;
#pragma unroll
          for (int j = 0; j < 8; ++j) {
            s0 += fmaxf((float)r0[j] + a2r[j], 0.0f) * fwr[j];
            s1 += fmaxf((float)r1[j] + a2r[j], 0.0f) * fwr[j];
          }
#pragma unroll
          for (int off = 32; off > 0; off >>= 1) {
            s0 += __shfl_down(s0, off, 64);
            s1 += __shfl_down(s1, off, 64);
          }
          if (lane == 0) { S[p] = s0; S[p + 8] = s1; }
        }
        if (p < NP) {
          const f16x8 r0 = *(const f16x8*)(abase + (size_t)p * NA);
          float s0 = 0.0f;
#pragma unroll
          for (int j = 0; j < 8; ++j)
            s0 += fmaxf((float)r0[j] + a2r[j], 0.0f) * fwr[j];
#pragma unroll
          for (int off = 32; off > 0; off >>= 1) s0 += __shfl_down(s0, off, 64);
          if (lane == 0) S[p] = s0;
        }
      }
      __syncthreads();
      // softmax (wave 0 butterfly)
      if (wv == 0) {
        const float v0 = S[lane];
        const float v1 = S[lane + 64];
        const float v2 = S[lane + 128];
        const float v3 = (lane < 4) ? S[192 + lane] : -INFINITY;
        float mx = fmaxf(fmaxf(v0, v1), fmaxf(v2, v3));
#pragma unroll
        for (int off = 32; off > 0; off >>= 1) mx = fmaxf(mx, __shfl_xor(mx, off, 64));
        float s = expf(v0 - mx) + expf(v1 - mx) + expf(v2 - mx) +
                  ((lane < 4) ? expf(v3 - mx) : 0.0f);
#pragma unroll
        for (int off = 32; off > 0; off >>= 1) s += __shfl_xor(s, off, 64);
        if (lane == 0) { S[200] = mx; S[201] = 1.0f / s; }
      }
      __syncthreads();
      if (tid < NP) {
        const float a = expf(S[tid] - S[200]) * S[201];
        S[256 + tid] = a;  // alpha
        if (q == 0) {
          const bool act = t < P.declen[b];
          P.out_alphas[((size_t)b * NTD + t) * NP + tid] = act ? a : 0.0f;
        }
      }
      __syncthreads();
      // awe: 4-way p-split (ph), 4 ch/thread (f16x4), 4 accumulator streams
      {
        const int ph = tid >> 7;           // 0..3
        const int cl = (tid & 127) * 4;    // 0..508
        const int c = q * 512 + cl;
        const f16* base = P.enc16 + (size_t)b * NP * NE + c;
        const int p0 = ph * 49, p1 = p0 + 49;  // 4*49 = 196 = NP
        float A0[4] = {}, A1[4] = {}, A2a[4] = {}, A3[4] = {};
        int p = p0;
        for (; p + 3 < p1; p += 4) {
          const f16x4 v0 = *(const f16x4*)&base[(size_t)p * NE];
          const f16x4 v1 = *(const f16x4*)&base[(size_t)(p + 1) * NE];
          const f16x4 v2 = *(const f16x4*)&base[(size_t)(p + 2) * NE];
          const f16x4 v3 = *(const f16x4*)&base[(size_t)(p + 3) * NE];
          const float ap0 = S[256 + p], ap1 = S[256 + p + 1];
          const float ap2 = S[256 + p + 2], ap3 = S[256 + p + 3];
#pragma unroll
          for (int j = 0; j < 4; ++j) {
            A0[j] += ap0 * (float)v0[j];
            A1[j] += ap1 * (float)v1[j];
            A2a[j] += ap2 * (float)v2[j];
            A3[j] += ap3 * (float)v3[j];
          }
        }
        for (; p < p1; ++p) {
          const f16x4 v0 = *(const f16x4*)&base[(size_t)p * NE];
          const float ap0 = S[256 + p];
#pragma unroll
          for (int j = 0; j < 4; ++j) A0[j] += ap0 * (float)v0[j];
        }
#pragma unroll
        for (int j = 0; j < 4; ++j)
          S[512 + ph * 512 + cl + j] = A0[j] + A1[j] + A2a[j] + A3[j];
      }
      __syncthreads();
      // combine 4 partials + gate (global, coalesced) -> xcat mid; q==0: h tail
      if (tid < 256) {
        const int c2 = tid * 2;
        float r0 = 0.0f, r1 = 0.0f;
#pragma unroll
        for (int w = 0; w < 4; ++w) {
          r0 += S[512 + w * 512 + c2];
          r1 += S[512 + w * 512 + c2 + 1];
        }
        const int n = q * 512 + c2;
        const float2 g = *(const float2*)&P.gate[(size_t)b * NE + n];
        f16x2 o; o[0] = (f16)(r0 * g.x); o[1] = (f16)(r1 * g.y);
        *(f16x2*)&P.xcat[(size_t)b * KC + 512 + n] = o;
      } else if (q == 0) {
        const int i0 = (tid - 256) * 2;
        *(f16x2*)&P.xcat[(size_t)b * KC + 2560 + i0] =
            *(const f16x2*)&P.h16[(size_t)b * ND + i0];
      }
      __syncthreads();
    }
    __threadfence();
    grid.sync();

    // ===== Phase 3: xlstm GEMM K=512..3072 + cell epilogue =================
    for (int task = bid; task < 256; task += nblk) {
      const int nt = task >> 1, mh = task & 1;
      f32x4 acc[2] = {};
      wave_gemm_s<2>(P.xcat + (size_t)mh * 32 * KC, KC,
                     P.Wcat2 + (size_t)nt * 16 * KC, KC,
                     512 + wv * 320, 512 + wv * 320 + 320, col, quad, acc);
#pragma unroll
      for (int mt = 0; mt < 2; ++mt)
#pragma unroll
        for (int rr = 0; rr < 4; ++rr)
          S[wv * 512 + (mt * 4 + rr) * 64 + lane] = acc[mt][rr];
      __syncthreads();
      {
        float s = S[tid];
#pragma unroll
        for (int w = 1; w < 8; ++w) s += S[w * 512 + tid];
        S[tid] = s;
      }
      __syncthreads();
      if (tid < 128) {
        const int ml = tid >> 2, dl = tid & 3;
        const int m = mh * 32 + ml;
        const int d = nt * 4 + dl;
        const int mt = ml >> 4, qd = (ml >> 2) & 3, rr = ml & 3;
        float g4[4];
#pragma unroll
        for (int g = 0; g < 4; ++g) {
          const int cv = dl * 4 + g;
          const int r = nt * 16 + cv;
          g4[g] = S[(mt * 4 + rr) * 64 + qd * 16 + cv] + P.bcat[r] +
                  P.embw[((size_t)t * NB + m) * NE + r];
        }
        const float iv = sigmoidf_(g4[0]);
        const float fv = sigmoidf_(g4[1]);
        const float gv = tanhf(g4[2]);
        const float ov = sigmoidf_(g4[3]);
        const float cold = P.cst[(size_t)m * ND + d];
        const float cn = fv * cold + iv * gv;
        const float hn = ov * tanhf(cn);
        P.hseq[((size_t)t * NB + m) * ND + d] = (f16)hn;
        if (t < P.declen[m]) {
          P.cst[(size_t)m * ND + d] = cn;
          P.h16[(size_t)m * ND + d] = (f16)hn;
        }
      }
      __syncthreads();
    }
    __threadfence();
    grid.sync();
  }
}

// ---------------------------------------------------------------------------
// Fallback per-step kernels — unchanged (validated R6-R8).
// ---------------------------------------------------------------------------
__global__ __launch_bounds__(256) void k_hgemm_v2(const f16* __restrict__ h16,
                                                  const f16* __restrict__ daWt,
                                                  const float* __restrict__ dab,
                                                  const f16* __restrict__ fbWt,
                                                  const float* __restrict__ fbb,
                                                  float* __restrict__ att2,
                                                  float* __restrict__ gate) {
  __shared__ float R[2 * 64 * 16];
  const int tid = threadIdx.x, lane = tid & 63, wv = tid >> 6;
  const int col = lane & 15, quad = lane >> 4;
  const int sub = wv >> 1, kh = wv & 1;
  const int nt = blockIdx.x * 2 + sub;  // 0..159
  const bool is_att = nt < 32;
  const f16* Brow = is_att ? (daWt + (size_t)nt * 16 * ND)
                           : (fbWt + (size_t)(nt - 32) * 16 * ND);
  f32x4 acc[4] = {};
  wave_gemm64(h16, Brow, ND, kh * 256, kh * 256 + 256, col, quad, acc);
  if (kh) {
#pragma unroll
    for (int mt = 0; mt < 4; ++mt)
#pragma unroll
      for (int rr = 0; rr < 4; ++rr)
        R[(sub * 64 + lane) * 16 + mt * 4 + rr] = acc[mt][rr];
  }
  __syncthreads();
  if (kh) return;
#pragma unroll
  for (int mt = 0; mt < 4; ++mt)
#pragma unroll
    for (int rr = 0; rr < 4; ++rr)
      acc[mt][rr] += R[(sub * 64 + lane) * 16 + mt * 4 + rr];
  if (is_att) {
    const int n = nt * 16 + col;
#pragma unroll
    for (int mt = 0; mt < 4; ++mt)
#pragma unroll
      for (int rr = 0; rr < 4; ++rr) {
        const int m = mt * 16 + quad * 4 + rr;
        att2[(size_t)m * NA + n] = acc[mt][rr] + dab[n];
      }
  } else {
    const int n = (nt - 32) * 16 + col;
#pragma unroll
    for (int mt = 0; mt < 4; ++mt)
#pragma unroll
      for (int rr = 0; rr < 4; ++rr) {
        const int m = mt * 16 + quad * 4 + rr;
        gate[(size_t)m * NE + n] = sigmoidf_(acc[mt][rr] + fbb[n]);
      }
  }
}

template <bool E16>
__global__ __launch_bounds__(512) void k_attn_awe(const f16* __restrict__ att1,
                                                  const float* __restrict__ att2,
                                                  const float* __restrict__ fullW,
                                                  const int* __restrict__ declen, int t,
                                                  const float* __restrict__ encf,
                                                  const f16* __restrict__ enc16,
                                                  const int* __restrict__ perm,
                                                  const float* __restrict__ gate,
                                                  const float* __restrict__ emb,
                                                  const int* __restrict__ caps_s,
                                                  const f16* __restrict__ h16,
                                                  f16* __restrict__ xcat,
                                                  float* __restrict__ out_alphas) {
  const int b = blockIdx.x;
  const int tid = threadIdx.x, wv = tid >> 6, lane = tid & 63;
  __shared__ float e[200];
  __shared__ float al[200];
  __shared__ float red2[2];
  {
    float a2r[8], fwr[8];
    const float4* A2 = (const float4*)(att2 + (size_t)b * NA + lane * 8);
    const float4* FW = (const float4*)(fullW + lane * 8);
    const float4 q0 = A2[0], q1 = A2[1], w0 = FW[0], w1 = FW[1];
    a2r[0] = q0.x; a2r[1] = q0.y; a2r[2] = q0.z; a2r[3] = q0.w;
    a2r[4] = q1.x; a2r[5] = q1.y; a2r[6] = q1.z; a2r[7] = q1.w;
    fwr[0] = w0.x; fwr[1] = w0.y; fwr[2] = w0.z; fwr[3] = w0.w;
    fwr[4] = w1.x; fwr[5] = w1.y; fwr[6] = w1.z; fwr[7] = w1.w;
    for (int p = wv; p < NP; p += 8) {
      const f16x8 row = *(const f16x8*)(att1 + ((size_t)b * NP + p) * NA + lane * 8);
      float acc = 0.0f;
#pragma unroll
      for (int j = 0; j < 8; ++j) acc += fmaxf((float)row[j] + a2r[j], 0.0f) * fwr[j];
#pragma unroll
      for (int off = 32; off > 0; off >>= 1) acc += __shfl_down(acc, off, 64);
      if (lane == 0) e[p] = acc;
    }
  }
  __syncthreads();
  if (wv == 0) {
    const float v0 = e[lane];
    const float v1 = e[lane + 64];
    const float v2 = e[lane + 128];
    const float v3 = (lane < 4) ? e[192 + lane] : -INFINITY;
    float mx = fmaxf(fmaxf(v0, v1), fmaxf(v2, v3));
#pragma unroll
    for (int off = 32; off > 0; off >>= 1) mx = fmaxf(mx, __shfl_xor(mx, off, 64));
    float s = expf(v0 - mx) + expf(v1 - mx) + expf(v2 - mx) +
              ((lane < 4) ? expf(v3 - mx) : 0.0f);
#pragma unroll
    for (int off = 32; off > 0; off >>= 1) s += __shfl_xor(s, off, 64);
    if (lane == 0) { red2[0] = mx; red2[1] = 1.0f / s; }
  }
  __syncthreads();
  {
    const float mx = red2[0], inv = red2[1];
    if (tid < NP) {
      const float a = expf(e[tid] - mx) * inv;
      al[tid] = a;
      const bool act = t < declen[b];
      out_alphas[((size_t)b * NTD + t) * NP + tid] = act ? a : 0.0f;
    }
  }
  __syncthreads();
  {
    const int c = tid * 4;
    float a0 = 0.0f, a1 = 0.0f, a2 = 0.0f, a3 = 0.0f;
    if (E16) {
      const f16* base = enc16 + (size_t)b * NP * NE + c;
      for (int p = 0; p < NP; ++p) {
        const f16x4 v = *(const f16x4*)&base[(size_t)p * NE];
        const float ap = al[p];
        a0 += ap * (float)v[0]; a1 += ap * (float)v[1];
        a2 += ap * (float)v[2]; a3 += ap * (float)v[3];
      }
    } else {
      const float* base = encf + (size_t)perm[b] * NP * NE + c;
      for (int p = 0; p < NP; ++p) {
        const float4 v = *(const float4*)&base[(size_t)p * NE];
        const float ap = al[p];
        a0 += ap * v.x; a1 += ap * v.y; a2 += ap * v.z; a3 += ap * v.w;
      }
    }
    const float4 g = *(const float4*)&gate[(size_t)b * NE + c];
    f16x4 o;
    o[0] = (f16)(a0 * g.x); o[1] = (f16)(a1 * g.y);
    o[2] = (f16)(a2 * g.z); o[3] = (f16)(a3 * g.w);
    *(f16x4*)&xcat[(size_t)b * KC + 512 + c] = o;
  }
  if (tid < 256) {
    const int cap = caps_s[b * NT_CAP + t];
    const int i0 = tid * 2;
    const float2 v = *(const float2*)(emb + (size_t)cap * 512 + i0);
    f16x2 ev; ev[0] = (f16)v.x; ev[1] = (f16)v.y;
    *(f16x2*)&xcat[(size_t)b * KC + i0] = ev;
    *(f16x2*)&xcat[(size_t)b * KC + 2560 + i0] = *(const f16x2*)&h16[(size_t)b * ND + i0];
  }
}

__global__ __launch_bounds__(512) void k_xlstm_v2(const f16* __restrict__ xcat,
                                                  const f16* __restrict__ Wcat2,
                                                  const float* __restrict__ bcat,
                                                  const int* __restrict__ declen, int t,
                                                  float* __restrict__ cst,
                                                  f16* __restrict__ h16,
                                                  f16* __restrict__ hnew16,
                                                  f16* __restrict__ hseq) {
  __shared__ float R[8 * 64 * 16];
  const int nt = blockIdx.x;
  const int tid = threadIdx.x, lane = tid & 63, wv = tid >> 6;
  const int col = lane & 15, quad = lane >> 4;
  f32x4 acc[4] = {};
  wave_gemm64(xcat, Wcat2 + (size_t)nt * 16 * KC, KC, wv * 384, wv * 384 + 384,
              col, quad, acc);
#pragma unroll
  for (int mt = 0; mt < 4; ++mt)
#pragma unroll
    for (int rr = 0; rr < 4; ++rr)
      R[(wv * 64 + lane) * 16 + mt * 4 + rr] = acc[mt][rr];
  __syncthreads();
  {
    const int j0 = tid * 2;
#pragma unroll
    for (int j = 0; j < 2; ++j) {
      const int e2 = j0 + j;
      float s = R[e2];
#pragma unroll
      for (int w = 1; w < 8; ++w) s += R[w * 1024 + e2];
      R[e2] = s;
    }
  }
  __syncthreads();
  if (tid < 256) {
    const int m = tid >> 2, dl = tid & 3;
    const int mt = m >> 4, qd = (m >> 2) & 3, rr = m & 3;
    float g4[4];
#pragma unroll
    for (int g = 0; g < 4; ++g) {
      const int cv = dl * 4 + g;
      g4[g] = R[(qd * 16 + cv) * 16 + mt * 4 + rr] + bcat[nt * 16 + cv];
    }
    const int d = nt * 4 + dl;
    const float iv = sigmoidf_(g4[0]);
    const float fv = sigmoidf_(g4[1]);
    const float gv = tanhf(g4[2]);
    const float ov = sigmoidf_(g4[3]);
    const float cold = cst[(size_t)m * ND + d];
    const float cn = fv * cold + iv * gv;
    const float hn = ov * tanhf(cn);
    hnew16[(size_t)m * ND + d] = (f16)hn;
    if (hseq) hseq[((size_t)t * NB + m) * ND + d] = (f16)hn;
    if (t < declen[m]) {
      cst[(size_t)m * ND + d] = cn;
      h16[(size_t)m * ND + d] = (f16)hn;
    }
  }
}

__global__ __launch_bounds__(256) void k_fc_mfma(const f16* __restrict__ hnew16,
                                                 const f16* __restrict__ fcWt,
                                                 const float* __restrict__ fcb,
                                                 const int* __restrict__ declen, int t,
                                                 float* __restrict__ out_pred) {
  const int tid = threadIdx.x, lane = tid & 63, wv = tid >> 6;
  const int col = lane & 15, quad = lane >> 4;
  const int nt = blockIdx.x * 4 + wv;  // 0..627
  f32x4 acc[4] = {};
  wave_gemm64(hnew16, fcWt + (size_t)nt * 16 * ND, ND, 0, ND, col, quad, acc);
  const int n = nt * 16 + col;
  if (n < NV) {
    const float bv = fcb[n];
#pragma unroll
    for (int mt = 0; mt < 4; ++mt)
#pragma unroll
      for (int rr = 0; rr < 4; ++rr) {
        const int m = mt * 16 + quad * 4 + rr;
        const bool act = t < declen[m];
        out_pred[((size_t)m * NTD + t) * NV + n] = act ? (acc[mt][rr] + bv) : 0.0f;
      }
  }
}

// ---------------------------------------------------------------------------
// K11v2 (batch): preds for ALL steps from hseq. LDS-tiled GEMM grid (157, 5).
// ---------------------------------------------------------------------------
__global__ __launch_bounds__(256) void k_fc_v2(const f16* __restrict__ hseq,
                                               const f16* __restrict__ fcWt,
                                               const float* __restrict__ fcb,
                                               const int* __restrict__ declen,
                                               float* __restrict__ out_pred) {
  __shared__ __align__(16) f16 lA[256 * LDK];
  __shared__ __align__(16) f16 lB[64 * LDK];
  const int n0 = blockIdx.x * 64, m0 = blockIdx.y * 256;
  const int tid = threadIdx.x, lane = tid & 63, wv = tid >> 6;
  const int col = lane & 15, quad = lane >> 4;
  const f16* gA = hseq + (size_t)(m0 + tid) * ND;
  const f16* gB = fcWt + (size_t)(n0 + (tid >> 2)) * ND + (tid & 3) * 16;
  f16* wA = &lA[tid * LDK];
  f16* wB = &lB[(tid >> 2) * LDK + (tid & 3) * 16];
  f32x4 acc[4][4] = {};
  for (int k0 = 0; k0 < ND; k0 += 64) {
#pragma unroll
    for (int u = 0; u < 8; ++u)
      *(f16x8*)(wA + u * 8) = *(const f16x8*)(gA + k0 + u * 8);
    *(f16x8*)(wB)     = *(const f16x8*)(gB + k0);
    *(f16x8*)(wB + 8) = *(const f16x8*)(gB + k0 + 8);
    __syncthreads();
#pragma unroll
    for (int kh = 0; kh < 2; ++kh) {
      f16x8 a[4], b[4];
#pragma unroll
      for (int i = 0; i < 4; ++i)
        a[i] = *(const f16x8*)&lA[(wv * 64 + i * 16 + col) * LDK + kh * 32 + quad * 8];
#pragma unroll
      for (int j = 0; j < 4; ++j)
        b[j] = *(const f16x8*)&lB[(j * 16 + col) * LDK + kh * 32 + quad * 8];
#pragma unroll
      for (int i = 0; i < 4; ++i)
#pragma unroll
        for (int j = 0; j < 4; ++j)
          acc[i][j] = __builtin_amdgcn_mfma_f32_16x16x32_f16(a[i], b[j], acc[i][j], 0, 0, 0);
    }
    __syncthreads();
  }
#pragma unroll
  for (int j = 0; j < 4; ++j) {
    const int n = n0 + j * 16 + col;
    if (n >= NV) continue;
    const float bv = fcb[n];
#pragma unroll
    for (int i = 0; i < 4; ++i)
#pragma unroll
      for (int rr = 0; rr < 4; ++rr) {
        const int r = m0 + wv * 64 + i * 16 + quad * 4 + rr;
        const int tt = r >> 6, m = r & 63;
        const bool act = tt < declen[m];
        out_pred[((size_t)m * NTD + tt) * NV + n] = act ? (acc[i][j][rr] + bv) : 0.0f;
      }
  }
}

// full3 fallback per-step kernels (non-coop): hall/logits/awe/xlstm_v3
__global__ __launch_bounds__(256) void k_hall(const f16* __restrict__ h16,
                                              const f16* __restrict__ daWt,
                                              const float* __restrict__ dab,
                                              const f16* __restrict__ fbWt,
                                              const float* __restrict__ fbb,
                                              const f16* __restrict__ Wcat2,
                                              float* __restrict__ att2,
                                              float* __restrict__ gate,
                                              float* __restrict__ hwhh) {
  __shared__ float R[4 * 1024];
  const int nt = blockIdx.x;
  const int tid = threadIdx.x, lane = tid & 63, wv = tid >> 6;
  const int col = lane & 15, quad = lane >> 4;
  const f16* Brow; int ldb;
  if (nt < 32)       { Brow = daWt + (size_t)nt * 16 * ND; ldb = ND; }
  else if (nt < 160) { Brow = fbWt + (size_t)(nt - 32) * 16 * ND; ldb = ND; }
  else               { Brow = Wcat2 + (size_t)(nt - 160) * 16 * KC + 2560; ldb = KC; }
  f32x4 acc[4] = {};
  wave_gemm_s<4>(h16, ND, Brow, ldb, wv * 128, wv * 128 + 128, col, quad, acc);
#pragma unroll
  for (int mt = 0; mt < 4; ++mt)
#pragma unroll
    for (int rr = 0; rr < 4; ++rr)
      R[wv * 1024 + (mt * 4 + rr) * 64 + lane] = acc[mt][rr];
  __syncthreads();
#pragma unroll
  for (int j = 0; j < 4; ++j) {
    const int slot = tid * 4 + j;
    const float s = R[slot] + R[1024 + slot] + R[2048 + slot] + R[3072 + slot];
    const int c2 = slot >> 6;
    const int lane_s = slot & 63;
    const int mt = c2 >> 2, rr = c2 & 3;
    const int m = mt * 16 + (lane_s >> 4) * 4 + rr;
    const int nl = lane_s & 15;
    if (nt < 32) {
      const int n = nt * 16 + nl;
      att2[(size_t)m * NA + n] = s + dab[n];
    } else if (nt < 160) {
      const int n = (nt - 32) * 16 + nl;
      gate[(size_t)m * NE + n] = sigmoidf_(s + fbb[n]);
    } else {
      const int r = (nt - 160) * 16 + nl;
      hwhh[(size_t)m * NE + r] = s;
    }
  }
}

__global__ __launch_bounds__(512) void k_logits(const f16* __restrict__ att1,
                                                const float* __restrict__ att2,
                                                const float* __restrict__ fullW,
                                                const int* __restrict__ declen, int t,
                                                float* __restrict__ alpha_ws,
                                                float* __restrict__ out_alphas) {
  const int b = blockIdx.x;
  const int tid = threadIdx.x, wv = tid >> 6, lane = tid & 63;
  __shared__ float e[200];
  __shared__ float red2[2];
  {
    float a2r[8], fwr[8];
    const float4* A2 = (const float4*)(att2 + (size_t)b * NA + lane * 8);
    const float4* FW = (const float4*)(fullW + lane * 8);
    const float4 q0 = A2[0], q1 = A2[1], w0 = FW[0], w1 = FW[1];
    a2r[0] = q0.x; a2r[1] = q0.y; a2r[2] = q0.z; a2r[3] = q0.w;
    a2r[4] = q1.x; a2r[5] = q1.y; a2r[6] = q1.z; a2r[7] = q1.w;
    fwr[0] = w0.x; fwr[1] = w0.y; fwr[2] = w0.z; fwr[3] = w0.w;
    fwr[4] = w1.x; fwr[5] = w1.y; fwr[6] = w1.z; fwr[7] = w1.w;
    for (int p = wv; p < NP; p += 8) {
      const f16x8 row = *(const f16x8*)(att1 + ((size_t)b * NP + p) * NA + lane * 8);
      float acc = 0.0f;
#pragma unroll
      for (int j = 0; j < 8; ++j) acc += fmaxf((float)row[j] + a2r[j], 0.0f) * fwr[j];
#pragma unroll
      for (int off = 32; off > 0; off >>= 1) acc += __shfl_down(acc, off, 64);
      if (lane == 0) e[p] = acc;
    }
  }
  __syncthreads();
  if (wv == 0) {
    const float v0 = e[lane];
    const float v1 = e[lane + 64];
    const float v2 = e[lane + 128];
    const float v3 = (lane < 4) ? e[192 + lane] : -INFINITY;
    float mx = fmaxf(fmaxf(v0, v1), fmaxf(v2, v3));
#pragma unroll
    for (int off = 32; off > 0; off >>= 1) mx = fmaxf(mx, __shfl_xor(mx, off, 64));
    float s = expf(v0 - mx) + expf(v1 - mx) + expf(v2 - mx) +
              ((lane < 4) ? expf(v3 - mx) : 0.0f);
#pragma unroll
    for (int off = 32; off > 0; off >>= 1) s += __shfl_xor(s, off, 64);
    if (lane == 0) { red2[0] = mx; red2[1] = 1.0f / s; }
  }
  __syncthreads();
  if (tid < NP) {
    const float a = expf(e[tid] - red2[0]) * red2[1];
    alpha_ws[(size_t)b * NP + tid] = a;
    const bool act = t < declen[b];
    out_alphas[((size_t)b * NTD + t) * NP + tid] = act ? a : 0.0f;
  }
}

__global__ __launch_bounds__(256) void k_awe(const f16* __restrict__ enc16,
                                             const float* __restrict__ alpha_ws,
                                             const float* __restrict__ gate,
                                             f16* __restrict__ xcat) {
  const int b = blockIdx.x >> 2, q = blockIdx.x & 3;
  const int tid = threadIdx.x;
  __shared__ float al[NP];
  if (tid < NP) al[tid] = alpha_ws[(size_t)b * NP + tid];
  __syncthreads();
  const int c = q * 512 + tid * 2;
  const f16* base = enc16 + (size_t)b * NP * NE + c;
  float a0 = 0.0f, a1 = 0.0f, b0 = 0.0f, b1 = 0.0f;
  for (int p = 0; p < NP; p += 2) {
    const f16x2 v0 = *(const f16x2*)&base[(size_t)p * NE];
    const f16x2 v1 = *(const f16x2*)&base[(size_t)(p + 1) * NE];
    const float ap0 = al[p], ap1 = al[p + 1];
    a0 += ap0 * (float)v0[0]; a1 += ap0 * (float)v0[1];
    b0 += ap1 * (float)v1[0]; b1 += ap1 * (float)v1[1];
  }
  a0 += b0; a1 += b1;
  const float2 g = *(const float2*)&gate[(size_t)b * NE + c];
  f16x2 o; o[0] = (f16)(a0 * g.x); o[1] = (f16)(a1 * g.y);
  *(f16x2*)&xcat[(size_t)b * KC + 512 + c] = o;
}

__global__ __launch_bounds__(512) void k_xlstm_v3(const f16* __restrict__ xcat,
                                                  const f16* __restrict__ Wcat2,
                                                  const float* __restrict__ bcat,
                                                  const float* __restrict__ hwhh,
                                                  const float* __restrict__ embw,
                                                  const int* __restrict__ declen, int t,
                                                  float* __restrict__ cst,
                                                  f16* __restrict__ h16,
                                                  f16* __restrict__ hnew16,
                                                  f16* __restrict__ hseq) {
  __shared__ float R[8 * 512];
  const int nt = blockIdx.x >> 1, mh = blockIdx.x & 1;
  const int tid = threadIdx.x, lane = tid & 63, wv = tid >> 6;
  const int col = lane & 15, quad = lane >> 4;
  f32x4 acc[2] = {};
  wave_gemm_s<2>(xcat + (size_t)mh * 32 * KC, KC,
                 Wcat2 + (size_t)nt * 16 * KC, KC,
                 512 + wv * 256, 512 + wv * 256 + 256, col, quad, acc);
#pragma unroll
  for (int mt = 0; mt < 2; ++mt)
#pragma unroll
    for (int rr = 0; rr < 4; ++rr)
      R[wv * 512 + (mt * 4 + rr) * 64 + lane] = acc[mt][rr];
  __syncthreads();
  {
    float s = R[tid];
#pragma unroll
    for (int w = 1; w < 8; ++w) s += R[w * 512 + tid];
    R[tid] = s;
  }
  __syncthreads();
  if (tid < 128) {
    const int ml = tid >> 2, dl = tid & 3;
    const int m = mh * 32 + ml;
    const int d = nt * 4 + dl;
    const int mt = ml >> 4, qd = (ml >> 2) & 3, rr = ml & 3;
    float g4[4];
#pragma unroll
    for (int g = 0; g < 4; ++g) {
      const int cv = dl * 4 + g;
      const int r = nt * 16 + cv;
      const float s = R[(mt * 4 + rr) * 64 + qd * 16 + cv];
      g4[g] = s + bcat[r] + hwhh[(size_t)m * NE + r] +
              embw[((size_t)t * NB + m) * NE + r];
    }
    const float iv = sigmoidf_(g4[0]);
    const float fv = sigmoidf_(g4[1]);
    const float gv = tanhf(g4[2]);
    const float ov = sigmoidf_(g4[3]);
    const float cold = cst[(size_t)m * ND + d];
    const float cn = fv * cold + iv * gv;
    const float hn = ov * tanhf(cn);
    hnew16[(size_t)m * ND + d] = (f16)hn;
    hseq[((size_t)t * NB + m) * ND + d] = (f16)hn;
    if (t < declen[m]) {
      cst[(size_t)m * ND + d] = cn;
      h16[(size_t)m * ND + d] = (f16)hn;
    }
  }
}

}  // namespace

extern "C" void kernel_launch(void* const* d_in, const int* in_sizes, int n_in,
                              void* d_out, int out_size, void* d_ws, size_t ws_size,
                              hipStream_t stream) {
  const float* enc        = (const float*)d_in[0];
  const int*   caps       = (const int*)d_in[1];
  const int*   caplen     = (const int*)d_in[2];
  const float* emb        = (const float*)d_in[3];
  const float* enc_att_W  = (const float*)d_in[4];
  const float* enc_att_b  = (const float*)d_in[5];
  const float* dec_att_W  = (const float*)d_in[6];
  const float* dec_att_b  = (const float*)d_in[7];
  const float* full_att_W = (const float*)d_in[8];
  // d_in[9] full_att_b: shift-invariant under softmax, unused.
  const float* init_h_W   = (const float*)d_in[10];
  const float* init_h_b   = (const float*)d_in[11];
  const float* init_c_W   = (const float*)d_in[12];
  const float* init_c_b   = (const float*)d_in[13];
  const float* f_beta_W   = (const float*)d_in[14];
  const float* f_beta_b   = (const float*)d_in[15];
  const float* W_ih       = (const float*)d_in[16];
  const float* b_ih       = (const float*)d_in[17];
  const float* W_hh       = (const float*)d_in[18];
  const float* b_hh       = (const float*)d_in[19];
  const float* fc_W       = (const float*)d_in[20];
  const float* fc_b       = (const float*)d_in[21];

  char* ws = (char*)d_ws;
  f16*   att1   = (f16*)(ws + OFF_ATT1);
  f16*   daWt   = (f16*)(ws + OFF_DAW);
  f16*   fbWt   = (f16*)(ws + OFF_FBW);
  f16*   eaWt   = (f16*)(ws + OFF_EAW);
  f16*   ihWt   = (f16*)(ws + OFF_IHW);
  f16*   icWt   = (f16*)(ws + OFF_ICW);
  f16*   fcWt   = (f16*)(ws + OFF_FCW);   // aliases eaWt/ihWt/icWt (written after)
  f16*   Wcat2  = (f16*)(ws + OFF_WCAT);
  f16*   mean16 = (f16*)(ws + OFF_MEAN16);
  f16*   h16    = (f16*)(ws + OFF_H16);
  f16*   hnew16 = (f16*)(ws + OFF_HNEW16);
  float* cst    = (float*)(ws + OFF_C);
  float* att2   = (float*)(ws + OFF_ATT2);
  float* gate   = (float*)(ws + OFF_GATE);
  float* alpha  = (float*)(ws + OFF_ALPHA);
  f16*   xcat   = (f16*)(ws + OFF_XCAT);
  int*   wsi    = (int*)(ws + OFF_INT);
  int*   perm   = wsi;
  int*   declen = wsi + 64;
  int*   caps_s = wsi + 128;
  float* bcat   = (float*)(ws + OFF_BCAT);
  f16*   enc16  = (f16*)(ws + OFF_ENC16);
  float* hwhh   = (float*)(ws + OFF_HWHH);
  float* embw   = (float*)(ws + OFF_EMBW);
  f16*   embs16 = (f16*)(ws + OFF_EMBS);

  const bool full  = ws_size >= FULL_BYTES;
  const bool batch = ws_size >= FULL2_BYTES;
  const bool full3 = ws_size >= FULL3_BYTES;
  f16* hseq = batch ? (f16*)(ws + OFF_HSEQ) : (f16*)nullptr;

  // cooperative-launch capability check (host-side queries only; graph-safe)
  bool coop_ok = false;
  int coop_grid = 0;
  if (full3) {
    int dev = 0;
    if (hipGetDevice(&dev) == hipSuccess) {
      int coop = 0;
      hipDeviceGetAttribute(&coop, hipDeviceAttributeCooperativeLaunch, dev);
      if (coop) {
        int ncu = 0;
        hipDeviceGetAttribute(&ncu, hipDeviceAttributeMultiprocessorCount, dev);
        int maxb = 0;
        if (hipOccupancyMaxActiveBlocksPerMultiprocessor(
                &maxb, reinterpret_cast<const void*>(&k_steps3), 512, 0) == hipSuccess &&
            maxb >= 1 && ncu > 0) {
          coop_grid = maxb * ncu;
          if (coop_grid > 256) coop_grid = 256;
          coop_ok = coop_grid >= 64;
        }
      }
    }
  }

  float* out         = (float*)d_out;
  float* out_pred    = out;
  float* out_caps    = out_pred + (size_t)NB * NTD * NV;
  float* out_declen  = out_caps + (size_t)NB * NT_CAP;
  float* out_alphas  = out_declen + NB;
  float* out_sortind = out_alphas + (size_t)NB * NTD * NP;

  k_sort<<<1, 64, 0, stream>>>(caplen, caps, perm, declen, caps_s,
                               out_caps, out_declen, out_sortind);
  k_tconv3<<<dim3(16, 64, 3), 256, 0, stream>>>(enc_att_W, eaWt, init_h_W, ihWt,
                                                init_c_W, icWt);
  k_tconv2b<<<dim3(80, 16), 256, 0, stream>>>(dec_att_W, daWt, f_beta_W, fbWt);
  if (full) {
    k_enc_cvt<<<dim3(196, 64), 256, 0, stream>>>(enc, perm, enc16);
    k_mean16<<<dim3(4, 64), 256, 0, stream>>>(enc16, mean16);
  } else {
    k_mean<<<dim3(4, 64), 256, 0, stream>>>(enc, perm, mean16);
  }
  k_init_mfma<<<dim3(16, 2), 256, 0, stream>>>(mean16, ihWt, icWt, init_h_b, init_c_b,
                                               h16, cst);
  if (full)
    k_att1_v3<<<dim3(98, 4), 256, 0, stream>>>(enc16, eaWt, enc_att_b, att1);
  else
    k_att1_mfma<false><<<dim3(4, 196), 256, 0, stream>>>(enc, enc16, perm, eaWt,
                                                         enc_att_b, att1);
  // fcWt write ALIASES eaWt/ihWt/icWt — must come after k_init/k_att1 (stream order).
  k_tconv<<<dim3(314, 16), 256, 0, stream>>>(fc_W, fcWt, 512, NV);
  k_cvt_wcat2<<<2048, 256, 0, stream>>>(W_ih, W_hh, b_ih, b_hh, Wcat2, bcat);
  if (full3) {
    k_embs<<<dim3(NTD, NB), 256, 0, stream>>>(emb, caps_s, embs16);
    k_embw<<<dim3(32, 5), 256, 0, stream>>>(embs16, Wcat2, embw);
  }

  if (full3 && coop_ok) {
    Step3Params P;
    P.h16 = h16; P.daWt = daWt; P.dab = dec_att_b; P.fbWt = fbWt; P.fbb = f_beta_b;
    P.Wcat2 = Wcat2; P.bcat = bcat; P.att1 = att1; P.fullW = full_att_W;
    P.enc16 = enc16; P.embw = embw; P.declen = declen;
    P.att2 = att2; P.gate = gate;
    P.out_alphas = out_alphas; P.xcat = xcat; P.cst = cst; P.hseq = hseq;
    void* args[] = { &P };
    hipLaunchCooperativeKernel(reinterpret_cast<const void*>(&k_steps3),
                               dim3(coop_grid), dim3(512), args, 0, stream);
    k_fc_v2<<<dim3(157, 5), 256, 0, stream>>>(hseq, fcWt, fc_b, declen, out_pred);
  } else if (full3) {
    for (int t = 0; t < NTD; ++t) {
      k_hall<<<288, 256, 0, stream>>>(h16, daWt, dec_att_b, fbWt, f_beta_b, Wcat2,
                                      att2, gate, hwhh);
      k_logits<<<NB, 512, 0, stream>>>(att1, att2, full_att_W, declen, t,
                                       alpha, out_alphas);
      k_awe<<<256, 256, 0, stream>>>(enc16, alpha, gate, xcat);
      k_xlstm_v3<<<256, 512, 0, stream>>>(xcat, Wcat2, bcat, hwhh, embw, declen, t,
                                          cst, h16, hnew16, hseq);
    }
    k_fc_v2<<<dim3(157, 5), 256, 0, stream>>>(hseq, fcWt, fc_b, declen, out_pred);
  } else {
    for (int t = 0; t < NTD; ++t) {
      k_hgemm_v2<<<80, 256, 0, stream>>>(h16, daWt, dec_att_b, fbWt, f_beta_b,
                                         att2, gate);
      if (full)
        k_attn_awe<true><<<NB, 512, 0, stream>>>(att1, att2, full_att_W, declen, t,
                                                 enc, enc16, perm, gate, emb, caps_s,
                                                 h16, xcat, out_alphas);
      else
        k_attn_awe<false><<<NB, 512, 0, stream>>>(att1, att2, full_att_W, declen, t,
                                                  enc, enc16, perm, gate, emb, caps_s,
                                                  h16, xcat, out_alphas);
      k_xlstm_v2<<<128, 512, 0, stream>>>(xcat, Wcat2, bcat, declen, t,
                                          cst, h16, hnew16, hseq);
      if (!batch)
        k_fc_mfma<<<157, 256, 0, stream>>>(hnew16, fcWt, fc_b, declen, t, out_pred);
    }
    if (batch)
      k_fc_v2<<<dim3(157, 5), 256, 0, stream>>>(hseq, fcWt, fc_b, declen, out_pred);
  }
}